// Round 3
// baseline (487.493 us; speedup 1.0000x reference)
//
#include <hip/hip_runtime.h>
#include <hip/hip_bf16.h>

#define NN 100000
#define NE 1600000
#define NR 100032            // NN rounded to 64-row blocks (table alloc rows)
#define NB2 196              // coarse buckets = ceil(NN/512)
#define NBLK 391             // hist/scatter blocks = ceil(NE/4096)
#define EPB 4096             // edges per hist/scatter block

#if defined(__has_builtin)
#  if __has_builtin(__builtin_amdgcn_cvt_pk_f32_fp8) && \
      __has_builtin(__builtin_amdgcn_cvt_pk_fp8_f32) && \
      __has_builtin(__builtin_amdgcn_cvt_f32_fp8)
#    define HWF8 1
#  endif
#endif

typedef float f32x2 __attribute__((ext_vector_type(2)));
typedef float f32x4 __attribute__((ext_vector_type(4)));
typedef short bf16x8 __attribute__((ext_vector_type(8)));

static __device__ __forceinline__ float bf2f(__hip_bfloat16 v) { return __bfloat162float(v); }
static __device__ __forceinline__ float bfu(unsigned short w) {
    return __uint_as_float((unsigned)w << 16);
}

// ---------------- fp8 e4m3 software codec (fallback, validated r3/r4) ---------
static __device__ __forceinline__ float f8d_sw(unsigned b) {
    unsigned e = (b >> 3) & 15u, m = b & 7u;
    float mag;
    if (e == 0) mag = (float)m * 0.001953125f;
    else        mag = __uint_as_float(((e + 120u) << 23) | (m << 20));
    return (b & 0x80u) ? -mag : mag;
}
static __device__ __forceinline__ unsigned char f8e_sw(float x) {
    unsigned u = __float_as_uint(x);
    unsigned s = (u >> 31) << 7;
    unsigned au = u & 0x7fffffffu;
    if (au >= 0x43E00000u) return (unsigned char)(s | 0x7Eu);
    if (au <  0x3A800000u) return (unsigned char)s;
    if (au <  0x3C800000u) {
        float a = __uint_as_float(au);
        int m = (int)rintf(a * 512.0f);
        if (m >= 8) return (unsigned char)(s | 0x08u);
        return (unsigned char)(s | (unsigned)m);
    }
    au += 0x80000u;
    if (au >= 0x43E00000u) return (unsigned char)(s | 0x7Eu);
    unsigned e = (au >> 23) - 120u;
    unsigned m = (au >> 20) & 7u;
    return (unsigned char)(s | (e << 3) | m);
}

// ---------------- fp8 helpers (HW if available) ----------------
static __device__ __forceinline__ float f8d1(unsigned b) {
#ifdef HWF8
    return __builtin_amdgcn_cvt_f32_fp8((int)b, 0);
#else
    return f8d_sw(b);
#endif
}
static __device__ __forceinline__ void f8d2(unsigned short v, float& x0, float& x1) {
#ifdef HWF8
    f32x2 r = __builtin_amdgcn_cvt_pk_f32_fp8((int)(unsigned)v, false);
    x0 = r.x; x1 = r.y;
#else
    x0 = f8d_sw(v & 255u); x1 = f8d_sw(v >> 8);
#endif
}
static __device__ __forceinline__ void f8d4(unsigned u, float* o) {
#ifdef HWF8
    f32x2 lo = __builtin_amdgcn_cvt_pk_f32_fp8((int)u, false);
    f32x2 hi = __builtin_amdgcn_cvt_pk_f32_fp8((int)u, true);
    o[0] = lo.x; o[1] = lo.y; o[2] = hi.x; o[3] = hi.y;
#else
    o[0] = f8d_sw(u & 255u); o[1] = f8d_sw((u >> 8) & 255u);
    o[2] = f8d_sw((u >> 16) & 255u); o[3] = f8d_sw(u >> 24);
#endif
}
static __device__ __forceinline__ unsigned short f8e2(float a, float b) {
#ifdef HWF8
    float ca = fminf(fmaxf(a, -448.0f), 448.0f);
    float cb = fminf(fmaxf(b, -448.0f), 448.0f);
    int p = __builtin_amdgcn_cvt_pk_fp8_f32(ca, cb, 0, false);
    return (unsigned short)(p & 0xFFFF);
#else
    return (unsigned short)f8e_sw(a) | ((unsigned short)f8e_sw(b) << 8);
#endif
}
static __device__ __forceinline__ unsigned char f8e1(float a) {
    return (unsigned char)(f8e2(a, 0.0f) & 0xFF);
}
// f32 -> bf16 bits by truncation (EXACT for values that came from fp8 e4m3)
static __device__ __forceinline__ unsigned bfpack(float lo, float hi) {
    return (__float_as_uint(lo) >> 16) | (__float_as_uint(hi) & 0xFFFF0000u);
}

// decode 16 fp8 (uint4) and accumulate UNWEIGHTED into 8 f32x2 (v_pk_add_f32)
static __device__ __forceinline__ void acc16_add(f32x2* acc, uint4 v) {
#ifdef HWF8
    acc[0] += __builtin_amdgcn_cvt_pk_f32_fp8((int)v.x, false);
    acc[1] += __builtin_amdgcn_cvt_pk_f32_fp8((int)v.x, true);
    acc[2] += __builtin_amdgcn_cvt_pk_f32_fp8((int)v.y, false);
    acc[3] += __builtin_amdgcn_cvt_pk_f32_fp8((int)v.y, true);
    acc[4] += __builtin_amdgcn_cvt_pk_f32_fp8((int)v.z, false);
    acc[5] += __builtin_amdgcn_cvt_pk_f32_fp8((int)v.z, true);
    acc[6] += __builtin_amdgcn_cvt_pk_f32_fp8((int)v.w, false);
    acc[7] += __builtin_amdgcn_cvt_pk_f32_fp8((int)v.w, true);
#else
    unsigned u[4] = {v.x, v.y, v.z, v.w};
#pragma unroll
    for (int q = 0; q < 4; q++) {
        float o[4]; f8d4(u[q], o);
        acc[2 * q]     += (f32x2){o[0], o[1]};
        acc[2 * q + 1] += (f32x2){o[2], o[3]};
    }
#endif
}
// decode 16 fp8 (uint4) and fma with scalar weight into 8 f32x2
static __device__ __forceinline__ void acc16_fma(f32x2* acc, uint4 v, float w) {
    f32x2 wv = (f32x2){w, w};
#ifdef HWF8
    acc[0] += __builtin_amdgcn_cvt_pk_f32_fp8((int)v.x, false) * wv;
    acc[1] += __builtin_amdgcn_cvt_pk_f32_fp8((int)v.x, true)  * wv;
    acc[2] += __builtin_amdgcn_cvt_pk_f32_fp8((int)v.y, false) * wv;
    acc[3] += __builtin_amdgcn_cvt_pk_f32_fp8((int)v.y, true)  * wv;
    acc[4] += __builtin_amdgcn_cvt_pk_f32_fp8((int)v.z, false) * wv;
    acc[5] += __builtin_amdgcn_cvt_pk_f32_fp8((int)v.z, true)  * wv;
    acc[6] += __builtin_amdgcn_cvt_pk_f32_fp8((int)v.w, false) * wv;
    acc[7] += __builtin_amdgcn_cvt_pk_f32_fp8((int)v.w, true)  * wv;
#else
    unsigned u[4] = {v.x, v.y, v.z, v.w};
#pragma unroll
    for (int q = 0; q < 4; q++) {
        float o[4]; f8d4(u[q], o);
        acc[2 * q]     += (f32x2){o[0] * w, o[1] * w};
        acc[2 * q + 1] += (f32x2){o[2] * w, o[3] * w};
    }
#endif
}

// ---------------- dtype probes (parallel) ----------------
__global__ void k_probe1(const unsigned short* __restrict__ xw,
                         const int* __restrict__ ei, int* __restrict__ raw) {
    int i = blockIdx.x * 256 + threadIdx.x;    // 65536 probes
    int nan = ((xw[i] & 0x7F80u) == 0x7F80u) ? 1 : 0;
    int odd = (ei[2 * i + 1] != 0) ? 1 : 0;
    unsigned long long bn = __ballot(nan);
    unsigned long long bo = __ballot(odd);
    if ((threadIdx.x & 63) == 0) {
        if (bn) atomicAdd(&raw[0], __popcll(bn));
        if (bo) atomicAdd(&raw[1], __popcll(bo));
    }
}
__global__ void k_probe2(const int* __restrict__ raw, int* __restrict__ flags) {
    if (threadIdx.x == 0) {
        flags[0] = (raw[0] > 0) ? 1 : 0;   // x/weights are f32
        flags[1] = (raw[1] == 0) ? 1 : 0;  // edge_index is int64
    }
}

static __device__ __forceinline__ int e_src(const int* ei, int e, int f64) {
    int v = f64 ? ei[2 * e] : ei[e];
    return min(max(v, 0), NN - 1);
}
static __device__ __forceinline__ int e_dst(const int* ei, int e, int f64) {
    int v = f64 ? ei[2 * (NE + e)] : ei[NE + e];
    return min(max(v, 0), NN - 1);
}
static __device__ __forceinline__ float ldx(const void* p, long long i, int f32) {
    return f32 ? ((const float*)p)[i] : bf2f(((const __hip_bfloat16*)p)[i]);
}

// ------------- parameter conversion: W -> bf16 in MFMA-frag order -------------
__global__ void cvt_params(const void* W1, const void* b1, const void* W2, const void* b2,
                           const void* W3, const void* b3, const void* Wa,
                           unsigned short* W1b, unsigned short* W2b, unsigned short* W3b,
                           float* b1f, float* b2f, float* b3f, float* Waf,
                           const int* flags) {
    int i = blockIdx.x * blockDim.x + threadIdx.x;
    int f = flags[0];
    if (i < 16384) {
        int j = i & 7, l = (i >> 3) & 63, c = (i >> 9) & 7, kc = i >> 12;
        int k = kc * 32 + ((l >> 4)) * 8 + j;
        int col = c * 16 + (l & 15);
        W1b[i] = __bfloat16_as_ushort(__float2bfloat16(ldx(W1, k * 128 + col, f)));
        W2b[i] = __bfloat16_as_ushort(__float2bfloat16(ldx(W2, k * 128 + col, f)));
    }
    if (i < 8192) {
        int j = i & 7, l = (i >> 3) & 63, c = (i >> 9) & 3, kc = i >> 11;
        int k = kc * 32 + ((l >> 4)) * 8 + j;
        int col = c * 16 + (l & 15);
        W3b[i] = __bfloat16_as_ushort(__float2bfloat16(ldx(W3, k * 64 + col, f)));
    }
    if (i < 4096)  Waf[i] = ldx(Wa, i, f);
    if (i < 128)   { b1f[i] = ldx(b1, i, f); b2f[i] = ldx(b2, i, f); }
    if (i < 64)    b3f[i] = ldx(b3, i, f);
}

// ---------------- x -> fp8 table P ----------------
__global__ void k_cvtx(const void* __restrict__ x, unsigned char* __restrict__ P,
                       const int* __restrict__ flags) {
    int i = blockIdx.x * blockDim.x + threadIdx.x;
    if (i >= (NN * 128) / 4) return;
    unsigned pk;
    if (flags[0]) {
        float4 v = ((const float4*)x)[i];
        pk = (unsigned)f8e2(v.x, v.y) | ((unsigned)f8e2(v.z, v.w) << 16);
    } else {
        ushort4 v = ((const ushort4*)x)[i];
        pk = (unsigned)f8e2(bfu(v.x), bfu(v.y)) | ((unsigned)f8e2(bfu(v.z), bfu(v.w)) << 16);
    }
    ((unsigned*)P)[i] = pk;
}

// ======== CSR build: atomic-free multisplit (validated r7) ========
__global__ __launch_bounds__(256) void k_hist(const int* __restrict__ ei,
                                              int* __restrict__ ghist,
                                              const int* __restrict__ flags) {
    __shared__ int h[NB2];
    int blk = blockIdx.x, t = threadIdx.x;
    for (int i = t; i < NB2; i += 256) h[i] = 0;
    __syncthreads();
    int f64 = flags[1];
    int e0 = blk * EPB;
    for (int i = t; i < EPB; i += 256) {
        int e = e0 + i;
        if (e < NE) atomicAdd(&h[e_dst(ei, e, f64) >> 9], 1);
    }
    __syncthreads();
    for (int i = t; i < NB2; i += 256) ghist[blk * NB2 + i] = h[i];
}

__global__ __launch_bounds__(256) void k_off(const int* __restrict__ ghist,
                                             int* __restrict__ cbase,
                                             int* __restrict__ offm,
                                             int* __restrict__ rowptr) {
    __shared__ int tot[NB2];
    int t = threadIdx.x;
    if (t < NB2) {
        int s = 0;
        for (int blk = 0; blk < NBLK; blk++) s += ghist[blk * NB2 + t];
        tot[t] = s;
    }
    __syncthreads();
    if (t == 0) {
        int run = 0;
        for (int b = 0; b < NB2; b++) { cbase[b] = run; run += tot[b]; }
        cbase[NB2] = run;
        rowptr[NN] = run;   // == NE
    }
    __syncthreads();
    if (t < NB2) {
        int run = cbase[t];
        for (int blk = 0; blk < NBLK; blk++) {
            offm[blk * NB2 + t] = run;
            run += ghist[blk * NB2 + t];
        }
    }
}

__global__ __launch_bounds__(256) void k_scatter(const int* __restrict__ ei,
                                                 const int* __restrict__ offm,
                                                 int* __restrict__ scratch,
                                                 const int* __restrict__ flags) {
    __shared__ int cur[NB2];
    int blk = blockIdx.x, t = threadIdx.x;
    for (int i = t; i < NB2; i += 256) cur[i] = offm[blk * NB2 + i];
    __syncthreads();
    int f64 = flags[1];
    int e0 = blk * EPB;
    for (int i = t; i < EPB; i += 256) {
        int e = e0 + i;
        if (e < NE) {
            int d = e_dst(ei, e, f64);
            int s = e_src(ei, e, f64);
            int p = atomicAdd(&cur[d >> 9], 1);
            p = min(max(p, 0), NE - 1);
            scratch[p] = s | ((d & 511) << 17);
        }
    }
}

__global__ __launch_bounds__(256) void k_build(const int* __restrict__ scratch,
                                               const int* __restrict__ cbase,
                                               int* __restrict__ rowptr,
                                               float* __restrict__ dis,
                                               int* __restrict__ csr) {
    __shared__ int hist[512];
    __shared__ int base[512];
    __shared__ int sd[256];
    int b = blockIdx.x, t = threadIdx.x;
    int n0 = b << 9;
    int s0 = cbase[b], s1 = cbase[b + 1];
    hist[t] = 0; hist[t + 256] = 0;
    __syncthreads();
    for (int i = s0 + t; i < s1; i += 256) {
        int dlo = (scratch[i] >> 17) & 511;
        atomicAdd(&hist[dlo], 1);
    }
    __syncthreads();
    int v0 = hist[2 * t], v1 = hist[2 * t + 1];
    int s = v0 + v1;
    sd[t] = s; __syncthreads();
    for (int o = 1; o < 256; o <<= 1) {
        int add = (t >= o) ? sd[t - o] : 0;
        __syncthreads();
        sd[t] += add;
        __syncthreads();
    }
    int run = s0 + sd[t] - s;
    base[2 * t] = run;
    base[2 * t + 1] = run + v0;
    int n = n0 + 2 * t;
    if (n < NN) {
        rowptr[n] = run;
        dis[n] = rsqrtf((float)v0 + 1.0f);
    }
    if (n + 1 < NN) {
        rowptr[n + 1] = run + v0;
        dis[n + 1] = rsqrtf((float)v1 + 1.0f);
    }
    __syncthreads();
    for (int i = s0 + t; i < s1; i += 256) {
        int v = scratch[i];
        int dlo = (v >> 17) & 511;
        int p = atomicAdd(&base[dlo], 1);
        p = min(max(p, 0), NE - 1);
        csr[p] = v & 0x1FFFF;
    }
}

// ------------- MFMA GEMM: O[NNxCOLS] = dis[row] * (A(fp8,128) @ W) ------------
// Pre-scales each output row by dis[row] so aggregation is an unweighted sum.
// Row NN is written as zeros (pad row gathered by invalid edge slots).
template <int NCT>    // NCT = COLS/16 (8 or 4)
__global__ __launch_bounds__(256) void k_xf_mfma(const unsigned char* __restrict__ A,
                                                 const unsigned short* __restrict__ Wf,
                                                 const float* __restrict__ dis,
                                                 unsigned char* __restrict__ O) {
    __shared__ unsigned short wl[NCT * 4 * 64 * 8];
    int t = threadIdx.x;
    int n0 = blockIdx.x * 64;
    {
        const uint4* wg = (const uint4*)Wf;
        uint4* wld = (uint4*)wl;
#pragma unroll
        for (int i = 0; i < NCT; i++) wld[i * 256 + t] = wg[i * 256 + t];
    }
    __syncthreads();
    int w = t >> 6, l = t & 63;
    int quad = l >> 4, m = l & 15;
    int arow = n0 + w * 16 + m;
    const unsigned char* ap = A + (size_t)arow * 128 + quad * 8;
    f32x4 acc[NCT];
#pragma unroll
    for (int c = 0; c < NCT; c++) acc[c] = (f32x4){0.0f, 0.0f, 0.0f, 0.0f};
#pragma unroll
    for (int kc = 0; kc < 4; kc++) {
        uint2 g = *(const uint2*)(ap + kc * 32);
        float o[8];
        f8d4(g.x, o); f8d4(g.y, o + 4);
        union { unsigned u[4]; bf16x8 v; } fr;
        fr.u[0] = bfpack(o[0], o[1]);
        fr.u[1] = bfpack(o[2], o[3]);
        fr.u[2] = bfpack(o[4], o[5]);
        fr.u[3] = bfpack(o[6], o[7]);
#pragma unroll
        for (int c = 0; c < NCT; c++) {
            bf16x8 bw = *(const bf16x8*)&wl[((kc * NCT + c) * 64 + l) * 8];
            acc[c] = __builtin_amdgcn_mfma_f32_16x16x32_bf16(fr.v, bw, acc[c], 0, 0, 0);
        }
    }
    int orow0 = n0 + w * 16 + quad * 4;
    float dsc[4];
#pragma unroll
    for (int r = 0; r < 4; r++) {
        int row = orow0 + r;
        dsc[r] = (row < NN) ? dis[row] : 0.0f;     // row==NN -> store zeros
    }
#pragma unroll
    for (int c = 0; c < NCT; c++) {
        int col = c * 16 + m;
#pragma unroll
        for (int r = 0; r < 4; r++) {
            int row = orow0 + r;
            if (row <= NN) O[(size_t)row * (NCT * 16) + col] = f8e1(acc[c][r] * dsc[r]);
        }
    }
}

// ---- agg, F=128: H = relu?((sum T'[src] + T'[n]) * dn + b), fp8->fp8 --------
// v3: T pre-scaled by dis => unweighted sum. 8 lanes per 128B row (16B/lane),
// 8 edges per wave-load. slot r = lane>>3, f = lane&7 (features 16f..16f+15).
// Invalid slots gather zero row NN. Self term = T'[n] (weight 1.0: its dis
// factor is already folded into T'; the trailing *dn supplies the second).
template <bool RELU>
__global__ __launch_bounds__(256) void k_agg128(const unsigned char* __restrict__ Tb,
                                                const int* __restrict__ rowptr,
                                                const int* __restrict__ csr,
                                                const float* __restrict__ dis,
                                                const float* __restrict__ bias,
                                                unsigned char* __restrict__ H) {
    int n = blockIdx.x * 4 + (threadIdx.x >> 6);
    int lane = threadIdx.x & 63;
    int r = lane >> 3;            // edge slot 0..7
    int f = lane & 7;             // feature group: bytes 16f..16f+15
    int fo = f << 4;
    float dn = dis[n];
    int s0 = rowptr[n], s1 = rowptr[n + 1];
    s0 = min(max(s0, 0), NE); s1 = min(max(s1, s0), NE);
    f32x2 acc[8];
#pragma unroll
    for (int k = 0; k < 8; k++) acc[k] = (f32x2){0.0f, 0.0f};
    {   // self term: T'[n] with weight 1.0 on slot 0 (dis already folded in)
        uint4 v = *(const uint4*)(Tb + (((unsigned)n << 7) + (unsigned)fo));
        acc16_fma(acc, v, (r == 0) ? 1.0f : 0.0f);
    }
    int pa = r << 2;              // bpermute byte addr of slot r in group 0
    for (int base = s0; base < s1; base += 64) {
        int m = min(64, s1 - base);
        unsigned voff = (unsigned)NN << 7;      // pad -> zero row
        if (lane < m) {
            int ss = csr[base + lane];
            ss = min(max(ss, 0), NN - 1);
            voff = (unsigned)ss << 7;
        }
        int ng  = (m + 7) >> 3;
        int ngp = (ng + 1) & ~1;  // pairs of groups for MLP=2; pads read zero row
        for (int g = 0; g < ngp; g += 2) {
            int a0 = pa + (g << 5);
            unsigned vo0 = (unsigned)__builtin_amdgcn_ds_bpermute(a0,      (int)voff);
            unsigned vo1 = (unsigned)__builtin_amdgcn_ds_bpermute(a0 + 32, (int)voff);
            uint4 v0 = *(const uint4*)(Tb + (vo0 + (unsigned)fo));
            uint4 v1 = *(const uint4*)(Tb + (vo1 + (unsigned)fo));
            acc16_add(acc, v0);
            acc16_add(acc, v1);
        }
    }
    // reduce across the 8 slots (lane strides 8, 16, 32)
#pragma unroll
    for (int k = 0; k < 8; k++) {
        acc[k].x += __shfl_xor(acc[k].x, 8, 64);
        acc[k].y += __shfl_xor(acc[k].y, 8, 64);
        acc[k].x += __shfl_xor(acc[k].x, 16, 64);
        acc[k].y += __shfl_xor(acc[k].y, 16, 64);
        acc[k].x += __shfl_xor(acc[k].x, 32, 64);
        acc[k].y += __shfl_xor(acc[k].y, 32, 64);
    }
    if (r == 0) {
        float4 B0 = *(const float4*)(bias + 16 * f);
        float4 B1 = *(const float4*)(bias + 16 * f + 4);
        float4 B2 = *(const float4*)(bias + 16 * f + 8);
        float4 B3 = *(const float4*)(bias + 16 * f + 12);
        float bb[16] = {B0.x, B0.y, B0.z, B0.w, B1.x, B1.y, B1.z, B1.w,
                        B2.x, B2.y, B2.z, B2.w, B3.x, B3.y, B3.z, B3.w};
        float t[16];
#pragma unroll
        for (int k = 0; k < 8; k++) {
            t[2 * k]     = acc[k].x * dn + bb[2 * k];
            t[2 * k + 1] = acc[k].y * dn + bb[2 * k + 1];
        }
        if (RELU) {
#pragma unroll
            for (int k = 0; k < 16; k++) t[k] = fmaxf(t[k], 0.0f);
        }
        uint4 o;
        o.x = (unsigned)f8e2(t[0],  t[1])  | ((unsigned)f8e2(t[2],  t[3])  << 16);
        o.y = (unsigned)f8e2(t[4],  t[5])  | ((unsigned)f8e2(t[6],  t[7])  << 16);
        o.z = (unsigned)f8e2(t[8],  t[9])  | ((unsigned)f8e2(t[10], t[11]) << 16);
        o.w = (unsigned)f8e2(t[12], t[13]) | ((unsigned)f8e2(t[14], t[15]) << 16);
        *(uint4*)(H + (((size_t)n << 7) + (size_t)fo)) = o;
    }
}

// ---- agg, F=64 final: h3 = (sum T3'[src] + T3'[n]) * dn + b3 -> bf16 --------
// v3: 4 lanes per 64B row (16B/lane), 16 edges per wave-load.
__global__ __launch_bounds__(256) void k_agg64(const unsigned char* __restrict__ Tb,
                                               const int* __restrict__ rowptr,
                                               const int* __restrict__ csr,
                                               const float* __restrict__ dis,
                                               const float* __restrict__ bias,
                                               unsigned short* __restrict__ Hb) {
    int n = blockIdx.x * 4 + (threadIdx.x >> 6);
    int lane = threadIdx.x & 63;
    int r = lane >> 2;            // edge slot 0..15
    int f = lane & 3;             // feature group: bytes 16f..16f+15
    int fo = f << 4;
    float dn = dis[n];
    int s0 = rowptr[n], s1 = rowptr[n + 1];
    s0 = min(max(s0, 0), NE); s1 = min(max(s1, s0), NE);
    f32x2 acc[8];
#pragma unroll
    for (int k = 0; k < 8; k++) acc[k] = (f32x2){0.0f, 0.0f};
    {   // self term: weight 1.0 (dis folded into T3')
        uint4 v = *(const uint4*)(Tb + (((unsigned)n << 6) + (unsigned)fo));
        acc16_fma(acc, v, (r == 0) ? 1.0f : 0.0f);
    }
    int pa = r << 2;
    for (int base = s0; base < s1; base += 64) {
        int m = min(64, s1 - base);
        unsigned voff = (unsigned)NN << 6;      // pad -> zero row
        if (lane < m) {
            int ss = csr[base + lane];
            ss = min(max(ss, 0), NN - 1);
            voff = (unsigned)ss << 6;
        }
        int ng  = (m + 15) >> 4;
        int ngp = (ng + 1) & ~1;
        for (int g = 0; g < ngp; g += 2) {
            int a0 = pa + (g << 6);   // lane index g*16+r -> byte addr g*64 + r*4
            unsigned vo0 = (unsigned)__builtin_amdgcn_ds_bpermute(a0,      (int)voff);
            unsigned vo1 = (unsigned)__builtin_amdgcn_ds_bpermute(a0 + 64, (int)voff);
            uint4 v0 = *(const uint4*)(Tb + (vo0 + (unsigned)fo));
            uint4 v1 = *(const uint4*)(Tb + (vo1 + (unsigned)fo));
            acc16_add(acc, v0);
            acc16_add(acc, v1);
        }
    }
    // reduce across the 16 slots (lane strides 4, 8, 16, 32)
#pragma unroll
    for (int k = 0; k < 8; k++) {
        acc[k].x += __shfl_xor(acc[k].x, 4, 64);
        acc[k].y += __shfl_xor(acc[k].y, 4, 64);
        acc[k].x += __shfl_xor(acc[k].x, 8, 64);
        acc[k].y += __shfl_xor(acc[k].y, 8, 64);
        acc[k].x += __shfl_xor(acc[k].x, 16, 64);
        acc[k].y += __shfl_xor(acc[k].y, 16, 64);
        acc[k].x += __shfl_xor(acc[k].x, 32, 64);
        acc[k].y += __shfl_xor(acc[k].y, 32, 64);
    }
    if (r == 0) {
        float4 B0 = *(const float4*)(bias + 16 * f);
        float4 B1 = *(const float4*)(bias + 16 * f + 4);
        float4 B2 = *(const float4*)(bias + 16 * f + 8);
        float4 B3 = *(const float4*)(bias + 16 * f + 12);
        float bb[16] = {B0.x, B0.y, B0.z, B0.w, B1.x, B1.y, B1.z, B1.w,
                        B2.x, B2.y, B2.z, B2.w, B3.x, B3.y, B3.z, B3.w};
        float t[16];
#pragma unroll
        for (int k = 0; k < 8; k++) {
            t[2 * k]     = acc[k].x * dn + bb[2 * k];
            t[2 * k + 1] = acc[k].y * dn + bb[2 * k + 1];
        }
        unsigned p[8];
#pragma unroll
        for (int k = 0; k < 8; k++)
            p[k] = (unsigned)__bfloat16_as_ushort(__float2bfloat16(t[2 * k])) |
                   ((unsigned)__bfloat16_as_ushort(__float2bfloat16(t[2 * k + 1])) << 16);
        unsigned short* op = Hb + (((size_t)n << 6) + (size_t)(f * 16));
        *(uint4*)op       = make_uint4(p[0], p[1], p[2], p[3]);
        *(uint4*)(op + 8) = make_uint4(p[4], p[5], p[6], p[7]);
    }
}

// ---------------- pooling v2: uint2 row-quad layout, 4 rows/wave/iter ---------
// lane l: row group rg=l>>4 (4 rows concurrent), feature quad cq=l&15.
__global__ __launch_bounds__(512) void k_colsum(const unsigned short* __restrict__ h3,
                                                float* __restrict__ colsum) {
    int t = threadIdx.x;
    int lane = t & 63;
    int rg = lane >> 4, cq = lane & 15;
    int wid = (blockIdx.x * 512 + t) >> 6;
    int nw = (gridDim.x * 512) >> 6;
    float a0 = 0, a1 = 0, a2 = 0, a3 = 0;
    for (int r = wid * 4 + rg; r < NN; r += nw * 4) {
        uint2 v = *(const uint2*)(h3 + ((size_t)r << 6) + cq * 4);
        a0 += bfu((unsigned short)(v.x & 0xFFFF));
        a1 += bfu((unsigned short)(v.x >> 16));
        a2 += bfu((unsigned short)(v.y & 0xFFFF));
        a3 += bfu((unsigned short)(v.y >> 16));
    }
    a0 += __shfl_xor(a0, 16, 64); a0 += __shfl_xor(a0, 32, 64);
    a1 += __shfl_xor(a1, 16, 64); a1 += __shfl_xor(a1, 32, 64);
    a2 += __shfl_xor(a2, 16, 64); a2 += __shfl_xor(a2, 32, 64);
    a3 += __shfl_xor(a3, 16, 64); a3 += __shfl_xor(a3, 32, 64);
    __shared__ float part[8][64];
    int w = t >> 6;
    if (rg == 0) {
        part[w][cq * 4 + 0] = a0;
        part[w][cq * 4 + 1] = a1;
        part[w][cq * 4 + 2] = a2;
        part[w][cq * 4 + 3] = a3;
    }
    __syncthreads();
    if (t < 64) {
        float s = 0;
#pragma unroll
        for (int i = 0; i < 8; i++) s += part[i][t];
        atomicAdd(&colsum[t], s);
    }
}

__global__ void k_ctx(const float* __restrict__ colsum, const float* __restrict__ Wa,
                      float* __restrict__ ctx) {
    __shared__ float ms[64];
    int j = threadIdx.x;
    ms[j] = colsum[j] * (1.0f / NN);
    __syncthreads();
    float s = 0.0f;
#pragma unroll
    for (int k = 0; k < 64; k++) s += ms[k] * Wa[k * 64 + j];
    ctx[j] = tanhf(s);
}

__global__ __launch_bounds__(512) void k_pool(const unsigned short* __restrict__ h3,
                                              const float* __restrict__ ctx,
                                              float* __restrict__ pooled) {
    int t = threadIdx.x;
    int lane = t & 63;
    int rg = lane >> 4, cq = lane & 15;
    int wid = (blockIdx.x * 512 + t) >> 6;
    int nw = (gridDim.x * 512) >> 6;
    float c0 = ctx[cq * 4 + 0], c1 = ctx[cq * 4 + 1];
    float c2 = ctx[cq * 4 + 2], c3 = ctx[cq * 4 + 3];
    float q0 = 0, q1 = 0, q2 = 0, q3 = 0;
    for (int r = wid * 4 + rg; r < NN; r += nw * 4) {
        uint2 v = *(const uint2*)(h3 + ((size_t)r << 6) + cq * 4);
        float x0 = bfu((unsigned short)(v.x & 0xFFFF));
        float x1 = bfu((unsigned short)(v.x >> 16));
        float x2 = bfu((unsigned short)(v.y & 0xFFFF));
        float x3 = bfu((unsigned short)(v.y >> 16));
        float p = x0 * c0 + x1 * c1 + x2 * c2 + x3 * c3;
        p += __shfl_xor(p, 1, 64);
        p += __shfl_xor(p, 2, 64);
        p += __shfl_xor(p, 4, 64);
        p += __shfl_xor(p, 8, 64);
        float sc = 1.0f / (1.0f + expf(-p));
        q0 += sc * x0; q1 += sc * x1; q2 += sc * x2; q3 += sc * x3;
    }
    q0 += __shfl_xor(q0, 16, 64); q0 += __shfl_xor(q0, 32, 64);
    q1 += __shfl_xor(q1, 16, 64); q1 += __shfl_xor(q1, 32, 64);
    q2 += __shfl_xor(q2, 16, 64); q2 += __shfl_xor(q2, 32, 64);
    q3 += __shfl_xor(q3, 16, 64); q3 += __shfl_xor(q3, 32, 64);
    __shared__ float part[8][64];
    int w = t >> 6;
    if (rg == 0) {
        part[w][cq * 4 + 0] = q0;
        part[w][cq * 4 + 1] = q1;
        part[w][cq * 4 + 2] = q2;
        part[w][cq * 4 + 3] = q3;
    }
    __syncthreads();
    if (t < 64) {
        float s = 0;
#pragma unroll
        for (int i = 0; i < 8; i++) s += part[i][t];
        atomicAdd(&pooled[t], s);
    }
}

// ---------------- final output write (4 elems/thread) ----------------
__global__ void k_out(const unsigned short* __restrict__ h3, const float* __restrict__ pooled,
                      void* __restrict__ out, const int* __restrict__ flags) {
    int q = blockIdx.x * blockDim.x + threadIdx.x;   // quad index; 6400064/4 = 1600016
    if (q >= 1600016) return;
    long long i0 = (long long)q * 4;
    float v[4];
#pragma unroll
    for (int k = 0; k < 4; k++) {
        long long i = i0 + k;
        v[k] = (i < 6400000LL) ? bfu(h3[i]) : pooled[i - 6400000LL];
    }
    if (flags[0]) {
        *(float4*)((float*)out + i0) = make_float4(v[0], v[1], v[2], v[3]);
    } else {
        unsigned lo = (unsigned)__bfloat16_as_ushort(__float2bfloat16(v[0])) |
                      ((unsigned)__bfloat16_as_ushort(__float2bfloat16(v[1])) << 16);
        unsigned hi = (unsigned)__bfloat16_as_ushort(__float2bfloat16(v[2])) |
                      ((unsigned)__bfloat16_as_ushort(__float2bfloat16(v[3])) << 16);
        *(uint2*)((unsigned short*)out + i0) = make_uint2(lo, hi);
    }
}

// ---------------- workspace layout (~21.5 MB) ----------------
static constexpr size_t AL(size_t x) { return (x + 255) & ~size_t(255); }
static constexpr size_t OFF_FLAGS  = 0;
static constexpr size_t OFF_RAW    = OFF_FLAGS + 256;
static constexpr size_t OFF_GHIST  = OFF_RAW + 256;
static constexpr size_t OFF_OFFM   = OFF_GHIST + AL((size_t)NBLK * NB2 * 4);
static constexpr size_t OFF_CBASE  = OFF_OFFM + AL((size_t)NBLK * NB2 * 4);
static constexpr size_t OFF_ROWPTR = OFF_CBASE + AL((NB2 + 1) * 4);
static constexpr size_t OFF_CSR    = OFF_ROWPTR + AL((NN + 1) * 4);
static constexpr size_t OFF_DIS    = OFF_CSR + AL((size_t)NE * 4);
static constexpr size_t OFF_P      = OFF_DIS + AL(NN * 4);     // NR*128 fp8; also scatter scratch; also bf16 h3
static constexpr size_t OFF_W1B    = OFF_P + AL((size_t)NR * 128);
static constexpr size_t OFF_W2B    = OFF_W1B + AL(16384 * 2);
static constexpr size_t OFF_W3B    = OFF_W2B + AL(16384 * 2);
static constexpr size_t OFF_B1F    = OFF_W3B + AL(8192 * 2);
static constexpr size_t OFF_B2F    = OFF_B1F + AL(128 * 4);
static constexpr size_t OFF_B3F    = OFF_B2F + AL(128 * 4);
static constexpr size_t OFF_WAF    = OFF_B3F + AL(64 * 4);
static constexpr size_t OFF_COLSUM = OFF_WAF + AL(4096 * 4);
static constexpr size_t OFF_POOLED = OFF_COLSUM + AL(64 * 4);
static constexpr size_t OFF_CTX    = OFF_POOLED + AL(64 * 4);

extern "C" void kernel_launch(void* const* d_in, const int* in_sizes, int n_in,
                              void* d_out, int out_size, void* d_ws, size_t ws_size,
                              hipStream_t stream) {
    const int* ei = (const int*)d_in[0];
    const void* x  = d_in[1];
    const void* W1 = d_in[2];
    const void* b1 = d_in[3];
    const void* W2 = d_in[4];
    const void* b2 = d_in[5];
    const void* W3 = d_in[6];
    const void* b3 = d_in[7];
    const void* Wa = d_in[8];

    char* ws = (char*)d_ws;
    int*   flags  = (int*)(ws + OFF_FLAGS);
    int*   raw    = (int*)(ws + OFF_RAW);
    int*   ghist  = (int*)(ws + OFF_GHIST);
    int*   offm   = (int*)(ws + OFF_OFFM);
    int*   cbase  = (int*)(ws + OFF_CBASE);
    int*   rowptr = (int*)(ws + OFF_ROWPTR);
    int*   csr    = (int*)(ws + OFF_CSR);
    float* dis    = (float*)(ws + OFF_DIS);
    unsigned char*  P    = (unsigned char*)(ws + OFF_P);
    int*            scrA = (int*)(ws + OFF_P);
    unsigned short* Hb   = (unsigned short*)(ws + OFF_P);
    unsigned short* W1b = (unsigned short*)(ws + OFF_W1B);
    unsigned short* W2b = (unsigned short*)(ws + OFF_W2B);
    unsigned short* W3b = (unsigned short*)(ws + OFF_W3B);
    float* b1f    = (float*)(ws + OFF_B1F);
    float* b2f    = (float*)(ws + OFF_B2F);
    float* b3f    = (float*)(ws + OFF_B3F);
    float* Waf    = (float*)(ws + OFF_WAF);
    float* colsum = (float*)(ws + OFF_COLSUM);
    float* pooled = (float*)(ws + OFF_POOLED);
    float* ctx    = (float*)(ws + OFF_CTX);

    unsigned char* Q = (unsigned char*)d_out;   // d_out doubles as T-scratch (12.8 MB)

    hipMemsetAsync(raw, 0, 256, stream);
    hipMemsetAsync(colsum, 0, 64 * 4, stream);
    hipMemsetAsync(pooled, 0, 64 * 4, stream);

    k_probe1<<<256, 256, 0, stream>>>((const unsigned short*)x, ei, raw);
    k_probe2<<<1, 64, 0, stream>>>(raw, flags);
    cvt_params<<<64, 256, 0, stream>>>(W1, b1, W2, b2, W3, b3, Wa,
                                       W1b, W2b, W3b, b1f, b2f, b3f, Waf, flags);

    // atomic-free CSR build
    k_hist<<<NBLK, 256, 0, stream>>>(ei, ghist, flags);
    k_off<<<1, 256, 0, stream>>>(ghist, cbase, offm, rowptr);
    k_scatter<<<NBLK, 256, 0, stream>>>(ei, offm, scrA, flags);
    k_build<<<NB2, 256, 0, stream>>>(scrA, cbase, rowptr, dis, csr);

    // x -> fp8 P (overwrites scatter scratch)
    k_cvtx<<<(NN * 128 / 4 + 255) / 256, 256, 0, stream>>>(x, P, flags);

    // L1: T' = dis*(P@W1) (Q, MFMA) ; P = relu((sum+self)*dn + b1)
    k_xf_mfma<8><<<NR / 64, 256, 0, stream>>>(P, W1b, dis, Q);
    k_agg128<true><<<NN / 4, 256, 0, stream>>>(Q, rowptr, csr, dis, b1f, P);
    // L2
    k_xf_mfma<8><<<NR / 64, 256, 0, stream>>>(P, W2b, dis, Q);
    k_agg128<true><<<NN / 4, 256, 0, stream>>>(Q, rowptr, csr, dis, b2f, P);
    // L3: T3' = dis*(P@W3) (Q, 64 cols) ; Hb = (sum+self)*dn + b3 (bf16)
    k_xf_mfma<4><<<NR / 64, 256, 0, stream>>>(P, W3b, dis, Q);
    k_agg64<<<NN / 4, 256, 0, stream>>>(Q, rowptr, csr, dis, b3f, Hb);

    // attention pooling (v2)
    k_colsum<<<256, 512, 0, stream>>>(Hb, colsum);
    k_ctx<<<1, 64, 0, stream>>>(colsum, Waf, ctx);
    k_pool<<<256, 512, 0, stream>>>(Hb, ctx, pooled);

    // final output
    k_out<<<(1600016 + 255) / 256, 256, 0, stream>>>(Hb, pooled, d_out, flags);
}

// Round 4
// 416.178 us; speedup vs baseline: 1.1714x; 1.1714x over previous
//
#include <hip/hip_runtime.h>
#include <hip/hip_bf16.h>

#define NN 100000
#define NE 1600000
#define NR 100032            // NN rounded to 64-row blocks (table alloc rows)
#define NB2 196              // coarse buckets = ceil(NN/512)
#define NBLK 391             // hist/scatter blocks = ceil(NE/4096)
#define EPB 4096             // edges per hist/scatter block

#if defined(__has_builtin)
#  if __has_builtin(__builtin_amdgcn_cvt_pk_f32_fp8) && \
      __has_builtin(__builtin_amdgcn_cvt_pk_fp8_f32) && \
      __has_builtin(__builtin_amdgcn_cvt_f32_fp8)
#    define HWF8 1
#  endif
#endif

typedef float f32x2 __attribute__((ext_vector_type(2)));
typedef float f32x4 __attribute__((ext_vector_type(4)));
typedef short bf16x8 __attribute__((ext_vector_type(8)));

static __device__ __forceinline__ float bf2f(__hip_bfloat16 v) { return __bfloat162float(v); }
static __device__ __forceinline__ float bfu(unsigned short w) {
    return __uint_as_float((unsigned)w << 16);
}

// ---------------- fp8 e4m3 software codec (fallback, validated r3/r4) ---------
static __device__ __forceinline__ float f8d_sw(unsigned b) {
    unsigned e = (b >> 3) & 15u, m = b & 7u;
    float mag;
    if (e == 0) mag = (float)m * 0.001953125f;
    else        mag = __uint_as_float(((e + 120u) << 23) | (m << 20));
    return (b & 0x80u) ? -mag : mag;
}
static __device__ __forceinline__ unsigned char f8e_sw(float x) {
    unsigned u = __float_as_uint(x);
    unsigned s = (u >> 31) << 7;
    unsigned au = u & 0x7fffffffu;
    if (au >= 0x43E00000u) return (unsigned char)(s | 0x7Eu);
    if (au <  0x3A800000u) return (unsigned char)s;
    if (au <  0x3C800000u) {
        float a = __uint_as_float(au);
        int m = (int)rintf(a * 512.0f);
        if (m >= 8) return (unsigned char)(s | 0x08u);
        return (unsigned char)(s | (unsigned)m);
    }
    au += 0x80000u;
    if (au >= 0x43E00000u) return (unsigned char)(s | 0x7Eu);
    unsigned e = (au >> 23) - 120u;
    unsigned m = (au >> 20) & 7u;
    return (unsigned char)(s | (e << 3) | m);
}

// ---------------- fp8 helpers (HW if available) ----------------
static __device__ __forceinline__ float f8d1(unsigned b) {
#ifdef HWF8
    return __builtin_amdgcn_cvt_f32_fp8((int)b, 0);
#else
    return f8d_sw(b);
#endif
}
static __device__ __forceinline__ void f8d2(unsigned short v, float& x0, float& x1) {
#ifdef HWF8
    f32x2 r = __builtin_amdgcn_cvt_pk_f32_fp8((int)(unsigned)v, false);
    x0 = r.x; x1 = r.y;
#else
    x0 = f8d_sw(v & 255u); x1 = f8d_sw(v >> 8);
#endif
}
static __device__ __forceinline__ void f8d4(unsigned u, float* o) {
#ifdef HWF8
    f32x2 lo = __builtin_amdgcn_cvt_pk_f32_fp8((int)u, false);
    f32x2 hi = __builtin_amdgcn_cvt_pk_f32_fp8((int)u, true);
    o[0] = lo.x; o[1] = lo.y; o[2] = hi.x; o[3] = hi.y;
#else
    o[0] = f8d_sw(u & 255u); o[1] = f8d_sw((u >> 8) & 255u);
    o[2] = f8d_sw((u >> 16) & 255u); o[3] = f8d_sw(u >> 24);
#endif
}
static __device__ __forceinline__ unsigned short f8e2(float a, float b) {
#ifdef HWF8
    float ca = fminf(fmaxf(a, -448.0f), 448.0f);
    float cb = fminf(fmaxf(b, -448.0f), 448.0f);
    int p = __builtin_amdgcn_cvt_pk_fp8_f32(ca, cb, 0, false);
    return (unsigned short)(p & 0xFFFF);
#else
    return (unsigned short)f8e_sw(a) | ((unsigned short)f8e_sw(b) << 8);
#endif
}
static __device__ __forceinline__ unsigned char f8e1(float a) {
    return (unsigned char)(f8e2(a, 0.0f) & 0xFF);
}
// f32 -> bf16 bits by truncation (EXACT for values that came from fp8 e4m3)
static __device__ __forceinline__ unsigned bfpack(float lo, float hi) {
    return (__float_as_uint(lo) >> 16) | (__float_as_uint(hi) & 0xFFFF0000u);
}

// decode 8 fp8 (uint2) and accumulate UNWEIGHTED into 4 f32x2 (v_pk_add_f32)
static __device__ __forceinline__ void acc8_add(f32x2* acc, uint2 v) {
#ifdef HWF8
    acc[0] += __builtin_amdgcn_cvt_pk_f32_fp8((int)v.x, false);
    acc[1] += __builtin_amdgcn_cvt_pk_f32_fp8((int)v.x, true);
    acc[2] += __builtin_amdgcn_cvt_pk_f32_fp8((int)v.y, false);
    acc[3] += __builtin_amdgcn_cvt_pk_f32_fp8((int)v.y, true);
#else
    unsigned u[2] = {v.x, v.y};
#pragma unroll
    for (int q = 0; q < 2; q++) {
        float o[4]; f8d4(u[q], o);
        acc[2 * q]     += (f32x2){o[0], o[1]};
        acc[2 * q + 1] += (f32x2){o[2], o[3]};
    }
#endif
}
// decode 8 fp8 (uint2) and fma with scalar weight into 4 f32x2
static __device__ __forceinline__ void acc8_fma(f32x2* acc, uint2 v, float w) {
    f32x2 wv = (f32x2){w, w};
#ifdef HWF8
    acc[0] += __builtin_amdgcn_cvt_pk_f32_fp8((int)v.x, false) * wv;
    acc[1] += __builtin_amdgcn_cvt_pk_f32_fp8((int)v.x, true)  * wv;
    acc[2] += __builtin_amdgcn_cvt_pk_f32_fp8((int)v.y, false) * wv;
    acc[3] += __builtin_amdgcn_cvt_pk_f32_fp8((int)v.y, true)  * wv;
#else
    unsigned u[2] = {v.x, v.y};
#pragma unroll
    for (int q = 0; q < 2; q++) {
        float o[4]; f8d4(u[q], o);
        acc[2 * q]     += (f32x2){o[0] * w, o[1] * w};
        acc[2 * q + 1] += (f32x2){o[2] * w, o[3] * w};
    }
#endif
}

// ---------------- dtype probes (parallel) ----------------
__global__ void k_probe1(const unsigned short* __restrict__ xw,
                         const int* __restrict__ ei, int* __restrict__ raw) {
    int i = blockIdx.x * 256 + threadIdx.x;    // 65536 probes
    int nan = ((xw[i] & 0x7F80u) == 0x7F80u) ? 1 : 0;
    int odd = (ei[2 * i + 1] != 0) ? 1 : 0;
    unsigned long long bn = __ballot(nan);
    unsigned long long bo = __ballot(odd);
    if ((threadIdx.x & 63) == 0) {
        if (bn) atomicAdd(&raw[0], __popcll(bn));
        if (bo) atomicAdd(&raw[1], __popcll(bo));
    }
}
__global__ void k_probe2(const int* __restrict__ raw, int* __restrict__ flags) {
    if (threadIdx.x == 0) {
        flags[0] = (raw[0] > 0) ? 1 : 0;   // x/weights are f32
        flags[1] = (raw[1] == 0) ? 1 : 0;  // edge_index is int64
    }
}

static __device__ __forceinline__ int e_src(const int* ei, int e, int f64) {
    int v = f64 ? ei[2 * e] : ei[e];
    return min(max(v, 0), NN - 1);
}
static __device__ __forceinline__ int e_dst(const int* ei, int e, int f64) {
    int v = f64 ? ei[2 * (NE + e)] : ei[NE + e];
    return min(max(v, 0), NN - 1);
}
static __device__ __forceinline__ float ldx(const void* p, long long i, int f32) {
    return f32 ? ((const float*)p)[i] : bf2f(((const __hip_bfloat16*)p)[i]);
}

// ------------- parameter conversion: W -> bf16 in MFMA-frag order -------------
__global__ void cvt_params(const void* W1, const void* b1, const void* W2, const void* b2,
                           const void* W3, const void* b3, const void* Wa,
                           unsigned short* W1b, unsigned short* W2b, unsigned short* W3b,
                           float* b1f, float* b2f, float* b3f, float* Waf,
                           const int* flags) {
    int i = blockIdx.x * blockDim.x + threadIdx.x;
    int f = flags[0];
    if (i < 16384) {
        int j = i & 7, l = (i >> 3) & 63, c = (i >> 9) & 7, kc = i >> 12;
        int k = kc * 32 + ((l >> 4)) * 8 + j;
        int col = c * 16 + (l & 15);
        W1b[i] = __bfloat16_as_ushort(__float2bfloat16(ldx(W1, k * 128 + col, f)));
        W2b[i] = __bfloat16_as_ushort(__float2bfloat16(ldx(W2, k * 128 + col, f)));
    }
    if (i < 8192) {
        int j = i & 7, l = (i >> 3) & 63, c = (i >> 9) & 3, kc = i >> 11;
        int k = kc * 32 + ((l >> 4)) * 8 + j;
        int col = c * 16 + (l & 15);
        W3b[i] = __bfloat16_as_ushort(__float2bfloat16(ldx(W3, k * 64 + col, f)));
    }
    if (i < 4096)  Waf[i] = ldx(Wa, i, f);
    if (i < 128)   { b1f[i] = ldx(b1, i, f); b2f[i] = ldx(b2, i, f); }
    if (i < 64)    b3f[i] = ldx(b3, i, f);
}

// ---------------- x -> fp8 table P ----------------
__global__ void k_cvtx(const void* __restrict__ x, unsigned char* __restrict__ P,
                       const int* __restrict__ flags) {
    int i = blockIdx.x * blockDim.x + threadIdx.x;
    if (i >= (NN * 128) / 4) return;
    unsigned pk;
    if (flags[0]) {
        float4 v = ((const float4*)x)[i];
        pk = (unsigned)f8e2(v.x, v.y) | ((unsigned)f8e2(v.z, v.w) << 16);
    } else {
        ushort4 v = ((const ushort4*)x)[i];
        pk = (unsigned)f8e2(bfu(v.x), bfu(v.y)) | ((unsigned)f8e2(bfu(v.z), bfu(v.w)) << 16);
    }
    ((unsigned*)P)[i] = pk;
}

// ======== CSR build: atomic-free multisplit (validated r7) ========
__global__ __launch_bounds__(256) void k_hist(const int* __restrict__ ei,
                                              int* __restrict__ ghist,
                                              const int* __restrict__ flags) {
    __shared__ int h[NB2];
    int blk = blockIdx.x, t = threadIdx.x;
    for (int i = t; i < NB2; i += 256) h[i] = 0;
    __syncthreads();
    int f64 = flags[1];
    int e0 = blk * EPB;
    for (int i = t; i < EPB; i += 256) {
        int e = e0 + i;
        if (e < NE) atomicAdd(&h[e_dst(ei, e, f64) >> 9], 1);
    }
    __syncthreads();
    for (int i = t; i < NB2; i += 256) ghist[blk * NB2 + i] = h[i];
}

__global__ __launch_bounds__(256) void k_off(const int* __restrict__ ghist,
                                             int* __restrict__ cbase,
                                             int* __restrict__ offm,
                                             int* __restrict__ rowptr) {
    __shared__ int tot[NB2];
    int t = threadIdx.x;
    if (t < NB2) {
        int s = 0;
        for (int blk = 0; blk < NBLK; blk++) s += ghist[blk * NB2 + t];
        tot[t] = s;
    }
    __syncthreads();
    if (t == 0) {
        int run = 0;
        for (int b = 0; b < NB2; b++) { cbase[b] = run; run += tot[b]; }
        cbase[NB2] = run;
        rowptr[NN] = run;   // == NE
    }
    __syncthreads();
    if (t < NB2) {
        int run = cbase[t];
        for (int blk = 0; blk < NBLK; blk++) {
            offm[blk * NB2 + t] = run;
            run += ghist[blk * NB2 + t];
        }
    }
}

__global__ __launch_bounds__(256) void k_scatter(const int* __restrict__ ei,
                                                 const int* __restrict__ offm,
                                                 int* __restrict__ scratch,
                                                 const int* __restrict__ flags) {
    __shared__ int cur[NB2];
    int blk = blockIdx.x, t = threadIdx.x;
    for (int i = t; i < NB2; i += 256) cur[i] = offm[blk * NB2 + i];
    __syncthreads();
    int f64 = flags[1];
    int e0 = blk * EPB;
    for (int i = t; i < EPB; i += 256) {
        int e = e0 + i;
        if (e < NE) {
            int d = e_dst(ei, e, f64);
            int s = e_src(ei, e, f64);
            int p = atomicAdd(&cur[d >> 9], 1);
            p = min(max(p, 0), NE - 1);
            scratch[p] = s | ((d & 511) << 17);
        }
    }
}

__global__ __launch_bounds__(256) void k_build(const int* __restrict__ scratch,
                                               const int* __restrict__ cbase,
                                               int* __restrict__ rowptr,
                                               float* __restrict__ dis,
                                               int* __restrict__ csr) {
    __shared__ int hist[512];
    __shared__ int base[512];
    __shared__ int sd[256];
    int b = blockIdx.x, t = threadIdx.x;
    int n0 = b << 9;
    int s0 = cbase[b], s1 = cbase[b + 1];
    hist[t] = 0; hist[t + 256] = 0;
    __syncthreads();
    for (int i = s0 + t; i < s1; i += 256) {
        int dlo = (scratch[i] >> 17) & 511;
        atomicAdd(&hist[dlo], 1);
    }
    __syncthreads();
    int v0 = hist[2 * t], v1 = hist[2 * t + 1];
    int s = v0 + v1;
    sd[t] = s; __syncthreads();
    for (int o = 1; o < 256; o <<= 1) {
        int add = (t >= o) ? sd[t - o] : 0;
        __syncthreads();
        sd[t] += add;
        __syncthreads();
    }
    int run = s0 + sd[t] - s;
    base[2 * t] = run;
    base[2 * t + 1] = run + v0;
    int n = n0 + 2 * t;
    if (n < NN) {
        rowptr[n] = run;
        dis[n] = rsqrtf((float)v0 + 1.0f);
    }
    if (n + 1 < NN) {
        rowptr[n + 1] = run + v0;
        dis[n + 1] = rsqrtf((float)v1 + 1.0f);
    }
    __syncthreads();
    for (int i = s0 + t; i < s1; i += 256) {
        int v = scratch[i];
        int dlo = (v >> 17) & 511;
        int p = atomicAdd(&base[dlo], 1);
        p = min(max(p, 0), NE - 1);
        csr[p] = v & 0x1FFFF;
    }
}

// ------------- MFMA GEMM: O[NNxCOLS] = dis[row] * (A(fp8,128) @ W) ------------
// Pre-scales each output row by dis[row] so aggregation is an unweighted sum.
// Row NN is written as zeros (pad row gathered by invalid edge slots).
template <int NCT>    // NCT = COLS/16 (8 or 4)
__global__ __launch_bounds__(256) void k_xf_mfma(const unsigned char* __restrict__ A,
                                                 const unsigned short* __restrict__ Wf,
                                                 const float* __restrict__ dis,
                                                 unsigned char* __restrict__ O) {
    __shared__ unsigned short wl[NCT * 4 * 64 * 8];
    int t = threadIdx.x;
    int n0 = blockIdx.x * 64;
    {
        const uint4* wg = (const uint4*)Wf;
        uint4* wld = (uint4*)wl;
#pragma unroll
        for (int i = 0; i < NCT; i++) wld[i * 256 + t] = wg[i * 256 + t];
    }
    __syncthreads();
    int w = t >> 6, l = t & 63;
    int quad = l >> 4, m = l & 15;
    int arow = n0 + w * 16 + m;
    const unsigned char* ap = A + (size_t)arow * 128 + quad * 8;
    f32x4 acc[NCT];
#pragma unroll
    for (int c = 0; c < NCT; c++) acc[c] = (f32x4){0.0f, 0.0f, 0.0f, 0.0f};
#pragma unroll
    for (int kc = 0; kc < 4; kc++) {
        uint2 g = *(const uint2*)(ap + kc * 32);
        float o[8];
        f8d4(g.x, o); f8d4(g.y, o + 4);
        union { unsigned u[4]; bf16x8 v; } fr;
        fr.u[0] = bfpack(o[0], o[1]);
        fr.u[1] = bfpack(o[2], o[3]);
        fr.u[2] = bfpack(o[4], o[5]);
        fr.u[3] = bfpack(o[6], o[7]);
#pragma unroll
        for (int c = 0; c < NCT; c++) {
            bf16x8 bw = *(const bf16x8*)&wl[((kc * NCT + c) * 64 + l) * 8];
            acc[c] = __builtin_amdgcn_mfma_f32_16x16x32_bf16(fr.v, bw, acc[c], 0, 0, 0);
        }
    }
    int orow0 = n0 + w * 16 + quad * 4;
    float dsc[4];
#pragma unroll
    for (int r = 0; r < 4; r++) {
        int row = orow0 + r;
        dsc[r] = (row < NN) ? dis[row] : 0.0f;     // row==NN -> store zeros
    }
#pragma unroll
    for (int c = 0; c < NCT; c++) {
        int col = c * 16 + m;
#pragma unroll
        for (int r = 0; r < 4; r++) {
            int row = orow0 + r;
            if (row <= NN) O[(size_t)row * (NCT * 16) + col] = f8e1(acc[c][r] * dsc[r]);
        }
    }
}

// ---- agg, F=128: H = relu?((sum T'[src] + T'[n]) * dn + b), fp8->fp8 --------
// v4: 1 node/wave, 4 slots x 16 lanes x 8B. Reduce = 2 shfl levels x 8 regs.
// slot r = lane>>4, f = lane&15 (features 8f..8f+7). Pair loop + single tail
// (no forced pad pair). Invalid lanes in a gather read zero row NN.
template <bool RELU>
__global__ __launch_bounds__(256) void k_agg128(const unsigned char* __restrict__ Tb,
                                                const int* __restrict__ rowptr,
                                                const int* __restrict__ csr,
                                                const float* __restrict__ dis,
                                                const float* __restrict__ bias,
                                                unsigned char* __restrict__ H) {
    int n = blockIdx.x * 4 + (threadIdx.x >> 6);
    int lane = threadIdx.x & 63;
    int r = lane >> 4;            // slot 0..3
    int f = lane & 15;            // feature group: bytes 8f..8f+7
    int fo = f << 3;
    float dn = dis[n];
    int s0 = rowptr[n], s1 = rowptr[n + 1];
    s0 = min(max(s0, 0), NE); s1 = min(max(s1, s0), NE);
    f32x2 acc[4];
#pragma unroll
    for (int k = 0; k < 4; k++) acc[k] = (f32x2){0.0f, 0.0f};
    {   // self term: T'[n] with weight 1.0 on slot 0 (dis already folded in)
        uint2 v = *(const uint2*)(Tb + (((unsigned)n << 7) + (unsigned)fo));
        acc8_fma(acc, v, (r == 0) ? 1.0f : 0.0f);
    }
    for (int base = s0; base < s1; base += 64) {
        int m = min(64, s1 - base);
        unsigned voff = (unsigned)NN << 7;      // pad -> zero row
        if (lane < m) {
            int ss = csr[base + lane];
            ss = min(max(ss, 0), NN - 1);
            voff = (unsigned)ss << 7;
        }
        int ng = (m + 3) >> 2;                  // groups of 4 edges
        int g = 0;
        for (; g + 2 <= ng; g += 2) {
            int a0 = (g * 4 + r) * 4;
            unsigned vo0 = (unsigned)__builtin_amdgcn_ds_bpermute(a0,      (int)voff);
            unsigned vo1 = (unsigned)__builtin_amdgcn_ds_bpermute(a0 + 16, (int)voff);
            uint2 v0 = *(const uint2*)(Tb + (vo0 + (unsigned)fo));
            uint2 v1 = *(const uint2*)(Tb + (vo1 + (unsigned)fo));
            acc8_add(acc, v0);
            acc8_add(acc, v1);
        }
        if (g < ng) {
            int a0 = (g * 4 + r) * 4;
            unsigned vo0 = (unsigned)__builtin_amdgcn_ds_bpermute(a0, (int)voff);
            uint2 v0 = *(const uint2*)(Tb + (vo0 + (unsigned)fo));
            acc8_add(acc, v0);
        }
    }
    // reduce across the 4 slots (lane strides 16, 32): 16 ds ops total
#pragma unroll
    for (int k = 0; k < 4; k++) {
        acc[k].x += __shfl_xor(acc[k].x, 16, 64);
        acc[k].y += __shfl_xor(acc[k].y, 16, 64);
        acc[k].x += __shfl_xor(acc[k].x, 32, 64);
        acc[k].y += __shfl_xor(acc[k].y, 32, 64);
    }
    if (r == 0) {
        float4 bA = *(const float4*)(bias + fo);
        float4 bB = *(const float4*)(bias + fo + 4);
        float t[8];
        t[0] = acc[0].x * dn + bA.x; t[1] = acc[0].y * dn + bA.y;
        t[2] = acc[1].x * dn + bA.z; t[3] = acc[1].y * dn + bA.w;
        t[4] = acc[2].x * dn + bB.x; t[5] = acc[2].y * dn + bB.y;
        t[6] = acc[3].x * dn + bB.z; t[7] = acc[3].y * dn + bB.w;
        if (RELU) {
#pragma unroll
            for (int k = 0; k < 8; k++) t[k] = fmaxf(t[k], 0.0f);
        }
        unsigned lo = (unsigned)f8e2(t[0], t[1]) | ((unsigned)f8e2(t[2], t[3]) << 16);
        unsigned hi = (unsigned)f8e2(t[4], t[5]) | ((unsigned)f8e2(t[6], t[7]) << 16);
        *(uint2*)(H + (((size_t)n << 7) + (size_t)fo)) = make_uint2(lo, hi);
    }
}

// ---- agg, F=64 final: h3 = (sum T3'[src] + T3'[n]) * dn + b3 -> bf16 --------
// v4: 2 nodes/wave (32 lanes each), 4 slots x 8 lanes x 8B. Reduce = 2 shfl
// levels (strides 8,16 — shared instruction covers both halves) = 8 ds/node.
__global__ __launch_bounds__(256) void k_agg64(const unsigned char* __restrict__ Tb,
                                               const int* __restrict__ rowptr,
                                               const int* __restrict__ csr,
                                               const float* __restrict__ dis,
                                               const float* __restrict__ bias,
                                               unsigned short* __restrict__ Hb) {
    int lane = threadIdx.x & 63;
    int half = lane >> 5;
    int hl = lane & 31;
    int n = blockIdx.x * 8 + (threadIdx.x >> 6) * 2 + half;
    int r = hl >> 3;              // slot 0..3
    int f = hl & 7;               // feature group: bytes 8f..8f+7
    int fo = f << 3;
    float dn = dis[n];
    int s0 = rowptr[n], s1 = rowptr[n + 1];
    s0 = min(max(s0, 0), NE); s1 = min(max(s1, s0), NE);
    f32x2 acc[4];
#pragma unroll
    for (int k = 0; k < 4; k++) acc[k] = (f32x2){0.0f, 0.0f};
    {   // self term: weight 1.0 (dis folded into T3')
        uint2 v = *(const uint2*)(Tb + (((unsigned)n << 6) + (unsigned)fo));
        acc8_fma(acc, v, (r == 0) ? 1.0f : 0.0f);
    }
    int ab = half << 7;           // bpermute byte base of own half (32 lanes * 4B)
    for (int base = s0; base < s1; base += 32) {
        int m = min(32, s1 - base);
        unsigned voff = (unsigned)NN << 6;      // pad -> zero row
        if (hl < m) {
            int ss = csr[base + hl];
            ss = min(max(ss, 0), NN - 1);
            voff = (unsigned)ss << 6;
        }
        int ng = (m + 3) >> 2;                  // groups of 4 edges
        int g = 0;
        for (; g + 2 <= ng; g += 2) {
            int a0 = ab + (g * 4 + r) * 4;
            unsigned vo0 = (unsigned)__builtin_amdgcn_ds_bpermute(a0,      (int)voff);
            unsigned vo1 = (unsigned)__builtin_amdgcn_ds_bpermute(a0 + 16, (int)voff);
            uint2 v0 = *(const uint2*)(Tb + (vo0 + (unsigned)fo));
            uint2 v1 = *(const uint2*)(Tb + (vo1 + (unsigned)fo));
            acc8_add(acc, v0);
            acc8_add(acc, v1);
        }
        if (g < ng) {
            int a0 = ab + (g * 4 + r) * 4;
            unsigned vo0 = (unsigned)__builtin_amdgcn_ds_bpermute(a0, (int)voff);
            uint2 v0 = *(const uint2*)(Tb + (vo0 + (unsigned)fo));
            acc8_add(acc, v0);
        }
    }
    // reduce across the 4 slots (lane strides 8, 16; stays within each half)
#pragma unroll
    for (int k = 0; k < 4; k++) {
        acc[k].x += __shfl_xor(acc[k].x, 8, 64);
        acc[k].y += __shfl_xor(acc[k].y, 8, 64);
        acc[k].x += __shfl_xor(acc[k].x, 16, 64);
        acc[k].y += __shfl_xor(acc[k].y, 16, 64);
    }
    if (r == 0) {
        float4 bA = *(const float4*)(bias + fo);
        float4 bB = *(const float4*)(bias + fo + 4);
        float t[8];
        t[0] = acc[0].x * dn + bA.x; t[1] = acc[0].y * dn + bA.y;
        t[2] = acc[1].x * dn + bA.z; t[3] = acc[1].y * dn + bA.w;
        t[4] = acc[2].x * dn + bB.x; t[5] = acc[2].y * dn + bB.y;
        t[6] = acc[3].x * dn + bB.z; t[7] = acc[3].y * dn + bB.w;
        unsigned p0 = (unsigned)__bfloat16_as_ushort(__float2bfloat16(t[0])) |
                      ((unsigned)__bfloat16_as_ushort(__float2bfloat16(t[1])) << 16);
        unsigned p1 = (unsigned)__bfloat16_as_ushort(__float2bfloat16(t[2])) |
                      ((unsigned)__bfloat16_as_ushort(__float2bfloat16(t[3])) << 16);
        unsigned p2 = (unsigned)__bfloat16_as_ushort(__float2bfloat16(t[4])) |
                      ((unsigned)__bfloat16_as_ushort(__float2bfloat16(t[5])) << 16);
        unsigned p3 = (unsigned)__bfloat16_as_ushort(__float2bfloat16(t[6])) |
                      ((unsigned)__bfloat16_as_ushort(__float2bfloat16(t[7])) << 16);
        *(uint4*)(Hb + (((size_t)n << 6) + (size_t)fo)) = make_uint4(p0, p1, p2, p3);
    }
}

// ---------------- pooling v2: uint2 row-quad layout, 4 rows/wave/iter ---------
// lane l: row group rg=l>>4 (4 rows concurrent), feature quad cq=l&15.
__global__ __launch_bounds__(512) void k_colsum(const unsigned short* __restrict__ h3,
                                                float* __restrict__ colsum) {
    int t = threadIdx.x;
    int lane = t & 63;
    int rg = lane >> 4, cq = lane & 15;
    int wid = (blockIdx.x * 512 + t) >> 6;
    int nw = (gridDim.x * 512) >> 6;
    float a0 = 0, a1 = 0, a2 = 0, a3 = 0;
    for (int r = wid * 4 + rg; r < NN; r += nw * 4) {
        uint2 v = *(const uint2*)(h3 + ((size_t)r << 6) + cq * 4);
        a0 += bfu((unsigned short)(v.x & 0xFFFF));
        a1 += bfu((unsigned short)(v.x >> 16));
        a2 += bfu((unsigned short)(v.y & 0xFFFF));
        a3 += bfu((unsigned short)(v.y >> 16));
    }
    a0 += __shfl_xor(a0, 16, 64); a0 += __shfl_xor(a0, 32, 64);
    a1 += __shfl_xor(a1, 16, 64); a1 += __shfl_xor(a1, 32, 64);
    a2 += __shfl_xor(a2, 16, 64); a2 += __shfl_xor(a2, 32, 64);
    a3 += __shfl_xor(a3, 16, 64); a3 += __shfl_xor(a3, 32, 64);
    __shared__ float part[8][64];
    int w = t >> 6;
    if (rg == 0) {
        part[w][cq * 4 + 0] = a0;
        part[w][cq * 4 + 1] = a1;
        part[w][cq * 4 + 2] = a2;
        part[w][cq * 4 + 3] = a3;
    }
    __syncthreads();
    if (t < 64) {
        float s = 0;
#pragma unroll
        for (int i = 0; i < 8; i++) s += part[i][t];
        atomicAdd(&colsum[t], s);
    }
}

__global__ void k_ctx(const float* __restrict__ colsum, const float* __restrict__ Wa,
                      float* __restrict__ ctx) {
    __shared__ float ms[64];
    int j = threadIdx.x;
    ms[j] = colsum[j] * (1.0f / NN);
    __syncthreads();
    float s = 0.0f;
#pragma unroll
    for (int k = 0; k < 64; k++) s += ms[k] * Wa[k * 64 + j];
    ctx[j] = tanhf(s);
}

__global__ __launch_bounds__(512) void k_pool(const unsigned short* __restrict__ h3,
                                              const float* __restrict__ ctx,
                                              float* __restrict__ pooled) {
    int t = threadIdx.x;
    int lane = t & 63;
    int rg = lane >> 4, cq = lane & 15;
    int wid = (blockIdx.x * 512 + t) >> 6;
    int nw = (gridDim.x * 512) >> 6;
    float c0 = ctx[cq * 4 + 0], c1 = ctx[cq * 4 + 1];
    float c2 = ctx[cq * 4 + 2], c3 = ctx[cq * 4 + 3];
    float q0 = 0, q1 = 0, q2 = 0, q3 = 0;
    for (int r = wid * 4 + rg; r < NN; r += nw * 4) {
        uint2 v = *(const uint2*)(h3 + ((size_t)r << 6) + cq * 4);
        float x0 = bfu((unsigned short)(v.x & 0xFFFF));
        float x1 = bfu((unsigned short)(v.x >> 16));
        float x2 = bfu((unsigned short)(v.y & 0xFFFF));
        float x3 = bfu((unsigned short)(v.y >> 16));
        float p = x0 * c0 + x1 * c1 + x2 * c2 + x3 * c3;
        p += __shfl_xor(p, 1, 64);
        p += __shfl_xor(p, 2, 64);
        p += __shfl_xor(p, 4, 64);
        p += __shfl_xor(p, 8, 64);
        float sc = 1.0f / (1.0f + expf(-p));
        q0 += sc * x0; q1 += sc * x1; q2 += sc * x2; q3 += sc * x3;
    }
    q0 += __shfl_xor(q0, 16, 64); q0 += __shfl_xor(q0, 32, 64);
    q1 += __shfl_xor(q1, 16, 64); q1 += __shfl_xor(q1, 32, 64);
    q2 += __shfl_xor(q2, 16, 64); q2 += __shfl_xor(q2, 32, 64);
    q3 += __shfl_xor(q3, 16, 64); q3 += __shfl_xor(q3, 32, 64);
    __shared__ float part[8][64];
    int w = t >> 6;
    if (rg == 0) {
        part[w][cq * 4 + 0] = q0;
        part[w][cq * 4 + 1] = q1;
        part[w][cq * 4 + 2] = q2;
        part[w][cq * 4 + 3] = q3;
    }
    __syncthreads();
    if (t < 64) {
        float s = 0;
#pragma unroll
        for (int i = 0; i < 8; i++) s += part[i][t];
        atomicAdd(&pooled[t], s);
    }
}

// ---------------- final output write (4 elems/thread) ----------------
__global__ void k_out(const unsigned short* __restrict__ h3, const float* __restrict__ pooled,
                      void* __restrict__ out, const int* __restrict__ flags) {
    int q = blockIdx.x * blockDim.x + threadIdx.x;   // quad index; 6400064/4 = 1600016
    if (q >= 1600016) return;
    long long i0 = (long long)q * 4;
    float v[4];
#pragma unroll
    for (int k = 0; k < 4; k++) {
        long long i = i0 + k;
        v[k] = (i < 6400000LL) ? bfu(h3[i]) : pooled[i - 6400000LL];
    }
    if (flags[0]) {
        *(float4*)((float*)out + i0) = make_float4(v[0], v[1], v[2], v[3]);
    } else {
        unsigned lo = (unsigned)__bfloat16_as_ushort(__float2bfloat16(v[0])) |
                      ((unsigned)__bfloat16_as_ushort(__float2bfloat16(v[1])) << 16);
        unsigned hi = (unsigned)__bfloat16_as_ushort(__float2bfloat16(v[2])) |
                      ((unsigned)__bfloat16_as_ushort(__float2bfloat16(v[3])) << 16);
        *(uint2*)((unsigned short*)out + i0) = make_uint2(lo, hi);
    }
}

// ---------------- workspace layout (~21.5 MB) ----------------
static constexpr size_t AL(size_t x) { return (x + 255) & ~size_t(255); }
static constexpr size_t OFF_FLAGS  = 0;
static constexpr size_t OFF_RAW    = OFF_FLAGS + 256;
static constexpr size_t OFF_GHIST  = OFF_RAW + 256;
static constexpr size_t OFF_OFFM   = OFF_GHIST + AL((size_t)NBLK * NB2 * 4);
static constexpr size_t OFF_CBASE  = OFF_OFFM + AL((size_t)NBLK * NB2 * 4);
static constexpr size_t OFF_ROWPTR = OFF_CBASE + AL((NB2 + 1) * 4);
static constexpr size_t OFF_CSR    = OFF_ROWPTR + AL((NN + 1) * 4);
static constexpr size_t OFF_DIS    = OFF_CSR + AL((size_t)NE * 4);
static constexpr size_t OFF_P      = OFF_DIS + AL(NN * 4);     // NR*128 fp8; also scatter scratch; also bf16 h3
static constexpr size_t OFF_W1B    = OFF_P + AL((size_t)NR * 128);
static constexpr size_t OFF_W2B    = OFF_W1B + AL(16384 * 2);
static constexpr size_t OFF_W3B    = OFF_W2B + AL(16384 * 2);
static constexpr size_t OFF_B1F    = OFF_W3B + AL(8192 * 2);
static constexpr size_t OFF_B2F    = OFF_B1F + AL(128 * 4);
static constexpr size_t OFF_B3F    = OFF_B2F + AL(128 * 4);
static constexpr size_t OFF_WAF    = OFF_B3F + AL(64 * 4);
static constexpr size_t OFF_COLSUM = OFF_WAF + AL(4096 * 4);
static constexpr size_t OFF_POOLED = OFF_COLSUM + AL(64 * 4);
static constexpr size_t OFF_CTX    = OFF_POOLED + AL(64 * 4);

extern "C" void kernel_launch(void* const* d_in, const int* in_sizes, int n_in,
                              void* d_out, int out_size, void* d_ws, size_t ws_size,
                              hipStream_t stream) {
    const int* ei = (const int*)d_in[0];
    const void* x  = d_in[1];
    const void* W1 = d_in[2];
    const void* b1 = d_in[3];
    const void* W2 = d_in[4];
    const void* b2 = d_in[5];
    const void* W3 = d_in[6];
    const void* b3 = d_in[7];
    const void* Wa = d_in[8];

    char* ws = (char*)d_ws;
    int*   flags  = (int*)(ws + OFF_FLAGS);
    int*   raw    = (int*)(ws + OFF_RAW);
    int*   ghist  = (int*)(ws + OFF_GHIST);
    int*   offm   = (int*)(ws + OFF_OFFM);
    int*   cbase  = (int*)(ws + OFF_CBASE);
    int*   rowptr = (int*)(ws + OFF_ROWPTR);
    int*   csr    = (int*)(ws + OFF_CSR);
    float* dis    = (float*)(ws + OFF_DIS);
    unsigned char*  P    = (unsigned char*)(ws + OFF_P);
    int*            scrA = (int*)(ws + OFF_P);
    unsigned short* Hb   = (unsigned short*)(ws + OFF_P);
    unsigned short* W1b = (unsigned short*)(ws + OFF_W1B);
    unsigned short* W2b = (unsigned short*)(ws + OFF_W2B);
    unsigned short* W3b = (unsigned short*)(ws + OFF_W3B);
    float* b1f    = (float*)(ws + OFF_B1F);
    float* b2f    = (float*)(ws + OFF_B2F);
    float* b3f    = (float*)(ws + OFF_B3F);
    float* Waf    = (float*)(ws + OFF_WAF);
    float* colsum = (float*)(ws + OFF_COLSUM);
    float* pooled = (float*)(ws + OFF_POOLED);
    float* ctx    = (float*)(ws + OFF_CTX);

    unsigned char* Q = (unsigned char*)d_out;   // d_out doubles as T-scratch (12.8 MB)

    hipMemsetAsync(raw, 0, 256, stream);
    hipMemsetAsync(colsum, 0, 64 * 4, stream);
    hipMemsetAsync(pooled, 0, 64 * 4, stream);

    k_probe1<<<256, 256, 0, stream>>>((const unsigned short*)x, ei, raw);
    k_probe2<<<1, 64, 0, stream>>>(raw, flags);
    cvt_params<<<64, 256, 0, stream>>>(W1, b1, W2, b2, W3, b3, Wa,
                                       W1b, W2b, W3b, b1f, b2f, b3f, Waf, flags);

    // atomic-free CSR build
    k_hist<<<NBLK, 256, 0, stream>>>(ei, ghist, flags);
    k_off<<<1, 256, 0, stream>>>(ghist, cbase, offm, rowptr);
    k_scatter<<<NBLK, 256, 0, stream>>>(ei, offm, scrA, flags);
    k_build<<<NB2, 256, 0, stream>>>(scrA, cbase, rowptr, dis, csr);

    // x -> fp8 P (overwrites scatter scratch)
    k_cvtx<<<(NN * 128 / 4 + 255) / 256, 256, 0, stream>>>(x, P, flags);

    // L1: T' = dis*(P@W1) (Q, MFMA) ; P = relu((sum+self)*dn + b1)
    k_xf_mfma<8><<<NR / 64, 256, 0, stream>>>(P, W1b, dis, Q);
    k_agg128<true><<<NN / 4, 256, 0, stream>>>(Q, rowptr, csr, dis, b1f, P);
    // L2
    k_xf_mfma<8><<<NR / 64, 256, 0, stream>>>(P, W2b, dis, Q);
    k_agg128<true><<<NN / 4, 256, 0, stream>>>(Q, rowptr, csr, dis, b2f, P);
    // L3: T3' = dis*(P@W3) (Q, 64 cols) ; Hb = (sum+self)*dn + b3 (bf16)
    k_xf_mfma<4><<<NR / 64, 256, 0, stream>>>(P, W3b, dis, Q);
    k_agg64<<<NN / 8, 256, 0, stream>>>(Q, rowptr, csr, dis, b3f, Hb);

    // attention pooling (v2)
    k_colsum<<<256, 512, 0, stream>>>(Hb, colsum);
    k_ctx<<<1, 64, 0, stream>>>(colsum, Waf, ctx);
    k_pool<<<256, 512, 0, stream>>>(Hb, ctx, pooled);

    // final output
    k_out<<<(1600016 + 255) / 256, 256, 0, stream>>>(Hb, pooled, d_out, flags);
}

// Round 5
// 415.212 us; speedup vs baseline: 1.1741x; 1.0023x over previous
//
#include <hip/hip_runtime.h>
#include <hip/hip_bf16.h>

#define NN 100000
#define NE 1600000
#define NR 100032            // NN rounded to 64-row blocks (table alloc rows)
#define NB2 196              // coarse buckets = ceil(NN/512)
#define NBLK 391             // hist/scatter blocks = ceil(NE/4096)
#define EPB 4096             // edges per hist/scatter block

#if defined(__has_builtin)
#  if __has_builtin(__builtin_amdgcn_cvt_pk_f32_fp8) && \
      __has_builtin(__builtin_amdgcn_cvt_pk_fp8_f32) && \
      __has_builtin(__builtin_amdgcn_cvt_f32_fp8)
#    define HWF8 1
#  endif
#endif

typedef float f32x2 __attribute__((ext_vector_type(2)));
typedef float f32x4 __attribute__((ext_vector_type(4)));
typedef short bf16x8 __attribute__((ext_vector_type(8)));

static __device__ __forceinline__ float bf2f(__hip_bfloat16 v) { return __bfloat162float(v); }
static __device__ __forceinline__ float bfu(unsigned short w) {
    return __uint_as_float((unsigned)w << 16);
}

// ---------------- fp8 e4m3 software codec (fallback, validated r3/r4) ---------
static __device__ __forceinline__ float f8d_sw(unsigned b) {
    unsigned e = (b >> 3) & 15u, m = b & 7u;
    float mag;
    if (e == 0) mag = (float)m * 0.001953125f;
    else        mag = __uint_as_float(((e + 120u) << 23) | (m << 20));
    return (b & 0x80u) ? -mag : mag;
}
static __device__ __forceinline__ unsigned char f8e_sw(float x) {
    unsigned u = __float_as_uint(x);
    unsigned s = (u >> 31) << 7;
    unsigned au = u & 0x7fffffffu;
    if (au >= 0x43E00000u) return (unsigned char)(s | 0x7Eu);
    if (au <  0x3A800000u) return (unsigned char)s;
    if (au <  0x3C800000u) {
        float a = __uint_as_float(au);
        int m = (int)rintf(a * 512.0f);
        if (m >= 8) return (unsigned char)(s | 0x08u);
        return (unsigned char)(s | (unsigned)m);
    }
    au += 0x80000u;
    if (au >= 0x43E00000u) return (unsigned char)(s | 0x7Eu);
    unsigned e = (au >> 23) - 120u;
    unsigned m = (au >> 20) & 7u;
    return (unsigned char)(s | (e << 3) | m);
}

// ---------------- fp8 helpers (HW if available) ----------------
static __device__ __forceinline__ float f8d1(unsigned b) {
#ifdef HWF8
    return __builtin_amdgcn_cvt_f32_fp8((int)b, 0);
#else
    return f8d_sw(b);
#endif
}
static __device__ __forceinline__ void f8d2(unsigned short v, float& x0, float& x1) {
#ifdef HWF8
    f32x2 r = __builtin_amdgcn_cvt_pk_f32_fp8((int)(unsigned)v, false);
    x0 = r.x; x1 = r.y;
#else
    x0 = f8d_sw(v & 255u); x1 = f8d_sw(v >> 8);
#endif
}
static __device__ __forceinline__ void f8d4(unsigned u, float* o) {
#ifdef HWF8
    f32x2 lo = __builtin_amdgcn_cvt_pk_f32_fp8((int)u, false);
    f32x2 hi = __builtin_amdgcn_cvt_pk_f32_fp8((int)u, true);
    o[0] = lo.x; o[1] = lo.y; o[2] = hi.x; o[3] = hi.y;
#else
    o[0] = f8d_sw(u & 255u); o[1] = f8d_sw((u >> 8) & 255u);
    o[2] = f8d_sw((u >> 16) & 255u); o[3] = f8d_sw(u >> 24);
#endif
}
static __device__ __forceinline__ unsigned short f8e2(float a, float b) {
#ifdef HWF8
    float ca = fminf(fmaxf(a, -448.0f), 448.0f);
    float cb = fminf(fmaxf(b, -448.0f), 448.0f);
    int p = __builtin_amdgcn_cvt_pk_fp8_f32(ca, cb, 0, false);
    return (unsigned short)(p & 0xFFFF);
#else
    return (unsigned short)f8e_sw(a) | ((unsigned short)f8e_sw(b) << 8);
#endif
}
static __device__ __forceinline__ unsigned char f8e1(float a) {
    return (unsigned char)(f8e2(a, 0.0f) & 0xFF);
}
// f32 -> bf16 bits by truncation (EXACT for values that came from fp8 e4m3)
static __device__ __forceinline__ unsigned bfpack(float lo, float hi) {
    return (__float_as_uint(lo) >> 16) | (__float_as_uint(hi) & 0xFFFF0000u);
}

// decode 8 fp8 (uint2) and accumulate UNWEIGHTED into 4 f32x2 (v_pk_add_f32)
static __device__ __forceinline__ void acc8_add(f32x2* acc, uint2 v) {
#ifdef HWF8
    acc[0] += __builtin_amdgcn_cvt_pk_f32_fp8((int)v.x, false);
    acc[1] += __builtin_amdgcn_cvt_pk_f32_fp8((int)v.x, true);
    acc[2] += __builtin_amdgcn_cvt_pk_f32_fp8((int)v.y, false);
    acc[3] += __builtin_amdgcn_cvt_pk_f32_fp8((int)v.y, true);
#else
    unsigned u[2] = {v.x, v.y};
#pragma unroll
    for (int q = 0; q < 2; q++) {
        float o[4]; f8d4(u[q], o);
        acc[2 * q]     += (f32x2){o[0], o[1]};
        acc[2 * q + 1] += (f32x2){o[2], o[3]};
    }
#endif
}

// ---------------- dtype probes (parallel) ----------------
__global__ void k_probe1(const unsigned short* __restrict__ xw,
                         const int* __restrict__ ei, int* __restrict__ raw) {
    int i = blockIdx.x * 256 + threadIdx.x;    // 65536 probes
    int nan = ((xw[i] & 0x7F80u) == 0x7F80u) ? 1 : 0;
    int odd = (ei[2 * i + 1] != 0) ? 1 : 0;
    unsigned long long bn = __ballot(nan);
    unsigned long long bo = __ballot(odd);
    if ((threadIdx.x & 63) == 0) {
        if (bn) atomicAdd(&raw[0], __popcll(bn));
        if (bo) atomicAdd(&raw[1], __popcll(bo));
    }
}
__global__ void k_probe2(const int* __restrict__ raw, int* __restrict__ flags) {
    if (threadIdx.x == 0) {
        flags[0] = (raw[0] > 0) ? 1 : 0;   // x/weights are f32
        flags[1] = (raw[1] == 0) ? 1 : 0;  // edge_index is int64
    }
}

static __device__ __forceinline__ int e_src(const int* ei, int e, int f64) {
    int v = f64 ? ei[2 * e] : ei[e];
    return min(max(v, 0), NN - 1);
}
static __device__ __forceinline__ int e_dst(const int* ei, int e, int f64) {
    int v = f64 ? ei[2 * (NE + e)] : ei[NE + e];
    return min(max(v, 0), NN - 1);
}
static __device__ __forceinline__ float ldx(const void* p, long long i, int f32) {
    return f32 ? ((const float*)p)[i] : bf2f(((const __hip_bfloat16*)p)[i]);
}

// ------------- parameter conversion: W -> bf16 in MFMA-frag order -------------
__global__ void cvt_params(const void* W1, const void* b1, const void* W2, const void* b2,
                           const void* W3, const void* b3, const void* Wa,
                           unsigned short* W1b, unsigned short* W2b, unsigned short* W3b,
                           float* b1f, float* b2f, float* b3f, float* Waf,
                           const int* flags) {
    int i = blockIdx.x * blockDim.x + threadIdx.x;
    int f = flags[0];
    if (i < 16384) {
        int j = i & 7, l = (i >> 3) & 63, c = (i >> 9) & 7, kc = i >> 12;
        int k = kc * 32 + ((l >> 4)) * 8 + j;
        int col = c * 16 + (l & 15);
        W1b[i] = __bfloat16_as_ushort(__float2bfloat16(ldx(W1, k * 128 + col, f)));
        W2b[i] = __bfloat16_as_ushort(__float2bfloat16(ldx(W2, k * 128 + col, f)));
    }
    if (i < 8192) {
        int j = i & 7, l = (i >> 3) & 63, c = (i >> 9) & 3, kc = i >> 11;
        int k = kc * 32 + ((l >> 4)) * 8 + j;
        int col = c * 16 + (l & 15);
        W3b[i] = __bfloat16_as_ushort(__float2bfloat16(ldx(W3, k * 64 + col, f)));
    }
    if (i < 4096)  Waf[i] = ldx(Wa, i, f);
    if (i < 128)   { b1f[i] = ldx(b1, i, f); b2f[i] = ldx(b2, i, f); }
    if (i < 64)    b3f[i] = ldx(b3, i, f);
}

// ---------------- x -> fp8 table P ----------------
__global__ void k_cvtx(const void* __restrict__ x, unsigned char* __restrict__ P,
                       const int* __restrict__ flags) {
    int i = blockIdx.x * blockDim.x + threadIdx.x;
    if (i >= (NN * 128) / 4) return;
    unsigned pk;
    if (flags[0]) {
        float4 v = ((const float4*)x)[i];
        pk = (unsigned)f8e2(v.x, v.y) | ((unsigned)f8e2(v.z, v.w) << 16);
    } else {
        ushort4 v = ((const ushort4*)x)[i];
        pk = (unsigned)f8e2(bfu(v.x), bfu(v.y)) | ((unsigned)f8e2(bfu(v.z), bfu(v.w)) << 16);
    }
    ((unsigned*)P)[i] = pk;
}

// ======== CSR build: atomic-free multisplit (validated r7) ========
__global__ __launch_bounds__(256) void k_hist(const int* __restrict__ ei,
                                              int* __restrict__ ghist,
                                              const int* __restrict__ flags) {
    __shared__ int h[NB2];
    int blk = blockIdx.x, t = threadIdx.x;
    for (int i = t; i < NB2; i += 256) h[i] = 0;
    __syncthreads();
    int f64 = flags[1];
    int e0 = blk * EPB;
    for (int i = t; i < EPB; i += 256) {
        int e = e0 + i;
        if (e < NE) atomicAdd(&h[e_dst(ei, e, f64) >> 9], 1);
    }
    __syncthreads();
    for (int i = t; i < NB2; i += 256) ghist[blk * NB2 + i] = h[i];
}

__global__ __launch_bounds__(256) void k_off(const int* __restrict__ ghist,
                                             int* __restrict__ cbase,
                                             int* __restrict__ offm,
                                             int* __restrict__ rowptr) {
    __shared__ int tot[NB2];
    int t = threadIdx.x;
    if (t < NB2) {
        int s = 0;
        for (int blk = 0; blk < NBLK; blk++) s += ghist[blk * NB2 + t];
        tot[t] = s;
    }
    __syncthreads();
    if (t == 0) {
        int run = 0;
        for (int b = 0; b < NB2; b++) { cbase[b] = run; run += tot[b]; }
        cbase[NB2] = run;
        rowptr[NN] = run;   // == NE
    }
    __syncthreads();
    if (t < NB2) {
        int run = cbase[t];
        for (int blk = 0; blk < NBLK; blk++) {
            offm[blk * NB2 + t] = run;
            run += ghist[blk * NB2 + t];
        }
    }
}

__global__ __launch_bounds__(256) void k_scatter(const int* __restrict__ ei,
                                                 const int* __restrict__ offm,
                                                 int* __restrict__ scratch,
                                                 const int* __restrict__ flags) {
    __shared__ int cur[NB2];
    int blk = blockIdx.x, t = threadIdx.x;
    for (int i = t; i < NB2; i += 256) cur[i] = offm[blk * NB2 + i];
    __syncthreads();
    int f64 = flags[1];
    int e0 = blk * EPB;
    for (int i = t; i < EPB; i += 256) {
        int e = e0 + i;
        if (e < NE) {
            int d = e_dst(ei, e, f64);
            int s = e_src(ei, e, f64);
            int p = atomicAdd(&cur[d >> 9], 1);
            p = min(max(p, 0), NE - 1);
            scratch[p] = s | ((d & 511) << 17);
        }
    }
}

__global__ __launch_bounds__(256) void k_build(const int* __restrict__ scratch,
                                               const int* __restrict__ cbase,
                                               int* __restrict__ rowptr,
                                               float* __restrict__ dis,
                                               int* __restrict__ csr) {
    __shared__ int hist[512];
    __shared__ int base[512];
    __shared__ int sd[256];
    int b = blockIdx.x, t = threadIdx.x;
    int n0 = b << 9;
    int s0 = cbase[b], s1 = cbase[b + 1];
    hist[t] = 0; hist[t + 256] = 0;
    __syncthreads();
    for (int i = s0 + t; i < s1; i += 256) {
        int dlo = (scratch[i] >> 17) & 511;
        atomicAdd(&hist[dlo], 1);
    }
    __syncthreads();
    int v0 = hist[2 * t], v1 = hist[2 * t + 1];
    int s = v0 + v1;
    sd[t] = s; __syncthreads();
    for (int o = 1; o < 256; o <<= 1) {
        int add = (t >= o) ? sd[t - o] : 0;
        __syncthreads();
        sd[t] += add;
        __syncthreads();
    }
    int run = s0 + sd[t] - s;
    base[2 * t] = run;
    base[2 * t + 1] = run + v0;
    int n = n0 + 2 * t;
    if (n < NN) {
        rowptr[n] = run;
        dis[n] = rsqrtf((float)v0 + 1.0f);
    }
    if (n + 1 < NN) {
        rowptr[n + 1] = run + v0;
        dis[n + 1] = rsqrtf((float)v1 + 1.0f);
    }
    __syncthreads();
    for (int i = s0 + t; i < s1; i += 256) {
        int v = scratch[i];
        int dlo = (v >> 17) & 511;
        int p = atomicAdd(&base[dlo], 1);
        p = min(max(p, 0), NE - 1);
        csr[p] = v & 0x1FFFF;
    }
}

// ------------- MFMA GEMM: O[NNxCOLS] = dis[row] * (A(fp8,128) @ W) ------------
// Pre-scales each output row by dis[row] so aggregation is an unweighted sum.
// Row NN is written as zeros (pad row gathered by invalid edge slots).
template <int NCT>    // NCT = COLS/16 (8 or 4)
__global__ __launch_bounds__(256) void k_xf_mfma(const unsigned char* __restrict__ A,
                                                 const unsigned short* __restrict__ Wf,
                                                 const float* __restrict__ dis,
                                                 unsigned char* __restrict__ O) {
    __shared__ unsigned short wl[NCT * 4 * 64 * 8];
    int t = threadIdx.x;
    int n0 = blockIdx.x * 64;
    {
        const uint4* wg = (const uint4*)Wf;
        uint4* wld = (uint4*)wl;
#pragma unroll
        for (int i = 0; i < NCT; i++) wld[i * 256 + t] = wg[i * 256 + t];
    }
    __syncthreads();
    int w = t >> 6, l = t & 63;
    int quad = l >> 4, m = l & 15;
    int arow = n0 + w * 16 + m;
    const unsigned char* ap = A + (size_t)arow * 128 + quad * 8;
    f32x4 acc[NCT];
#pragma unroll
    for (int c = 0; c < NCT; c++) acc[c] = (f32x4){0.0f, 0.0f, 0.0f, 0.0f};
#pragma unroll
    for (int kc = 0; kc < 4; kc++) {
        uint2 g = *(const uint2*)(ap + kc * 32);
        float o[8];
        f8d4(g.x, o); f8d4(g.y, o + 4);
        union { unsigned u[4]; bf16x8 v; } fr;
        fr.u[0] = bfpack(o[0], o[1]);
        fr.u[1] = bfpack(o[2], o[3]);
        fr.u[2] = bfpack(o[4], o[5]);
        fr.u[3] = bfpack(o[6], o[7]);
#pragma unroll
        for (int c = 0; c < NCT; c++) {
            bf16x8 bw = *(const bf16x8*)&wl[((kc * NCT + c) * 64 + l) * 8];
            acc[c] = __builtin_amdgcn_mfma_f32_16x16x32_bf16(fr.v, bw, acc[c], 0, 0, 0);
        }
    }
    int orow0 = n0 + w * 16 + quad * 4;
    float dsc[4];
#pragma unroll
    for (int r = 0; r < 4; r++) {
        int row = orow0 + r;
        dsc[r] = (row < NN) ? dis[row] : 0.0f;     // row==NN -> store zeros
    }
#pragma unroll
    for (int c = 0; c < NCT; c++) {
        int col = c * 16 + m;
#pragma unroll
        for (int r = 0; r < 4; r++) {
            int row = orow0 + r;
            if (row <= NN) O[(size_t)row * (NCT * 16) + col] = f8e1(acc[c][r] * dsc[r]);
        }
    }
}

// ---- agg, F=128: H = relu?((sum T'[src] + T'[n]) * dn + b), fp8->fp8 --------
// v5: 1 node/wave, 4 slots x 16 lanes x 8B, QUAD-depth inner loop: 4 groups
// (16 edges) per iteration, MLP=4. Pad groups gather the zero row NN (L2-hot,
// branchless). Typical node (deg<=16) = exactly one straight-line iteration.
// csr entries are pre-masked to 17 bits; any value stays inside the 25.6MB
// T buffer, so no per-edge clamp is needed.
template <bool RELU>
__global__ __launch_bounds__(256) void k_agg128(const unsigned char* __restrict__ Tb,
                                                const int* __restrict__ rowptr,
                                                const int* __restrict__ csr,
                                                const float* __restrict__ dis,
                                                const float* __restrict__ bias,
                                                unsigned char* __restrict__ H) {
    int n = blockIdx.x * 4 + (threadIdx.x >> 6);
    int lane = threadIdx.x & 63;
    int r = lane >> 4;            // slot 0..3
    int f = lane & 15;            // feature group: bytes 8f..8f+7
    int fo = f << 3;
    float dn = dis[n];
    int s0 = rowptr[n], s1 = rowptr[n + 1];
    s0 = min(max(s0, 0), NE); s1 = min(max(s1, s0), NE);
    f32x2 acc[4];
#pragma unroll
    for (int k = 0; k < 4; k++) acc[k] = (f32x2){0.0f, 0.0f};
    if (r == 0) {   // self term: T'[n], weight 1.0 (dis already folded into T')
        uint2 v = *(const uint2*)(Tb + (((unsigned)n << 7) + (unsigned)fo));
        acc8_add(acc, v);
    }
    for (int base = s0; base < s1; base += 64) {
        int m = min(64, s1 - base);
        unsigned voff = (unsigned)NN << 7;          // pad -> zero row
        if (lane < m) voff = (unsigned)csr[base + lane] << 7;
        int nq = (m + 15) >> 4;                     // quads of 4 groups (16 edges)
        for (int q = 0; q < nq; q++) {
            int a0 = q * 64 + r * 4;
            unsigned vo0 = (unsigned)__builtin_amdgcn_ds_bpermute(a0,      (int)voff);
            unsigned vo1 = (unsigned)__builtin_amdgcn_ds_bpermute(a0 + 16, (int)voff);
            unsigned vo2 = (unsigned)__builtin_amdgcn_ds_bpermute(a0 + 32, (int)voff);
            unsigned vo3 = (unsigned)__builtin_amdgcn_ds_bpermute(a0 + 48, (int)voff);
            uint2 v0 = *(const uint2*)(Tb + (vo0 + (unsigned)fo));
            uint2 v1 = *(const uint2*)(Tb + (vo1 + (unsigned)fo));
            uint2 v2 = *(const uint2*)(Tb + (vo2 + (unsigned)fo));
            uint2 v3 = *(const uint2*)(Tb + (vo3 + (unsigned)fo));
            acc8_add(acc, v0);
            acc8_add(acc, v1);
            acc8_add(acc, v2);
            acc8_add(acc, v3);
        }
    }
    // reduce across the 4 slots (lane strides 16, 32): 16 ds ops total
#pragma unroll
    for (int k = 0; k < 4; k++) {
        acc[k].x += __shfl_xor(acc[k].x, 16, 64);
        acc[k].y += __shfl_xor(acc[k].y, 16, 64);
        acc[k].x += __shfl_xor(acc[k].x, 32, 64);
        acc[k].y += __shfl_xor(acc[k].y, 32, 64);
    }
    if (r == 0) {
        float4 bA = *(const float4*)(bias + fo);
        float4 bB = *(const float4*)(bias + fo + 4);
        float t[8];
        t[0] = acc[0].x * dn + bA.x; t[1] = acc[0].y * dn + bA.y;
        t[2] = acc[1].x * dn + bA.z; t[3] = acc[1].y * dn + bA.w;
        t[4] = acc[2].x * dn + bB.x; t[5] = acc[2].y * dn + bB.y;
        t[6] = acc[3].x * dn + bB.z; t[7] = acc[3].y * dn + bB.w;
        if (RELU) {
#pragma unroll
            for (int k = 0; k < 8; k++) t[k] = fmaxf(t[k], 0.0f);
        }
        unsigned lo = (unsigned)f8e2(t[0], t[1]) | ((unsigned)f8e2(t[2], t[3]) << 16);
        unsigned hi = (unsigned)f8e2(t[4], t[5]) | ((unsigned)f8e2(t[6], t[7]) << 16);
        *(uint2*)(H + (((size_t)n << 7) + (size_t)fo)) = make_uint2(lo, hi);
    }
}

// ---- agg, F=64 final: h3 = (sum T3'[src] + T3'[n]) * dn + b3 -> bf16 --------
// v5: 2 nodes/wave (32 lanes each), 4 slots x 8 lanes x 8B, quad inner loop.
__global__ __launch_bounds__(256) void k_agg64(const unsigned char* __restrict__ Tb,
                                               const int* __restrict__ rowptr,
                                               const int* __restrict__ csr,
                                               const float* __restrict__ dis,
                                               const float* __restrict__ bias,
                                               unsigned short* __restrict__ Hb) {
    int lane = threadIdx.x & 63;
    int half = lane >> 5;
    int hl = lane & 31;
    int n = blockIdx.x * 8 + (threadIdx.x >> 6) * 2 + half;
    int r = hl >> 3;              // slot 0..3
    int f = hl & 7;               // feature group: bytes 8f..8f+7
    int fo = f << 3;
    float dn = dis[n];
    int s0 = rowptr[n], s1 = rowptr[n + 1];
    s0 = min(max(s0, 0), NE); s1 = min(max(s1, s0), NE);
    f32x2 acc[4];
#pragma unroll
    for (int k = 0; k < 4; k++) acc[k] = (f32x2){0.0f, 0.0f};
    if (r == 0) {   // self term: weight 1.0 (dis folded into T3')
        uint2 v = *(const uint2*)(Tb + (((unsigned)n << 6) + (unsigned)fo));
        acc8_add(acc, v);
    }
    int ab = half << 7;           // bpermute byte base of own half (32 lanes * 4B)
    for (int base = s0; base < s1; base += 32) {
        int m = min(32, s1 - base);
        unsigned voff = (unsigned)NN << 6;          // pad -> zero row
        if (hl < m) voff = (unsigned)csr[base + hl] << 6;
        int nq = (m + 15) >> 4;                     // quads of 4 groups (16 edges)
        for (int q = 0; q < nq; q++) {
            int a0 = ab + q * 64 + r * 4;
            unsigned vo0 = (unsigned)__builtin_amdgcn_ds_bpermute(a0,      (int)voff);
            unsigned vo1 = (unsigned)__builtin_amdgcn_ds_bpermute(a0 + 16, (int)voff);
            unsigned vo2 = (unsigned)__builtin_amdgcn_ds_bpermute(a0 + 32, (int)voff);
            unsigned vo3 = (unsigned)__builtin_amdgcn_ds_bpermute(a0 + 48, (int)voff);
            uint2 v0 = *(const uint2*)(Tb + (vo0 + (unsigned)fo));
            uint2 v1 = *(const uint2*)(Tb + (vo1 + (unsigned)fo));
            uint2 v2 = *(const uint2*)(Tb + (vo2 + (unsigned)fo));
            uint2 v3 = *(const uint2*)(Tb + (vo3 + (unsigned)fo));
            acc8_add(acc, v0);
            acc8_add(acc, v1);
            acc8_add(acc, v2);
            acc8_add(acc, v3);
        }
    }
    // reduce across the 4 slots (lane strides 8, 16; stays within each half)
#pragma unroll
    for (int k = 0; k < 4; k++) {
        acc[k].x += __shfl_xor(acc[k].x, 8, 64);
        acc[k].y += __shfl_xor(acc[k].y, 8, 64);
        acc[k].x += __shfl_xor(acc[k].x, 16, 64);
        acc[k].y += __shfl_xor(acc[k].y, 16, 64);
    }
    if (r == 0) {
        float4 bA = *(const float4*)(bias + fo);
        float4 bB = *(const float4*)(bias + fo + 4);
        float t[8];
        t[0] = acc[0].x * dn + bA.x; t[1] = acc[0].y * dn + bA.y;
        t[2] = acc[1].x * dn + bA.z; t[3] = acc[1].y * dn + bA.w;
        t[4] = acc[2].x * dn + bB.x; t[5] = acc[2].y * dn + bB.y;
        t[6] = acc[3].x * dn + bB.z; t[7] = acc[3].y * dn + bB.w;
        unsigned p0 = (unsigned)__bfloat16_as_ushort(__float2bfloat16(t[0])) |
                      ((unsigned)__bfloat16_as_ushort(__float2bfloat16(t[1])) << 16);
        unsigned p1 = (unsigned)__bfloat16_as_ushort(__float2bfloat16(t[2])) |
                      ((unsigned)__bfloat16_as_ushort(__float2bfloat16(t[3])) << 16);
        unsigned p2 = (unsigned)__bfloat16_as_ushort(__float2bfloat16(t[4])) |
                      ((unsigned)__bfloat16_as_ushort(__float2bfloat16(t[5])) << 16);
        unsigned p3 = (unsigned)__bfloat16_as_ushort(__float2bfloat16(t[6])) |
                      ((unsigned)__bfloat16_as_ushort(__float2bfloat16(t[7])) << 16);
        *(uint4*)(Hb + (((size_t)n << 6) + (size_t)fo)) = make_uint4(p0, p1, p2, p3);
    }
}

// ---------------- pooling v2: uint2 row-quad layout, 4 rows/wave/iter ---------
// lane l: row group rg=l>>4 (4 rows concurrent), feature quad cq=l&15.
__global__ __launch_bounds__(512) void k_colsum(const unsigned short* __restrict__ h3,
                                                float* __restrict__ colsum) {
    int t = threadIdx.x;
    int lane = t & 63;
    int rg = lane >> 4, cq = lane & 15;
    int wid = (blockIdx.x * 512 + t) >> 6;
    int nw = (gridDim.x * 512) >> 6;
    float a0 = 0, a1 = 0, a2 = 0, a3 = 0;
    for (int r = wid * 4 + rg; r < NN; r += nw * 4) {
        uint2 v = *(const uint2*)(h3 + ((size_t)r << 6) + cq * 4);
        a0 += bfu((unsigned short)(v.x & 0xFFFF));
        a1 += bfu((unsigned short)(v.x >> 16));
        a2 += bfu((unsigned short)(v.y & 0xFFFF));
        a3 += bfu((unsigned short)(v.y >> 16));
    }
    a0 += __shfl_xor(a0, 16, 64); a0 += __shfl_xor(a0, 32, 64);
    a1 += __shfl_xor(a1, 16, 64); a1 += __shfl_xor(a1, 32, 64);
    a2 += __shfl_xor(a2, 16, 64); a2 += __shfl_xor(a2, 32, 64);
    a3 += __shfl_xor(a3, 16, 64); a3 += __shfl_xor(a3, 32, 64);
    __shared__ float part[8][64];
    int w = t >> 6;
    if (rg == 0) {
        part[w][cq * 4 + 0] = a0;
        part[w][cq * 4 + 1] = a1;
        part[w][cq * 4 + 2] = a2;
        part[w][cq * 4 + 3] = a3;
    }
    __syncthreads();
    if (t < 64) {
        float s = 0;
#pragma unroll
        for (int i = 0; i < 8; i++) s += part[i][t];
        atomicAdd(&colsum[t], s);
    }
}

__global__ void k_ctx(const float* __restrict__ colsum, const float* __restrict__ Wa,
                      float* __restrict__ ctx) {
    __shared__ float ms[64];
    int j = threadIdx.x;
    ms[j] = colsum[j] * (1.0f / NN);
    __syncthreads();
    float s = 0.0f;
#pragma unroll
    for (int k = 0; k < 64; k++) s += ms[k] * Wa[k * 64 + j];
    ctx[j] = tanhf(s);
}

__global__ __launch_bounds__(512) void k_pool(const unsigned short* __restrict__ h3,
                                              const float* __restrict__ ctx,
                                              float* __restrict__ pooled) {
    int t = threadIdx.x;
    int lane = t & 63;
    int rg = lane >> 4, cq = lane & 15;
    int wid = (blockIdx.x * 512 + t) >> 6;
    int nw = (gridDim.x * 512) >> 6;
    float c0 = ctx[cq * 4 + 0], c1 = ctx[cq * 4 + 1];
    float c2 = ctx[cq * 4 + 2], c3 = ctx[cq * 4 + 3];
    float q0 = 0, q1 = 0, q2 = 0, q3 = 0;
    for (int r = wid * 4 + rg; r < NN; r += nw * 4) {
        uint2 v = *(const uint2*)(h3 + ((size_t)r << 6) + cq * 4);
        float x0 = bfu((unsigned short)(v.x & 0xFFFF));
        float x1 = bfu((unsigned short)(v.x >> 16));
        float x2 = bfu((unsigned short)(v.y & 0xFFFF));
        float x3 = bfu((unsigned short)(v.y >> 16));
        float p = x0 * c0 + x1 * c1 + x2 * c2 + x3 * c3;
        p += __shfl_xor(p, 1, 64);
        p += __shfl_xor(p, 2, 64);
        p += __shfl_xor(p, 4, 64);
        p += __shfl_xor(p, 8, 64);
        float sc = 1.0f / (1.0f + expf(-p));
        q0 += sc * x0; q1 += sc * x1; q2 += sc * x2; q3 += sc * x3;
    }
    q0 += __shfl_xor(q0, 16, 64); q0 += __shfl_xor(q0, 32, 64);
    q1 += __shfl_xor(q1, 16, 64); q1 += __shfl_xor(q1, 32, 64);
    q2 += __shfl_xor(q2, 16, 64); q2 += __shfl_xor(q2, 32, 64);
    q3 += __shfl_xor(q3, 16, 64); q3 += __shfl_xor(q3, 32, 64);
    __shared__ float part[8][64];
    int w = t >> 6;
    if (rg == 0) {
        part[w][cq * 4 + 0] = q0;
        part[w][cq * 4 + 1] = q1;
        part[w][cq * 4 + 2] = q2;
        part[w][cq * 4 + 3] = q3;
    }
    __syncthreads();
    if (t < 64) {
        float s = 0;
#pragma unroll
        for (int i = 0; i < 8; i++) s += part[i][t];
        atomicAdd(&pooled[t], s);
    }
}

// ---------------- final output write (4 elems/thread) ----------------
__global__ void k_out(const unsigned short* __restrict__ h3, const float* __restrict__ pooled,
                      void* __restrict__ out, const int* __restrict__ flags) {
    int q = blockIdx.x * blockDim.x + threadIdx.x;   // quad index; 6400064/4 = 1600016
    if (q >= 1600016) return;
    long long i0 = (long long)q * 4;
    float v[4];
#pragma unroll
    for (int k = 0; k < 4; k++) {
        long long i = i0 + k;
        v[k] = (i < 6400000LL) ? bfu(h3[i]) : pooled[i - 6400000LL];
    }
    if (flags[0]) {
        *(float4*)((float*)out + i0) = make_float4(v[0], v[1], v[2], v[3]);
    } else {
        unsigned lo = (unsigned)__bfloat16_as_ushort(__float2bfloat16(v[0])) |
                      ((unsigned)__bfloat16_as_ushort(__float2bfloat16(v[1])) << 16);
        unsigned hi = (unsigned)__bfloat16_as_ushort(__float2bfloat16(v[2])) |
                      ((unsigned)__bfloat16_as_ushort(__float2bfloat16(v[3])) << 16);
        *(uint2*)((unsigned short*)out + i0) = make_uint2(lo, hi);
    }
}

// ---------------- workspace layout (~21.5 MB) ----------------
static constexpr size_t AL(size_t x) { return (x + 255) & ~size_t(255); }
static constexpr size_t OFF_FLAGS  = 0;
static constexpr size_t OFF_RAW    = OFF_FLAGS + 256;
static constexpr size_t OFF_GHIST  = OFF_RAW + 256;
static constexpr size_t OFF_OFFM   = OFF_GHIST + AL((size_t)NBLK * NB2 * 4);
static constexpr size_t OFF_CBASE  = OFF_OFFM + AL((size_t)NBLK * NB2 * 4);
static constexpr size_t OFF_ROWPTR = OFF_CBASE + AL((NB2 + 1) * 4);
static constexpr size_t OFF_CSR    = OFF_ROWPTR + AL((NN + 1) * 4);
static constexpr size_t OFF_DIS    = OFF_CSR + AL((size_t)NE * 4);
static constexpr size_t OFF_P      = OFF_DIS + AL(NN * 4);     // NR*128 fp8; also scatter scratch; also bf16 h3
static constexpr size_t OFF_W1B    = OFF_P + AL((size_t)NR * 128);
static constexpr size_t OFF_W2B    = OFF_W1B + AL(16384 * 2);
static constexpr size_t OFF_W3B    = OFF_W2B + AL(16384 * 2);
static constexpr size_t OFF_B1F    = OFF_W3B + AL(8192 * 2);
static constexpr size_t OFF_B2F    = OFF_B1F + AL(128 * 4);
static constexpr size_t OFF_B3F    = OFF_B2F + AL(128 * 4);
static constexpr size_t OFF_WAF    = OFF_B3F + AL(64 * 4);
static constexpr size_t OFF_COLSUM = OFF_WAF + AL(4096 * 4);
static constexpr size_t OFF_POOLED = OFF_COLSUM + AL(64 * 4);
static constexpr size_t OFF_CTX    = OFF_POOLED + AL(64 * 4);

extern "C" void kernel_launch(void* const* d_in, const int* in_sizes, int n_in,
                              void* d_out, int out_size, void* d_ws, size_t ws_size,
                              hipStream_t stream) {
    const int* ei = (const int*)d_in[0];
    const void* x  = d_in[1];
    const void* W1 = d_in[2];
    const void* b1 = d_in[3];
    const void* W2 = d_in[4];
    const void* b2 = d_in[5];
    const void* W3 = d_in[6];
    const void* b3 = d_in[7];
    const void* Wa = d_in[8];

    char* ws = (char*)d_ws;
    int*   flags  = (int*)(ws + OFF_FLAGS);
    int*   raw    = (int*)(ws + OFF_RAW);
    int*   ghist  = (int*)(ws + OFF_GHIST);
    int*   offm   = (int*)(ws + OFF_OFFM);
    int*   cbase  = (int*)(ws + OFF_CBASE);
    int*   rowptr = (int*)(ws + OFF_ROWPTR);
    int*   csr    = (int*)(ws + OFF_CSR);
    float* dis    = (float*)(ws + OFF_DIS);
    unsigned char*  P    = (unsigned char*)(ws + OFF_P);
    int*            scrA = (int*)(ws + OFF_P);
    unsigned short* Hb   = (unsigned short*)(ws + OFF_P);
    unsigned short* W1b = (unsigned short*)(ws + OFF_W1B);
    unsigned short* W2b = (unsigned short*)(ws + OFF_W2B);
    unsigned short* W3b = (unsigned short*)(ws + OFF_W3B);
    float* b1f    = (float*)(ws + OFF_B1F);
    float* b2f    = (float*)(ws + OFF_B2F);
    float* b3f    = (float*)(ws + OFF_B3F);
    float* Waf    = (float*)(ws + OFF_WAF);
    float* colsum = (float*)(ws + OFF_COLSUM);
    float* pooled = (float*)(ws + OFF_POOLED);
    float* ctx    = (float*)(ws + OFF_CTX);

    unsigned char* Q = (unsigned char*)d_out;   // d_out doubles as T-scratch (12.8 MB)

    hipMemsetAsync(raw, 0, 256, stream);
    hipMemsetAsync(colsum, 0, 64 * 4, stream);
    hipMemsetAsync(pooled, 0, 64 * 4, stream);

    k_probe1<<<256, 256, 0, stream>>>((const unsigned short*)x, ei, raw);
    k_probe2<<<1, 64, 0, stream>>>(raw, flags);
    cvt_params<<<64, 256, 0, stream>>>(W1, b1, W2, b2, W3, b3, Wa,
                                       W1b, W2b, W3b, b1f, b2f, b3f, Waf, flags);

    // atomic-free CSR build
    k_hist<<<NBLK, 256, 0, stream>>>(ei, ghist, flags);
    k_off<<<1, 256, 0, stream>>>(ghist, cbase, offm, rowptr);
    k_scatter<<<NBLK, 256, 0, stream>>>(ei, offm, scrA, flags);
    k_build<<<NB2, 256, 0, stream>>>(scrA, cbase, rowptr, dis, csr);

    // x -> fp8 P (overwrites scatter scratch)
    k_cvtx<<<(NN * 128 / 4 + 255) / 256, 256, 0, stream>>>(x, P, flags);

    // L1: T' = dis*(P@W1) (Q, MFMA) ; P = relu((sum+self)*dn + b1)
    k_xf_mfma<8><<<NR / 64, 256, 0, stream>>>(P, W1b, dis, Q);
    k_agg128<true><<<NN / 4, 256, 0, stream>>>(Q, rowptr, csr, dis, b1f, P);
    // L2
    k_xf_mfma<8><<<NR / 64, 256, 0, stream>>>(P, W2b, dis, Q);
    k_agg128<true><<<NN / 4, 256, 0, stream>>>(Q, rowptr, csr, dis, b2f, P);
    // L3: T3' = dis*(P@W3) (Q, 64 cols) ; Hb = (sum+self)*dn + b3 (bf16)
    k_xf_mfma<4><<<NR / 64, 256, 0, stream>>>(P, W3b, dis, Q);
    k_agg64<<<NN / 8, 256, 0, stream>>>(Q, rowptr, csr, dis, b3f, Hb);

    // attention pooling (v2)
    k_colsum<<<256, 512, 0, stream>>>(Hb, colsum);
    k_ctx<<<1, 64, 0, stream>>>(colsum, Waf, ctx);
    k_pool<<<256, 512, 0, stream>>>(Hb, ctx, pooled);

    // final output
    k_out<<<(1600016 + 255) / 256, 256, 0, stream>>>(Hb, pooled, d_out, flags);
}

// Round 6
// 393.112 us; speedup vs baseline: 1.2401x; 1.0562x over previous
//
#include <hip/hip_runtime.h>
#include <hip/hip_bf16.h>

#define NN 100000
#define NE 1600000
#define NR 100032            // NN rounded to 64-row blocks (table alloc rows)
#define NB2 196              // coarse buckets = ceil(NN/512)
#define NBLK 391             // hist/scatter blocks = ceil(NE/4096)
#define EPB 4096             // edges per hist/scatter block

#if defined(__has_builtin)
#  if __has_builtin(__builtin_amdgcn_cvt_pk_f32_fp8) && \
      __has_builtin(__builtin_amdgcn_cvt_pk_fp8_f32) && \
      __has_builtin(__builtin_amdgcn_cvt_f32_fp8)
#    define HWF8 1
#  endif
#endif

typedef float f32x2 __attribute__((ext_vector_type(2)));
typedef float f32x4 __attribute__((ext_vector_type(4)));
typedef short bf16x8 __attribute__((ext_vector_type(8)));

static __device__ __forceinline__ float bf2f(__hip_bfloat16 v) { return __bfloat162float(v); }
static __device__ __forceinline__ float bfu(unsigned short w) {
    return __uint_as_float((unsigned)w << 16);
}

// ---------------- fp8 e4m3 software codec (fallback, validated r3/r4) ---------
static __device__ __forceinline__ float f8d_sw(unsigned b) {
    unsigned e = (b >> 3) & 15u, m = b & 7u;
    float mag;
    if (e == 0) mag = (float)m * 0.001953125f;
    else        mag = __uint_as_float(((e + 120u) << 23) | (m << 20));
    return (b & 0x80u) ? -mag : mag;
}
static __device__ __forceinline__ unsigned char f8e_sw(float x) {
    unsigned u = __float_as_uint(x);
    unsigned s = (u >> 31) << 7;
    unsigned au = u & 0x7fffffffu;
    if (au >= 0x43E00000u) return (unsigned char)(s | 0x7Eu);
    if (au <  0x3A800000u) return (unsigned char)s;
    if (au <  0x3C800000u) {
        float a = __uint_as_float(au);
        int m = (int)rintf(a * 512.0f);
        if (m >= 8) return (unsigned char)(s | 0x08u);
        return (unsigned char)(s | (unsigned)m);
    }
    au += 0x80000u;
    if (au >= 0x43E00000u) return (unsigned char)(s | 0x7Eu);
    unsigned e = (au >> 23) - 120u;
    unsigned m = (au >> 20) & 7u;
    return (unsigned char)(s | (e << 3) | m);
}

// ---------------- fp8 helpers (HW if available) ----------------
static __device__ __forceinline__ void f8d4(unsigned u, float* o) {
#ifdef HWF8
    f32x2 lo = __builtin_amdgcn_cvt_pk_f32_fp8((int)u, false);
    f32x2 hi = __builtin_amdgcn_cvt_pk_f32_fp8((int)u, true);
    o[0] = lo.x; o[1] = lo.y; o[2] = hi.x; o[3] = hi.y;
#else
    o[0] = f8d_sw(u & 255u); o[1] = f8d_sw((u >> 8) & 255u);
    o[2] = f8d_sw((u >> 16) & 255u); o[3] = f8d_sw(u >> 24);
#endif
}
static __device__ __forceinline__ unsigned short f8e2(float a, float b) {
#ifdef HWF8
    float ca = fminf(fmaxf(a, -448.0f), 448.0f);
    float cb = fminf(fmaxf(b, -448.0f), 448.0f);
    int p = __builtin_amdgcn_cvt_pk_fp8_f32(ca, cb, 0, false);
    return (unsigned short)(p & 0xFFFF);
#else
    return (unsigned short)f8e_sw(a) | ((unsigned short)f8e_sw(b) << 8);
#endif
}
// f32 -> bf16 bits by truncation (EXACT for values that came from fp8 e4m3)
static __device__ __forceinline__ unsigned bfpack(float lo, float hi) {
    return (__float_as_uint(lo) >> 16) | (__float_as_uint(hi) & 0xFFFF0000u);
}

// decode 8 fp8 (uint2) and accumulate UNWEIGHTED into 4 f32x2 (v_pk_add_f32)
static __device__ __forceinline__ void acc8_add(f32x2* acc, uint2 v) {
#ifdef HWF8
    acc[0] += __builtin_amdgcn_cvt_pk_f32_fp8((int)v.x, false);
    acc[1] += __builtin_amdgcn_cvt_pk_f32_fp8((int)v.x, true);
    acc[2] += __builtin_amdgcn_cvt_pk_f32_fp8((int)v.y, false);
    acc[3] += __builtin_amdgcn_cvt_pk_f32_fp8((int)v.y, true);
#else
    unsigned u[2] = {v.x, v.y};
#pragma unroll
    for (int q = 0; q < 2; q++) {
        float o[4]; f8d4(u[q], o);
        acc[2 * q]     += (f32x2){o[0], o[1]};
        acc[2 * q + 1] += (f32x2){o[2], o[3]};
    }
#endif
}

// ---------------- dtype probe (writes raw; flags derived inline) --------------
__global__ void k_probe1(const unsigned short* __restrict__ xw,
                         const int* __restrict__ ei, int* __restrict__ raw) {
    int i = blockIdx.x * 256 + threadIdx.x;    // 65536 probes
    int nan = ((xw[i] & 0x7F80u) == 0x7F80u) ? 1 : 0;
    int odd = (ei[2 * i + 1] != 0) ? 1 : 0;
    unsigned long long bn = __ballot(nan);
    unsigned long long bo = __ballot(odd);
    if ((threadIdx.x & 63) == 0) {
        if (bn) atomicAdd(&raw[0], __popcll(bn));
        if (bo) atomicAdd(&raw[1], __popcll(bo));
    }
}
// raw[0] > 0  -> x/weights are f32 ;  raw[1] == 0 -> edge_index is int64

static __device__ __forceinline__ int e_src(const int* ei, int e, int f64) {
    int v = f64 ? ei[2 * e] : ei[e];
    return min(max(v, 0), NN - 1);
}
static __device__ __forceinline__ int e_dst(const int* ei, int e, int f64) {
    int v = f64 ? ei[2 * (NE + e)] : ei[NE + e];
    return min(max(v, 0), NN - 1);
}
static __device__ __forceinline__ float ldx(const void* p, long long i, int f32) {
    return f32 ? ((const float*)p)[i] : bf2f(((const __hip_bfloat16*)p)[i]);
}

// ---- fused prep: x->fp8 P, W->bf16 frag tables, biases, zeroing (post-build) -
__global__ __launch_bounds__(256) void k_prep(const void* __restrict__ x,
                                              const void* W1, const void* b1,
                                              const void* W2, const void* b2,
                                              const void* W3, const void* b3,
                                              const void* Wa,
                                              unsigned short* W1b, unsigned short* W2b,
                                              unsigned short* W3b,
                                              float* b1f, float* b2f, float* b3f,
                                              float* Waf,
                                              unsigned char* __restrict__ P,
                                              const int* __restrict__ raw,
                                              float* colsum, float* pooled, int* wsync) {
    int t = threadIdx.x;
    int gi = blockIdx.x;
    int f = raw[0] > 0;
    if (gi < 12500) {
        int i = gi * 256 + t;                     // < 3,200,000 exactly
        unsigned pk;
        if (f) {
            float4 v = ((const float4*)x)[i];
            pk = (unsigned)f8e2(v.x, v.y) | ((unsigned)f8e2(v.z, v.w) << 16);
        } else {
            ushort4 v = ((const ushort4*)x)[i];
            pk = (unsigned)f8e2(bfu(v.x), bfu(v.y)) | ((unsigned)f8e2(bfu(v.z), bfu(v.w)) << 16);
        }
        ((unsigned*)P)[i] = pk;
        return;
    }
    int i = (gi - 12500) * 256 + t;               // 0..16383
    {
        int j = i & 7, l = (i >> 3) & 63, c = (i >> 9) & 7, kc = i >> 12;
        int k = kc * 32 + ((l >> 4)) * 8 + j;
        int col = c * 16 + (l & 15);
        W1b[i] = __bfloat16_as_ushort(__float2bfloat16(ldx(W1, k * 128 + col, f)));
        W2b[i] = __bfloat16_as_ushort(__float2bfloat16(ldx(W2, k * 128 + col, f)));
    }
    if (i < 8192) {
        int j = i & 7, l = (i >> 3) & 63, c = (i >> 9) & 3, kc = i >> 11;
        int k = kc * 32 + ((l >> 4)) * 8 + j;
        int col = c * 16 + (l & 15);
        W3b[i] = __bfloat16_as_ushort(__float2bfloat16(ldx(W3, k * 64 + col, f)));
    }
    if (i < 4096)  Waf[i] = ldx(Wa, i, f);
    if (i < 128)   { b1f[i] = ldx(b1, i, f); b2f[i] = ldx(b2, i, f); }
    if (i < 64)    b3f[i] = ldx(b3, i, f);
    if (gi == 12500) {
        if (t < 64) { colsum[t] = 0.0f; pooled[t] = 0.0f; }
        if (t == 0) *wsync = 0;
    }
    if (gi == 12501) {
        // zero pad rows NN..NR-1 of P (gathered by invalid edge slots)
        for (int z = t; z < (NR - NN) * 32; z += 256)
            ((unsigned*)(P + (size_t)NN * 128))[z] = 0u;
    }
}

// ======== CSR build: atomic-free multisplit (validated r7) ========
__global__ __launch_bounds__(256) void k_hist(const int* __restrict__ ei,
                                              int* __restrict__ ghist,
                                              const int* __restrict__ raw) {
    __shared__ int h[NB2];
    int blk = blockIdx.x, t = threadIdx.x;
    for (int i = t; i < NB2; i += 256) h[i] = 0;
    __syncthreads();
    int f64 = (raw[1] == 0);
    int e0 = blk * EPB;
    for (int i = t; i < EPB; i += 256) {
        int e = e0 + i;
        if (e < NE) atomicAdd(&h[e_dst(ei, e, f64) >> 9], 1);
    }
    __syncthreads();
    for (int i = t; i < NB2; i += 256) ghist[blk * NB2 + i] = h[i];
}

__global__ __launch_bounds__(256) void k_off(const int* __restrict__ ghist,
                                             int* __restrict__ cbase,
                                             int* __restrict__ offm,
                                             int* __restrict__ rowptr) {
    __shared__ int tot[NB2];
    int t = threadIdx.x;
    if (t < NB2) {
        int s = 0;
        for (int blk = 0; blk < NBLK; blk++) s += ghist[blk * NB2 + t];
        tot[t] = s;
    }
    __syncthreads();
    if (t == 0) {
        int run = 0;
        for (int b = 0; b < NB2; b++) { cbase[b] = run; run += tot[b]; }
        cbase[NB2] = run;
        rowptr[NN] = run;   // == NE
    }
    __syncthreads();
    if (t < NB2) {
        int run = cbase[t];
        for (int blk = 0; blk < NBLK; blk++) {
            offm[blk * NB2 + t] = run;
            run += ghist[blk * NB2 + t];
        }
    }
}

__global__ __launch_bounds__(256) void k_scatter(const int* __restrict__ ei,
                                                 const int* __restrict__ offm,
                                                 int* __restrict__ scratch,
                                                 const int* __restrict__ raw) {
    __shared__ int cur[NB2];
    int blk = blockIdx.x, t = threadIdx.x;
    for (int i = t; i < NB2; i += 256) cur[i] = offm[blk * NB2 + i];
    __syncthreads();
    int f64 = (raw[1] == 0);
    int e0 = blk * EPB;
    for (int i = t; i < EPB; i += 256) {
        int e = e0 + i;
        if (e < NE) {
            int d = e_dst(ei, e, f64);
            int s = e_src(ei, e, f64);
            int p = atomicAdd(&cur[d >> 9], 1);
            p = min(max(p, 0), NE - 1);
            scratch[p] = s | ((d & 511) << 17);
        }
    }
}

__global__ __launch_bounds__(256) void k_build(const int* __restrict__ scratch,
                                               const int* __restrict__ cbase,
                                               int* __restrict__ rowptr,
                                               float* __restrict__ dis,
                                               int* __restrict__ csr) {
    __shared__ int hist[512];
    __shared__ int base[512];
    __shared__ int sd[256];
    int b = blockIdx.x, t = threadIdx.x;
    int n0 = b << 9;
    int s0 = cbase[b], s1 = cbase[b + 1];
    hist[t] = 0; hist[t + 256] = 0;
    __syncthreads();
    for (int i = s0 + t; i < s1; i += 256) {
        int dlo = (scratch[i] >> 17) & 511;
        atomicAdd(&hist[dlo], 1);
    }
    __syncthreads();
    int v0 = hist[2 * t], v1 = hist[2 * t + 1];
    int s = v0 + v1;
    sd[t] = s; __syncthreads();
    for (int o = 1; o < 256; o <<= 1) {
        int add = (t >= o) ? sd[t - o] : 0;
        __syncthreads();
        sd[t] += add;
        __syncthreads();
    }
    int run = s0 + sd[t] - s;
    base[2 * t] = run;
    base[2 * t + 1] = run + v0;
    int n = n0 + 2 * t;
    if (n < NN) {
        rowptr[n] = run;
        dis[n] = rsqrtf((float)v0 + 1.0f);
    }
    if (n + 1 < NN) {
        rowptr[n + 1] = run + v0;
        dis[n + 1] = rsqrtf((float)v1 + 1.0f);
    }
    __syncthreads();
    for (int i = s0 + t; i < s1; i += 256) {
        int v = scratch[i];
        int dlo = (v >> 17) & 511;
        int p = atomicAdd(&base[dlo], 1);
        p = min(max(p, 0), NE - 1);
        csr[p] = v & 0x1FFFF;
    }
}

// ------------- MFMA GEMM: O[NNxCOLS] = dis[row] * (A(fp8,128) @ W) ------------
// v2: operands SWAPPED (D = W^T · P^T): each lane's acc[c][0..3] are 4
// CONSECUTIVE output columns of ONE node -> pack to u32 in-register, store
// 1 dword per c (8 stores vs 32 byte-stores). A/B fragment layouts of
// mfma_16x16x32 are mirror-symmetric, so the weight tables and A staging are
// unchanged. Row NN written as zeros (pad row gathered by invalid edge slots).
template <int NCT>    // NCT = COLS/16 (8 or 4)
__global__ __launch_bounds__(256) void k_xf_mfma(const unsigned char* __restrict__ A,
                                                 const unsigned short* __restrict__ Wf,
                                                 const float* __restrict__ dis,
                                                 unsigned char* __restrict__ O) {
    __shared__ unsigned short wl[NCT * 4 * 64 * 8];
    int t = threadIdx.x;
    int n0 = blockIdx.x * 64;
    {
        const uint4* wg = (const uint4*)Wf;
        uint4* wld = (uint4*)wl;
#pragma unroll
        for (int i = 0; i < NCT; i++) wld[i * 256 + t] = wg[i * 256 + t];
    }
    __syncthreads();
    int w = t >> 6, l = t & 63;
    int quad = l >> 4, m = l & 15;
    int node = n0 + w * 16 + m;
    const unsigned char* ap = A + (size_t)node * 128 + quad * 8;
    f32x4 acc[NCT];
#pragma unroll
    for (int c = 0; c < NCT; c++) acc[c] = (f32x4){0.0f, 0.0f, 0.0f, 0.0f};
#pragma unroll
    for (int kc = 0; kc < 4; kc++) {
        uint2 g = *(const uint2*)(ap + kc * 32);
        float o[8];
        f8d4(g.x, o); f8d4(g.y, o + 4);
        union { unsigned u[4]; bf16x8 v; } fr;
        fr.u[0] = bfpack(o[0], o[1]);
        fr.u[1] = bfpack(o[2], o[3]);
        fr.u[2] = bfpack(o[4], o[5]);
        fr.u[3] = bfpack(o[6], o[7]);
#pragma unroll
        for (int c = 0; c < NCT; c++) {
            bf16x8 bw = *(const bf16x8*)&wl[((kc * NCT + c) * 64 + l) * 8];
            // swapped: A-operand = weights (as W^T), B-operand = node rows
            acc[c] = __builtin_amdgcn_mfma_f32_16x16x32_bf16(bw, fr.v, acc[c], 0, 0, 0);
        }
    }
    // D[row=j_local][col=node_local]: this lane owns node `node`, cols
    // c*16 + quad*4 + (0..3) for each c.
    float d = (node < NN) ? dis[node] : 0.0f;     // node==NN -> store zeros
    if (node <= NN) {
        unsigned char* orow = O + (size_t)node * (NCT * 16) + quad * 4;
#pragma unroll
        for (int c = 0; c < NCT; c++) {
            unsigned pk = (unsigned)f8e2(acc[c][0] * d, acc[c][1] * d)
                        | ((unsigned)f8e2(acc[c][2] * d, acc[c][3] * d) << 16);
            *(unsigned*)(orow + c * 16) = pk;
        }
    }
}

// ---- agg, F=128: H = relu?((sum T'[src] + T'[n]) * dn + b), fp8->fp8 --------
// v5: 1 node/wave, 4 slots x 16 lanes x 8B, quad-depth inner loop (16 edges
// per iteration, MLP=4). Pad groups gather the zero row NN (branchless).
template <bool RELU>
__global__ __launch_bounds__(256) void k_agg128(const unsigned char* __restrict__ Tb,
                                                const int* __restrict__ rowptr,
                                                const int* __restrict__ csr,
                                                const float* __restrict__ dis,
                                                const float* __restrict__ bias,
                                                unsigned char* __restrict__ H) {
    int n = blockIdx.x * 4 + (threadIdx.x >> 6);
    int lane = threadIdx.x & 63;
    int r = lane >> 4;            // slot 0..3
    int f = lane & 15;            // feature group: bytes 8f..8f+7
    int fo = f << 3;
    float dn = dis[n];
    int s0 = rowptr[n], s1 = rowptr[n + 1];
    s0 = min(max(s0, 0), NE); s1 = min(max(s1, s0), NE);
    f32x2 acc[4];
#pragma unroll
    for (int k = 0; k < 4; k++) acc[k] = (f32x2){0.0f, 0.0f};
    if (r == 0) {   // self term: T'[n], weight 1.0 (dis already folded into T')
        uint2 v = *(const uint2*)(Tb + (((unsigned)n << 7) + (unsigned)fo));
        acc8_add(acc, v);
    }
    for (int base = s0; base < s1; base += 64) {
        int m = min(64, s1 - base);
        unsigned voff = (unsigned)NN << 7;          // pad -> zero row
        if (lane < m) voff = (unsigned)csr[base + lane] << 7;
        int nq = (m + 15) >> 4;                     // quads of 4 groups (16 edges)
        for (int q = 0; q < nq; q++) {
            int a0 = q * 64 + r * 4;
            unsigned vo0 = (unsigned)__builtin_amdgcn_ds_bpermute(a0,      (int)voff);
            unsigned vo1 = (unsigned)__builtin_amdgcn_ds_bpermute(a0 + 16, (int)voff);
            unsigned vo2 = (unsigned)__builtin_amdgcn_ds_bpermute(a0 + 32, (int)voff);
            unsigned vo3 = (unsigned)__builtin_amdgcn_ds_bpermute(a0 + 48, (int)voff);
            uint2 v0 = *(const uint2*)(Tb + (vo0 + (unsigned)fo));
            uint2 v1 = *(const uint2*)(Tb + (vo1 + (unsigned)fo));
            uint2 v2 = *(const uint2*)(Tb + (vo2 + (unsigned)fo));
            uint2 v3 = *(const uint2*)(Tb + (vo3 + (unsigned)fo));
            acc8_add(acc, v0);
            acc8_add(acc, v1);
            acc8_add(acc, v2);
            acc8_add(acc, v3);
        }
    }
    // reduce across the 4 slots (lane strides 16, 32): 16 ds ops total
#pragma unroll
    for (int k = 0; k < 4; k++) {
        acc[k].x += __shfl_xor(acc[k].x, 16, 64);
        acc[k].y += __shfl_xor(acc[k].y, 16, 64);
        acc[k].x += __shfl_xor(acc[k].x, 32, 64);
        acc[k].y += __shfl_xor(acc[k].y, 32, 64);
    }
    if (r == 0) {
        float4 bA = *(const float4*)(bias + fo);
        float4 bB = *(const float4*)(bias + fo + 4);
        float t[8];
        t[0] = acc[0].x * dn + bA.x; t[1] = acc[0].y * dn + bA.y;
        t[2] = acc[1].x * dn + bA.z; t[3] = acc[1].y * dn + bA.w;
        t[4] = acc[2].x * dn + bB.x; t[5] = acc[2].y * dn + bB.y;
        t[6] = acc[3].x * dn + bB.z; t[7] = acc[3].y * dn + bB.w;
        if (RELU) {
#pragma unroll
            for (int k = 0; k < 8; k++) t[k] = fmaxf(t[k], 0.0f);
        }
        unsigned lo = (unsigned)f8e2(t[0], t[1]) | ((unsigned)f8e2(t[2], t[3]) << 16);
        unsigned hi = (unsigned)f8e2(t[4], t[5]) | ((unsigned)f8e2(t[6], t[7]) << 16);
        *(uint2*)(H + (((size_t)n << 7) + (size_t)fo)) = make_uint2(lo, hi);
    }
}

// ---- agg, F=64 final: h3 = (sum T3'[src] + T3'[n]) * dn + b3 -> bf16 --------
// v5: 2 nodes/wave (32 lanes each), 4 slots x 8 lanes x 8B, quad inner loop.
__global__ __launch_bounds__(256) void k_agg64(const unsigned char* __restrict__ Tb,
                                               const int* __restrict__ rowptr,
                                               const int* __restrict__ csr,
                                               const float* __restrict__ dis,
                                               const float* __restrict__ bias,
                                               unsigned short* __restrict__ Hb) {
    int lane = threadIdx.x & 63;
    int half = lane >> 5;
    int hl = lane & 31;
    int n = blockIdx.x * 8 + (threadIdx.x >> 6) * 2 + half;
    int r = hl >> 3;              // slot 0..3
    int f = hl & 7;               // feature group: bytes 8f..8f+7
    int fo = f << 3;
    float dn = dis[n];
    int s0 = rowptr[n], s1 = rowptr[n + 1];
    s0 = min(max(s0, 0), NE); s1 = min(max(s1, s0), NE);
    f32x2 acc[4];
#pragma unroll
    for (int k = 0; k < 4; k++) acc[k] = (f32x2){0.0f, 0.0f};
    if (r == 0) {   // self term: weight 1.0 (dis folded into T3')
        uint2 v = *(const uint2*)(Tb + (((unsigned)n << 6) + (unsigned)fo));
        acc8_add(acc, v);
    }
    int ab = half << 7;           // bpermute byte base of own half (32 lanes * 4B)
    for (int base = s0; base < s1; base += 32) {
        int m = min(32, s1 - base);
        unsigned voff = (unsigned)NN << 6;          // pad -> zero row
        if (hl < m) voff = (unsigned)csr[base + hl] << 6;
        int nq = (m + 15) >> 4;                     // quads of 4 groups (16 edges)
        for (int q = 0; q < nq; q++) {
            int a0 = ab + q * 64 + r * 4;
            unsigned vo0 = (unsigned)__builtin_amdgcn_ds_bpermute(a0,      (int)voff);
            unsigned vo1 = (unsigned)__builtin_amdgcn_ds_bpermute(a0 + 16, (int)voff);
            unsigned vo2 = (unsigned)__builtin_amdgcn_ds_bpermute(a0 + 32, (int)voff);
            unsigned vo3 = (unsigned)__builtin_amdgcn_ds_bpermute(a0 + 48, (int)voff);
            uint2 v0 = *(const uint2*)(Tb + (vo0 + (unsigned)fo));
            uint2 v1 = *(const uint2*)(Tb + (vo1 + (unsigned)fo));
            uint2 v2 = *(const uint2*)(Tb + (vo2 + (unsigned)fo));
            uint2 v3 = *(const uint2*)(Tb + (vo3 + (unsigned)fo));
            acc8_add(acc, v0);
            acc8_add(acc, v1);
            acc8_add(acc, v2);
            acc8_add(acc, v3);
        }
    }
    // reduce across the 4 slots (lane strides 8, 16; stays within each half)
#pragma unroll
    for (int k = 0; k < 4; k++) {
        acc[k].x += __shfl_xor(acc[k].x, 8, 64);
        acc[k].y += __shfl_xor(acc[k].y, 8, 64);
        acc[k].x += __shfl_xor(acc[k].x, 16, 64);
        acc[k].y += __shfl_xor(acc[k].y, 16, 64);
    }
    if (r == 0) {
        float4 bA = *(const float4*)(bias + fo);
        float4 bB = *(const float4*)(bias + fo + 4);
        float t[8];
        t[0] = acc[0].x * dn + bA.x; t[1] = acc[0].y * dn + bA.y;
        t[2] = acc[1].x * dn + bA.z; t[3] = acc[1].y * dn + bA.w;
        t[4] = acc[2].x * dn + bB.x; t[5] = acc[2].y * dn + bB.y;
        t[6] = acc[3].x * dn + bB.z; t[7] = acc[3].y * dn + bB.w;
        unsigned p0 = (unsigned)__bfloat16_as_ushort(__float2bfloat16(t[0])) |
                      ((unsigned)__bfloat16_as_ushort(__float2bfloat16(t[1])) << 16);
        unsigned p1 = (unsigned)__bfloat16_as_ushort(__float2bfloat16(t[2])) |
                      ((unsigned)__bfloat16_as_ushort(__float2bfloat16(t[3])) << 16);
        unsigned p2 = (unsigned)__bfloat16_as_ushort(__float2bfloat16(t[4])) |
                      ((unsigned)__bfloat16_as_ushort(__float2bfloat16(t[5])) << 16);
        unsigned p3 = (unsigned)__bfloat16_as_ushort(__float2bfloat16(t[6])) |
                      ((unsigned)__bfloat16_as_ushort(__float2bfloat16(t[7])) << 16);
        *(uint4*)(Hb + (((size_t)n << 6) + (size_t)fo)) = make_uint4(p0, p1, p2, p3);
    }
}

// ---------------- pooling: colsum (+ fused ctx via last-block) ----------------
__global__ __launch_bounds__(512) void k_colsum(const unsigned short* __restrict__ h3,
                                                float* __restrict__ colsum,
                                                const float* __restrict__ Waf,
                                                float* __restrict__ ctx,
                                                int* __restrict__ wsync) {
    int t = threadIdx.x;
    int lane = t & 63;
    int rg = lane >> 4, cq = lane & 15;
    int wid = (blockIdx.x * 512 + t) >> 6;
    int nw = (gridDim.x * 512) >> 6;
    float a0 = 0, a1 = 0, a2 = 0, a3 = 0;
    for (int r = wid * 4 + rg; r < NN; r += nw * 4) {
        uint2 v = *(const uint2*)(h3 + ((size_t)r << 6) + cq * 4);
        a0 += bfu((unsigned short)(v.x & 0xFFFF));
        a1 += bfu((unsigned short)(v.x >> 16));
        a2 += bfu((unsigned short)(v.y & 0xFFFF));
        a3 += bfu((unsigned short)(v.y >> 16));
    }
    a0 += __shfl_xor(a0, 16, 64); a0 += __shfl_xor(a0, 32, 64);
    a1 += __shfl_xor(a1, 16, 64); a1 += __shfl_xor(a1, 32, 64);
    a2 += __shfl_xor(a2, 16, 64); a2 += __shfl_xor(a2, 32, 64);
    a3 += __shfl_xor(a3, 16, 64); a3 += __shfl_xor(a3, 32, 64);
    __shared__ float part[8][64];
    int w = t >> 6;
    if (rg == 0) {
        part[w][cq * 4 + 0] = a0;
        part[w][cq * 4 + 1] = a1;
        part[w][cq * 4 + 2] = a2;
        part[w][cq * 4 + 3] = a3;
    }
    __syncthreads();
    if (t < 64) {
        float s = 0;
#pragma unroll
        for (int i = 0; i < 8; i++) s += part[i][t];
        atomicAdd(&colsum[t], s);
    }
    // last block computes ctx = tanh(mean @ Wa)
    __shared__ int lastf;
    __syncthreads();
    if (t == 0) {
        __threadfence();
        int old = atomicAdd(wsync, 1);
        lastf = (old == (int)gridDim.x - 1) ? 1 : 0;
    }
    __syncthreads();
    if (lastf) {
        __shared__ float ms[64];
        if (t < 64) {
            __threadfence();
            ms[t] = atomicAdd(&colsum[t], 0.0f) * (1.0f / NN);  // coherent read
        }
        __syncthreads();
        if (t < 64) {
            float s = 0.0f;
#pragma unroll
            for (int k = 0; k < 64; k++) s += ms[k] * Waf[k * 64 + t];
            ctx[t] = tanhf(s);
        }
    }
}

// -------- pooling pass 2: attention pool + fused h3 -> out copy ---------------
__global__ __launch_bounds__(512) void k_pool(const unsigned short* __restrict__ h3,
                                              const float* __restrict__ ctx,
                                              float* __restrict__ pooled,
                                              void* __restrict__ out,
                                              const int* __restrict__ raw) {
    int t = threadIdx.x;
    int lane = t & 63;
    int rg = lane >> 4, cq = lane & 15;
    int wid = (blockIdx.x * 512 + t) >> 6;
    int nw = (gridDim.x * 512) >> 6;
    int f32o = raw[0] > 0;
    float c0 = ctx[cq * 4 + 0], c1 = ctx[cq * 4 + 1];
    float c2 = ctx[cq * 4 + 2], c3 = ctx[cq * 4 + 3];
    float q0 = 0, q1 = 0, q2 = 0, q3 = 0;
    for (int r = wid * 4 + rg; r < NN; r += nw * 4) {
        uint2 v = *(const uint2*)(h3 + ((size_t)r << 6) + cq * 4);
        float x0 = bfu((unsigned short)(v.x & 0xFFFF));
        float x1 = bfu((unsigned short)(v.x >> 16));
        float x2 = bfu((unsigned short)(v.y & 0xFFFF));
        float x3 = bfu((unsigned short)(v.y >> 16));
        // fused output write (h3 part of out); T3' scratch in d_out is dead here
        if (f32o) {
            *(float4*)((float*)out + ((size_t)r << 6) + cq * 4) =
                make_float4(x0, x1, x2, x3);
        } else {
            *(uint2*)((unsigned short*)out + ((size_t)r << 6) + cq * 4) = v;
        }
        float p = x0 * c0 + x1 * c1 + x2 * c2 + x3 * c3;
        p += __shfl_xor(p, 1, 64);
        p += __shfl_xor(p, 2, 64);
        p += __shfl_xor(p, 4, 64);
        p += __shfl_xor(p, 8, 64);
        float sc = 1.0f / (1.0f + expf(-p));
        q0 += sc * x0; q1 += sc * x1; q2 += sc * x2; q3 += sc * x3;
    }
    q0 += __shfl_xor(q0, 16, 64); q0 += __shfl_xor(q0, 32, 64);
    q1 += __shfl_xor(q1, 16, 64); q1 += __shfl_xor(q1, 32, 64);
    q2 += __shfl_xor(q2, 16, 64); q2 += __shfl_xor(q2, 32, 64);
    q3 += __shfl_xor(q3, 16, 64); q3 += __shfl_xor(q3, 32, 64);
    __shared__ float part[8][64];
    int w = t >> 6;
    if (rg == 0) {
        part[w][cq * 4 + 0] = q0;
        part[w][cq * 4 + 1] = q1;
        part[w][cq * 4 + 2] = q2;
        part[w][cq * 4 + 3] = q3;
    }
    __syncthreads();
    if (t < 64) {
        float s = 0;
#pragma unroll
        for (int i = 0; i < 8; i++) s += part[i][t];
        atomicAdd(&pooled[t], s);
    }
}

// ---------------- tail: write the 64 pooled values ----------------------------
__global__ void k_tail(const float* __restrict__ pooled, void* __restrict__ out,
                       const int* __restrict__ raw) {
    int j = threadIdx.x;   // 64 threads
    if (raw[0] > 0) {
        ((float*)out)[6400000 + j] = pooled[j];
    } else {
        ((unsigned short*)out)[6400000 + j] =
            __bfloat16_as_ushort(__float2bfloat16(pooled[j]));
    }
}

// ---------------- workspace layout (~21.5 MB) ----------------
static constexpr size_t AL(size_t x) { return (x + 255) & ~size_t(255); }
static constexpr size_t OFF_FLAGS  = 0;
static constexpr size_t OFF_RAW    = OFF_FLAGS + 256;
static constexpr size_t OFF_GHIST  = OFF_RAW + 256;
static constexpr size_t OFF_OFFM   = OFF_GHIST + AL((size_t)NBLK * NB2 * 4);
static constexpr size_t OFF_CBASE  = OFF_OFFM + AL((size_t)NBLK * NB2 * 4);
static constexpr size_t OFF_ROWPTR = OFF_CBASE + AL((NB2 + 1) * 4);
static constexpr size_t OFF_CSR    = OFF_ROWPTR + AL((NN + 1) * 4);
static constexpr size_t OFF_DIS    = OFF_CSR + AL((size_t)NE * 4);
static constexpr size_t OFF_P      = OFF_DIS + AL(NN * 4);     // NR*128 fp8; also scatter scratch; also bf16 h3
static constexpr size_t OFF_W1B    = OFF_P + AL((size_t)NR * 128);
static constexpr size_t OFF_W2B    = OFF_W1B + AL(16384 * 2);
static constexpr size_t OFF_W3B    = OFF_W2B + AL(16384 * 2);
static constexpr size_t OFF_B1F    = OFF_W3B + AL(8192 * 2);
static constexpr size_t OFF_B2F    = OFF_B1F + AL(128 * 4);
static constexpr size_t OFF_B3F    = OFF_B2F + AL(128 * 4);
static constexpr size_t OFF_WAF    = OFF_B3F + AL(64 * 4);
static constexpr size_t OFF_COLSUM = OFF_WAF + AL(4096 * 4);
static constexpr size_t OFF_POOLED = OFF_COLSUM + AL(64 * 4);
static constexpr size_t OFF_CTX    = OFF_POOLED + AL(64 * 4);
static constexpr size_t OFF_SYNC   = OFF_CTX + AL(64 * 4);

extern "C" void kernel_launch(void* const* d_in, const int* in_sizes, int n_in,
                              void* d_out, int out_size, void* d_ws, size_t ws_size,
                              hipStream_t stream) {
    const int* ei = (const int*)d_in[0];
    const void* x  = d_in[1];
    const void* W1 = d_in[2];
    const void* b1 = d_in[3];
    const void* W2 = d_in[4];
    const void* b2 = d_in[5];
    const void* W3 = d_in[6];
    const void* b3 = d_in[7];
    const void* Wa = d_in[8];

    char* ws = (char*)d_ws;
    int*   raw    = (int*)(ws + OFF_RAW);
    int*   ghist  = (int*)(ws + OFF_GHIST);
    int*   offm   = (int*)(ws + OFF_OFFM);
    int*   cbase  = (int*)(ws + OFF_CBASE);
    int*   rowptr = (int*)(ws + OFF_ROWPTR);
    int*   csr    = (int*)(ws + OFF_CSR);
    float* dis    = (float*)(ws + OFF_DIS);
    unsigned char*  P    = (unsigned char*)(ws + OFF_P);
    int*            scrA = (int*)(ws + OFF_P);
    unsigned short* Hb   = (unsigned short*)(ws + OFF_P);
    unsigned short* W1b = (unsigned short*)(ws + OFF_W1B);
    unsigned short* W2b = (unsigned short*)(ws + OFF_W2B);
    unsigned short* W3b = (unsigned short*)(ws + OFF_W3B);
    float* b1f    = (float*)(ws + OFF_B1F);
    float* b2f    = (float*)(ws + OFF_B2F);
    float* b3f    = (float*)(ws + OFF_B3F);
    float* Waf    = (float*)(ws + OFF_WAF);
    float* colsum = (float*)(ws + OFF_COLSUM);
    float* pooled = (float*)(ws + OFF_POOLED);
    float* ctx    = (float*)(ws + OFF_CTX);
    int*   wsync  = (int*)(ws + OFF_SYNC);

    unsigned char* Q = (unsigned char*)d_out;   // d_out doubles as T-scratch (12.8 MB)

    hipMemsetAsync(raw, 0, 256, stream);

    k_probe1<<<256, 256, 0, stream>>>((const unsigned short*)x, ei, raw);

    // atomic-free CSR build (uses P region as scatter scratch)
    k_hist<<<NBLK, 256, 0, stream>>>(ei, ghist, raw);
    k_off<<<1, 256, 0, stream>>>(ghist, cbase, offm, rowptr);
    k_scatter<<<NBLK, 256, 0, stream>>>(ei, offm, scrA, raw);
    k_build<<<NB2, 256, 0, stream>>>(scrA, cbase, rowptr, dis, csr);

    // fused prep: x->fp8 P (overwrites scratch), W tables, biases, zeroing
    k_prep<<<12564, 256, 0, stream>>>(x, W1, b1, W2, b2, W3, b3, Wa,
                                      W1b, W2b, W3b, b1f, b2f, b3f, Waf,
                                      P, raw, colsum, pooled, wsync);

    // L1: T' = dis*(P@W1) (Q, MFMA) ; P = relu((sum+self)*dn + b1)
    k_xf_mfma<8><<<NR / 64, 256, 0, stream>>>(P, W1b, dis, Q);
    k_agg128<true><<<NN / 4, 256, 0, stream>>>(Q, rowptr, csr, dis, b1f, P);
    // L2
    k_xf_mfma<8><<<NR / 64, 256, 0, stream>>>(P, W2b, dis, Q);
    k_agg128<true><<<NN / 4, 256, 0, stream>>>(Q, rowptr, csr, dis, b2f, P);
    // L3: T3' = dis*(P@W3) (Q, 64 cols) ; Hb = (sum+self)*dn + b3 (bf16)
    k_xf_mfma<4><<<NR / 64, 256, 0, stream>>>(P, W3b, dis, Q);
    k_agg64<<<NN / 8, 256, 0, stream>>>(Q, rowptr, csr, dis, b3f, Hb);

    // attention pooling (ctx fused into colsum's last block)
    k_colsum<<<256, 512, 0, stream>>>(Hb, colsum, Waf, ctx, wsync);
    k_pool<<<256, 512, 0, stream>>>(Hb, ctx, pooled, d_out, raw);
    k_tail<<<1, 64, 0, stream>>>(pooled, d_out, raw);
}

// Round 7
// 367.278 us; speedup vs baseline: 1.3273x; 1.0703x over previous
//
#include <hip/hip_runtime.h>
#include <hip/hip_bf16.h>

#define NN 100000
#define NE 1600000
#define NR 100032            // NN rounded to 64-row blocks (table alloc rows)
#define NB2 196              // coarse buckets = ceil(NN/512)
#define NBLK 391             // hist/scatter blocks = ceil(NE/4096)
#define EPB 4096             // edges per hist/scatter block

#if defined(__has_builtin)
#  if __has_builtin(__builtin_amdgcn_cvt_pk_f32_fp8) && \
      __has_builtin(__builtin_amdgcn_cvt_pk_fp8_f32) && \
      __has_builtin(__builtin_amdgcn_cvt_f32_fp8)
#    define HWF8 1
#  endif
#endif

typedef float f32x2 __attribute__((ext_vector_type(2)));
typedef float f32x4 __attribute__((ext_vector_type(4)));
typedef short bf16x8 __attribute__((ext_vector_type(8)));

static __device__ __forceinline__ float bf2f(__hip_bfloat16 v) { return __bfloat162float(v); }
static __device__ __forceinline__ float bfu(unsigned short w) {
    return __uint_as_float((unsigned)w << 16);
}

// ---------------- fp8 e4m3 software codec (fallback, validated r3/r4) ---------
static __device__ __forceinline__ float f8d_sw(unsigned b) {
    unsigned e = (b >> 3) & 15u, m = b & 7u;
    float mag;
    if (e == 0) mag = (float)m * 0.001953125f;
    else        mag = __uint_as_float(((e + 120u) << 23) | (m << 20));
    return (b & 0x80u) ? -mag : mag;
}
static __device__ __forceinline__ unsigned char f8e_sw(float x) {
    unsigned u = __float_as_uint(x);
    unsigned s = (u >> 31) << 7;
    unsigned au = u & 0x7fffffffu;
    if (au >= 0x43E00000u) return (unsigned char)(s | 0x7Eu);
    if (au <  0x3A800000u) return (unsigned char)s;
    if (au <  0x3C800000u) {
        float a = __uint_as_float(au);
        int m = (int)rintf(a * 512.0f);
        if (m >= 8) return (unsigned char)(s | 0x08u);
        return (unsigned char)(s | (unsigned)m);
    }
    au += 0x80000u;
    if (au >= 0x43E00000u) return (unsigned char)(s | 0x7Eu);
    unsigned e = (au >> 23) - 120u;
    unsigned m = (au >> 20) & 7u;
    return (unsigned char)(s | (e << 3) | m);
}

// ---------------- fp8 helpers (HW if available) ----------------
static __device__ __forceinline__ void f8d4(unsigned u, float* o) {
#ifdef HWF8
    f32x2 lo = __builtin_amdgcn_cvt_pk_f32_fp8((int)u, false);
    f32x2 hi = __builtin_amdgcn_cvt_pk_f32_fp8((int)u, true);
    o[0] = lo.x; o[1] = lo.y; o[2] = hi.x; o[3] = hi.y;
#else
    o[0] = f8d_sw(u & 255u); o[1] = f8d_sw((u >> 8) & 255u);
    o[2] = f8d_sw((u >> 16) & 255u); o[3] = f8d_sw(u >> 24);
#endif
}
static __device__ __forceinline__ unsigned short f8e2(float a, float b) {
#ifdef HWF8
    float ca = fminf(fmaxf(a, -448.0f), 448.0f);
    float cb = fminf(fmaxf(b, -448.0f), 448.0f);
    int p = __builtin_amdgcn_cvt_pk_fp8_f32(ca, cb, 0, false);
    return (unsigned short)(p & 0xFFFF);
#else
    return (unsigned short)f8e_sw(a) | ((unsigned short)f8e_sw(b) << 8);
#endif
}
// f32 -> bf16 bits by truncation (EXACT for values that came from fp8 e4m3)
static __device__ __forceinline__ unsigned bfpack(float lo, float hi) {
    return (__float_as_uint(lo) >> 16) | (__float_as_uint(hi) & 0xFFFF0000u);
}

// decode 8 fp8 (uint2) and accumulate UNWEIGHTED into 4 f32x2 (v_pk_add_f32)
static __device__ __forceinline__ void acc8_add(f32x2* acc, uint2 v) {
#ifdef HWF8
    acc[0] += __builtin_amdgcn_cvt_pk_f32_fp8((int)v.x, false);
    acc[1] += __builtin_amdgcn_cvt_pk_f32_fp8((int)v.x, true);
    acc[2] += __builtin_amdgcn_cvt_pk_f32_fp8((int)v.y, false);
    acc[3] += __builtin_amdgcn_cvt_pk_f32_fp8((int)v.y, true);
#else
    unsigned u[2] = {v.x, v.y};
#pragma unroll
    for (int q = 0; q < 2; q++) {
        float o[4]; f8d4(u[q], o);
        acc[2 * q]     += (f32x2){o[0], o[1]};
        acc[2 * q + 1] += (f32x2){o[2], o[3]};
    }
#endif
}

// ---------------- dtype probe (writes raw; flags derived inline) --------------
__global__ void k_probe1(const unsigned short* __restrict__ xw,
                         const int* __restrict__ ei, int* __restrict__ raw) {
    int i = blockIdx.x * 256 + threadIdx.x;    // 65536 probes
    int nan = ((xw[i] & 0x7F80u) == 0x7F80u) ? 1 : 0;
    int odd = (ei[2 * i + 1] != 0) ? 1 : 0;
    unsigned long long bn = __ballot(nan);
    unsigned long long bo = __ballot(odd);
    if ((threadIdx.x & 63) == 0) {
        if (bn) atomicAdd(&raw[0], __popcll(bn));
        if (bo) atomicAdd(&raw[1], __popcll(bo));
    }
}
// raw[0] > 0  -> x/weights are f32 ;  raw[1] == 0 -> edge_index is int64

static __device__ __forceinline__ int e_src(const int* ei, int e, int f64) {
    int v = f64 ? ei[2 * e] : ei[e];
    return min(max(v, 0), NN - 1);
}
static __device__ __forceinline__ int e_dst(const int* ei, int e, int f64) {
    int v = f64 ? ei[2 * (NE + e)] : ei[NE + e];
    return min(max(v, 0), NN - 1);
}
static __device__ __forceinline__ float ldx(const void* p, long long i, int f32) {
    return f32 ? ((const float*)p)[i] : bf2f(((const __hip_bfloat16*)p)[i]);
}

// ---- fused prep: x->fp8 P, W->bf16 frag tables, biases, zeroing (post-build) -
__global__ __launch_bounds__(256) void k_prep(const void* __restrict__ x,
                                              const void* W1, const void* b1,
                                              const void* W2, const void* b2,
                                              const void* W3, const void* b3,
                                              const void* Wa,
                                              unsigned short* W1b, unsigned short* W2b,
                                              unsigned short* W3b,
                                              float* b1f, float* b2f, float* b3f,
                                              float* Waf,
                                              unsigned char* __restrict__ P,
                                              const int* __restrict__ raw,
                                              float* colsum, float* pooled, int* wsync) {
    int t = threadIdx.x;
    int gi = blockIdx.x;
    int f = raw[0] > 0;
    if (gi < 12500) {
        int i = gi * 256 + t;                     // < 3,200,000 exactly
        unsigned pk;
        if (f) {
            float4 v = ((const float4*)x)[i];
            pk = (unsigned)f8e2(v.x, v.y) | ((unsigned)f8e2(v.z, v.w) << 16);
        } else {
            ushort4 v = ((const ushort4*)x)[i];
            pk = (unsigned)f8e2(bfu(v.x), bfu(v.y)) | ((unsigned)f8e2(bfu(v.z), bfu(v.w)) << 16);
        }
        ((unsigned*)P)[i] = pk;
        return;
    }
    int i = (gi - 12500) * 256 + t;               // 0..16383
    {
        int j = i & 7, l = (i >> 3) & 63, c = (i >> 9) & 7, kc = i >> 12;
        int k = kc * 32 + ((l >> 4)) * 8 + j;
        int col = c * 16 + (l & 15);
        W1b[i] = __bfloat16_as_ushort(__float2bfloat16(ldx(W1, k * 128 + col, f)));
        W2b[i] = __bfloat16_as_ushort(__float2bfloat16(ldx(W2, k * 128 + col, f)));
    }
    if (i < 8192) {
        int j = i & 7, l = (i >> 3) & 63, c = (i >> 9) & 3, kc = i >> 11;
        int k = kc * 32 + ((l >> 4)) * 8 + j;
        int col = c * 16 + (l & 15);
        W3b[i] = __bfloat16_as_ushort(__float2bfloat16(ldx(W3, k * 64 + col, f)));
    }
    if (i < 4096)  Waf[i] = ldx(Wa, i, f);
    if (i < 128)   { b1f[i] = ldx(b1, i, f); b2f[i] = ldx(b2, i, f); }
    if (i < 64)    b3f[i] = ldx(b3, i, f);
    if (gi == 12500) {
        if (t < 64) { colsum[t] = 0.0f; pooled[t] = 0.0f; }
        if (t == 0) { wsync[0] = 0; wsync[1] = 0; }
    }
    if (gi == 12501) {
        // zero pad rows NN..NR-1 of P (gathered by invalid edge slots)
        for (int z = t; z < (NR - NN) * 32; z += 256)
            ((unsigned*)(P + (size_t)NN * 128))[z] = 0u;
    }
}

// ======== CSR build: atomic-free multisplit ========
__global__ __launch_bounds__(256) void k_hist(const int* __restrict__ ei,
                                              int* __restrict__ ghist,
                                              const int* __restrict__ raw) {
    __shared__ int h[NB2];
    int blk = blockIdx.x, t = threadIdx.x;
    for (int i = t; i < NB2; i += 256) h[i] = 0;
    __syncthreads();
    int f64 = (raw[1] == 0);
    int e0 = blk * EPB;
    for (int i = t; i < EPB; i += 256) {
        int e = e0 + i;
        if (e < NE) atomicAdd(&h[e_dst(ei, e, f64) >> 9], 1);
    }
    __syncthreads();
    for (int i = t; i < NB2; i += 256) ghist[blk * NB2 + i] = h[i];
}

// v2: parallel per-bucket scan over the 391 hist blocks (196 blocks x 512 thr).
// Writes offm WITHOUT the cbase base (k_scatter adds it) and tot[b].
__global__ __launch_bounds__(512) void k_offA(const int* __restrict__ ghist,
                                              int* __restrict__ tot,
                                              int* __restrict__ offm) {
    int b = blockIdx.x;               // bucket 0..NB2-1
    int t = threadIdx.x;              // 0..511 (covers NBLK=391)
    __shared__ int wsum[8];
    __shared__ int woff[8];
    int v = (t < NBLK) ? ghist[t * NB2 + b] : 0;
    int s = v;
#pragma unroll
    for (int o = 1; o < 64; o <<= 1) {
        int u = __shfl_up(s, o, 64);
        if ((t & 63) >= o) s += u;
    }
    int w = t >> 6;
    if ((t & 63) == 63) wsum[w] = s;
    __syncthreads();
    if (t == 0) {
        int run = 0;
#pragma unroll
        for (int i = 0; i < 8; i++) { woff[i] = run; run += wsum[i]; }
        tot[b] = run;
    }
    __syncthreads();
    if (t < NBLK) offm[t * NB2 + b] = s - v + woff[w];   // exclusive prefix
}

__global__ void k_offB(const int* __restrict__ tot,
                       int* __restrict__ cbase, int* __restrict__ rowptr) {
    if (threadIdx.x == 0) {
        int run = 0;
        for (int b = 0; b < NB2; b++) { cbase[b] = run; run += tot[b]; }
        cbase[NB2] = run;
        rowptr[NN] = run;   // == NE
    }
}

__global__ __launch_bounds__(256) void k_scatter(const int* __restrict__ ei,
                                                 const int* __restrict__ offm,
                                                 const int* __restrict__ cbase,
                                                 int* __restrict__ scratch,
                                                 const int* __restrict__ raw) {
    __shared__ int cur[NB2];
    int blk = blockIdx.x, t = threadIdx.x;
    for (int i = t; i < NB2; i += 256) cur[i] = offm[blk * NB2 + i] + cbase[i];
    __syncthreads();
    int f64 = (raw[1] == 0);
    int e0 = blk * EPB;
    for (int i = t; i < EPB; i += 256) {
        int e = e0 + i;
        if (e < NE) {
            int d = e_dst(ei, e, f64);
            int s = e_src(ei, e, f64);
            int p = atomicAdd(&cur[d >> 9], 1);
            p = min(max(p, 0), NE - 1);
            scratch[p] = s | ((d & 511) << 17);
        }
    }
}

__global__ __launch_bounds__(256) void k_build(const int* __restrict__ scratch,
                                               const int* __restrict__ cbase,
                                               int* __restrict__ rowptr,
                                               float* __restrict__ dis,
                                               int* __restrict__ csr) {
    __shared__ int hist[512];
    __shared__ int base[512];
    __shared__ int sd[256];
    int b = blockIdx.x, t = threadIdx.x;
    int n0 = b << 9;
    int s0 = cbase[b], s1 = cbase[b + 1];
    hist[t] = 0; hist[t + 256] = 0;
    __syncthreads();
    for (int i = s0 + t; i < s1; i += 256) {
        int dlo = (scratch[i] >> 17) & 511;
        atomicAdd(&hist[dlo], 1);
    }
    __syncthreads();
    int v0 = hist[2 * t], v1 = hist[2 * t + 1];
    int s = v0 + v1;
    sd[t] = s; __syncthreads();
    for (int o = 1; o < 256; o <<= 1) {
        int add = (t >= o) ? sd[t - o] : 0;
        __syncthreads();
        sd[t] += add;
        __syncthreads();
    }
    int run = s0 + sd[t] - s;
    base[2 * t] = run;
    base[2 * t + 1] = run + v0;
    int n = n0 + 2 * t;
    if (n < NN) {
        rowptr[n] = run;
        dis[n] = rsqrtf((float)v0 + 1.0f);
    }
    if (n + 1 < NN) {
        rowptr[n + 1] = run + v0;
        dis[n + 1] = rsqrtf((float)v1 + 1.0f);
    }
    __syncthreads();
    for (int i = s0 + t; i < s1; i += 256) {
        int v = scratch[i];
        int dlo = (v >> 17) & 511;
        int p = atomicAdd(&base[dlo], 1);
        p = min(max(p, 0), NE - 1);
        csr[p] = v & 0x1FFFF;
    }
}

// ------------- MFMA GEMM: O[NNxCOLS] = dis[row] * (A(fp8,128) @ W) ------------
// Operands swapped (D = W^T · P^T): each lane's acc[c][0..3] are 4 consecutive
// output columns of one node -> pack to u32, 1 dword store per c.
template <int NCT>    // NCT = COLS/16 (8 or 4)
__global__ __launch_bounds__(256) void k_xf_mfma(const unsigned char* __restrict__ A,
                                                 const unsigned short* __restrict__ Wf,
                                                 const float* __restrict__ dis,
                                                 unsigned char* __restrict__ O) {
    __shared__ unsigned short wl[NCT * 4 * 64 * 8];
    int t = threadIdx.x;
    int n0 = blockIdx.x * 64;
    {
        const uint4* wg = (const uint4*)Wf;
        uint4* wld = (uint4*)wl;
#pragma unroll
        for (int i = 0; i < NCT; i++) wld[i * 256 + t] = wg[i * 256 + t];
    }
    __syncthreads();
    int w = t >> 6, l = t & 63;
    int quad = l >> 4, m = l & 15;
    int node = n0 + w * 16 + m;
    const unsigned char* ap = A + (size_t)node * 128 + quad * 8;
    f32x4 acc[NCT];
#pragma unroll
    for (int c = 0; c < NCT; c++) acc[c] = (f32x4){0.0f, 0.0f, 0.0f, 0.0f};
#pragma unroll
    for (int kc = 0; kc < 4; kc++) {
        uint2 g = *(const uint2*)(ap + kc * 32);
        float o[8];
        f8d4(g.x, o); f8d4(g.y, o + 4);
        union { unsigned u[4]; bf16x8 v; } fr;
        fr.u[0] = bfpack(o[0], o[1]);
        fr.u[1] = bfpack(o[2], o[3]);
        fr.u[2] = bfpack(o[4], o[5]);
        fr.u[3] = bfpack(o[6], o[7]);
#pragma unroll
        for (int c = 0; c < NCT; c++) {
            bf16x8 bw = *(const bf16x8*)&wl[((kc * NCT + c) * 64 + l) * 8];
            acc[c] = __builtin_amdgcn_mfma_f32_16x16x32_bf16(bw, fr.v, acc[c], 0, 0, 0);
        }
    }
    float d = (node < NN) ? dis[node] : 0.0f;     // node==NN -> store zeros
    if (node <= NN) {
        unsigned char* orow = O + (size_t)node * (NCT * 16) + quad * 4;
#pragma unroll
        for (int c = 0; c < NCT; c++) {
            unsigned pk = (unsigned)f8e2(acc[c][0] * d, acc[c][1] * d)
                        | ((unsigned)f8e2(acc[c][2] * d, acc[c][3] * d) << 16);
            *(unsigned*)(orow + c * 16) = pk;
        }
    }
}

// ---- agg, F=128: H = relu?((sum T'[src] + T'[n]) * dn + b), fp8->fp8 --------
template <bool RELU>
__global__ __launch_bounds__(256) void k_agg128(const unsigned char* __restrict__ Tb,
                                                const int* __restrict__ rowptr,
                                                const int* __restrict__ csr,
                                                const float* __restrict__ dis,
                                                const float* __restrict__ bias,
                                                unsigned char* __restrict__ H) {
    int n = blockIdx.x * 4 + (threadIdx.x >> 6);
    int lane = threadIdx.x & 63;
    int r = lane >> 4;            // slot 0..3
    int f = lane & 15;            // feature group: bytes 8f..8f+7
    int fo = f << 3;
    float dn = dis[n];
    int s0 = rowptr[n], s1 = rowptr[n + 1];
    s0 = min(max(s0, 0), NE); s1 = min(max(s1, s0), NE);
    f32x2 acc[4];
#pragma unroll
    for (int k = 0; k < 4; k++) acc[k] = (f32x2){0.0f, 0.0f};
    if (r == 0) {   // self term: T'[n], weight 1.0 (dis already folded into T')
        uint2 v = *(const uint2*)(Tb + (((unsigned)n << 7) + (unsigned)fo));
        acc8_add(acc, v);
    }
    for (int base = s0; base < s1; base += 64) {
        int m = min(64, s1 - base);
        unsigned voff = (unsigned)NN << 7;          // pad -> zero row
        if (lane < m) voff = (unsigned)csr[base + lane] << 7;
        int nq = (m + 15) >> 4;                     // quads of 4 groups (16 edges)
        for (int q = 0; q < nq; q++) {
            int a0 = q * 64 + r * 4;
            unsigned vo0 = (unsigned)__builtin_amdgcn_ds_bpermute(a0,      (int)voff);
            unsigned vo1 = (unsigned)__builtin_amdgcn_ds_bpermute(a0 + 16, (int)voff);
            unsigned vo2 = (unsigned)__builtin_amdgcn_ds_bpermute(a0 + 32, (int)voff);
            unsigned vo3 = (unsigned)__builtin_amdgcn_ds_bpermute(a0 + 48, (int)voff);
            uint2 v0 = *(const uint2*)(Tb + (vo0 + (unsigned)fo));
            uint2 v1 = *(const uint2*)(Tb + (vo1 + (unsigned)fo));
            uint2 v2 = *(const uint2*)(Tb + (vo2 + (unsigned)fo));
            uint2 v3 = *(const uint2*)(Tb + (vo3 + (unsigned)fo));
            acc8_add(acc, v0);
            acc8_add(acc, v1);
            acc8_add(acc, v2);
            acc8_add(acc, v3);
        }
    }
#pragma unroll
    for (int k = 0; k < 4; k++) {
        acc[k].x += __shfl_xor(acc[k].x, 16, 64);
        acc[k].y += __shfl_xor(acc[k].y, 16, 64);
        acc[k].x += __shfl_xor(acc[k].x, 32, 64);
        acc[k].y += __shfl_xor(acc[k].y, 32, 64);
    }
    if (r == 0) {
        float4 bA = *(const float4*)(bias + fo);
        float4 bB = *(const float4*)(bias + fo + 4);
        float t[8];
        t[0] = acc[0].x * dn + bA.x; t[1] = acc[0].y * dn + bA.y;
        t[2] = acc[1].x * dn + bA.z; t[3] = acc[1].y * dn + bA.w;
        t[4] = acc[2].x * dn + bB.x; t[5] = acc[2].y * dn + bB.y;
        t[6] = acc[3].x * dn + bB.z; t[7] = acc[3].y * dn + bB.w;
        if (RELU) {
#pragma unroll
            for (int k = 0; k < 8; k++) t[k] = fmaxf(t[k], 0.0f);
        }
        unsigned lo = (unsigned)f8e2(t[0], t[1]) | ((unsigned)f8e2(t[2], t[3]) << 16);
        unsigned hi = (unsigned)f8e2(t[4], t[5]) | ((unsigned)f8e2(t[6], t[7]) << 16);
        *(uint2*)(H + (((size_t)n << 7) + (size_t)fo)) = make_uint2(lo, hi);
    }
}

// ---- agg, F=64 final: h3 = (sum T3'[src] + T3'[n]) * dn + b3 -> bf16 --------
__global__ __launch_bounds__(256) void k_agg64(const unsigned char* __restrict__ Tb,
                                               const int* __restrict__ rowptr,
                                               const int* __restrict__ csr,
                                               const float* __restrict__ dis,
                                               const float* __restrict__ bias,
                                               unsigned short* __restrict__ Hb) {
    int lane = threadIdx.x & 63;
    int half = lane >> 5;
    int hl = lane & 31;
    int n = blockIdx.x * 8 + (threadIdx.x >> 6) * 2 + half;
    int r = hl >> 3;              // slot 0..3
    int f = hl & 7;               // feature group: bytes 8f..8f+7
    int fo = f << 3;
    float dn = dis[n];
    int s0 = rowptr[n], s1 = rowptr[n + 1];
    s0 = min(max(s0, 0), NE); s1 = min(max(s1, s0), NE);
    f32x2 acc[4];
#pragma unroll
    for (int k = 0; k < 4; k++) acc[k] = (f32x2){0.0f, 0.0f};
    if (r == 0) {   // self term: weight 1.0 (dis folded into T3')
        uint2 v = *(const uint2*)(Tb + (((unsigned)n << 6) + (unsigned)fo));
        acc8_add(acc, v);
    }
    int ab = half << 7;           // bpermute byte base of own half (32 lanes * 4B)
    for (int base = s0; base < s1; base += 32) {
        int m = min(32, s1 - base);
        unsigned voff = (unsigned)NN << 6;          // pad -> zero row
        if (hl < m) voff = (unsigned)csr[base + hl] << 6;
        int nq = (m + 15) >> 4;                     // quads of 4 groups (16 edges)
        for (int q = 0; q < nq; q++) {
            int a0 = ab + q * 64 + r * 4;
            unsigned vo0 = (unsigned)__builtin_amdgcn_ds_bpermute(a0,      (int)voff);
            unsigned vo1 = (unsigned)__builtin_amdgcn_ds_bpermute(a0 + 16, (int)voff);
            unsigned vo2 = (unsigned)__builtin_amdgcn_ds_bpermute(a0 + 32, (int)voff);
            unsigned vo3 = (unsigned)__builtin_amdgcn_ds_bpermute(a0 + 48, (int)voff);
            uint2 v0 = *(const uint2*)(Tb + (vo0 + (unsigned)fo));
            uint2 v1 = *(const uint2*)(Tb + (vo1 + (unsigned)fo));
            uint2 v2 = *(const uint2*)(Tb + (vo2 + (unsigned)fo));
            uint2 v3 = *(const uint2*)(Tb + (vo3 + (unsigned)fo));
            acc8_add(acc, v0);
            acc8_add(acc, v1);
            acc8_add(acc, v2);
            acc8_add(acc, v3);
        }
    }
#pragma unroll
    for (int k = 0; k < 4; k++) {
        acc[k].x += __shfl_xor(acc[k].x, 8, 64);
        acc[k].y += __shfl_xor(acc[k].y, 8, 64);
        acc[k].x += __shfl_xor(acc[k].x, 16, 64);
        acc[k].y += __shfl_xor(acc[k].y, 16, 64);
    }
    if (r == 0) {
        float4 bA = *(const float4*)(bias + fo);
        float4 bB = *(const float4*)(bias + fo + 4);
        float t[8];
        t[0] = acc[0].x * dn + bA.x; t[1] = acc[0].y * dn + bA.y;
        t[2] = acc[1].x * dn + bA.z; t[3] = acc[1].y * dn + bA.w;
        t[4] = acc[2].x * dn + bB.x; t[5] = acc[2].y * dn + bB.y;
        t[6] = acc[3].x * dn + bB.z; t[7] = acc[3].y * dn + bB.w;
        unsigned p0 = (unsigned)__bfloat16_as_ushort(__float2bfloat16(t[0])) |
                      ((unsigned)__bfloat16_as_ushort(__float2bfloat16(t[1])) << 16);
        unsigned p1 = (unsigned)__bfloat16_as_ushort(__float2bfloat16(t[2])) |
                      ((unsigned)__bfloat16_as_ushort(__float2bfloat16(t[3])) << 16);
        unsigned p2 = (unsigned)__bfloat16_as_ushort(__float2bfloat16(t[4])) |
                      ((unsigned)__bfloat16_as_ushort(__float2bfloat16(t[5])) << 16);
        unsigned p3 = (unsigned)__bfloat16_as_ushort(__float2bfloat16(t[6])) |
                      ((unsigned)__bfloat16_as_ushort(__float2bfloat16(t[7])) << 16);
        *(uint4*)(Hb + (((size_t)n << 6) + (size_t)fo)) = make_uint4(p0, p1, p2, p3);
    }
}

// ---------------- pooling: colsum (+ fused ctx via last-block) ----------------
__global__ __launch_bounds__(512) void k_colsum(const unsigned short* __restrict__ h3,
                                                float* __restrict__ colsum,
                                                const float* __restrict__ Waf,
                                                float* __restrict__ ctx,
                                                int* __restrict__ wsync) {
    int t = threadIdx.x;
    int lane = t & 63;
    int rg = lane >> 4, cq = lane & 15;
    int wid = (blockIdx.x * 512 + t) >> 6;
    int nw = (gridDim.x * 512) >> 6;
    float a0 = 0, a1 = 0, a2 = 0, a3 = 0;
    for (int r = wid * 4 + rg; r < NN; r += nw * 4) {
        uint2 v = *(const uint2*)(h3 + ((size_t)r << 6) + cq * 4);
        a0 += bfu((unsigned short)(v.x & 0xFFFF));
        a1 += bfu((unsigned short)(v.x >> 16));
        a2 += bfu((unsigned short)(v.y & 0xFFFF));
        a3 += bfu((unsigned short)(v.y >> 16));
    }
    a0 += __shfl_xor(a0, 16, 64); a0 += __shfl_xor(a0, 32, 64);
    a1 += __shfl_xor(a1, 16, 64); a1 += __shfl_xor(a1, 32, 64);
    a2 += __shfl_xor(a2, 16, 64); a2 += __shfl_xor(a2, 32, 64);
    a3 += __shfl_xor(a3, 16, 64); a3 += __shfl_xor(a3, 32, 64);
    __shared__ float part[8][64];
    int w = t >> 6;
    if (rg == 0) {
        part[w][cq * 4 + 0] = a0;
        part[w][cq * 4 + 1] = a1;
        part[w][cq * 4 + 2] = a2;
        part[w][cq * 4 + 3] = a3;
    }
    __syncthreads();
    if (t < 64) {
        float s = 0;
#pragma unroll
        for (int i = 0; i < 8; i++) s += part[i][t];
        atomicAdd(&colsum[t], s);
    }
    // last block computes ctx = tanh(mean @ Wa)
    __shared__ int lastf;
    __syncthreads();
    if (t == 0) {
        __threadfence();
        int old = atomicAdd(&wsync[0], 1);
        lastf = (old == (int)gridDim.x - 1) ? 1 : 0;
    }
    __syncthreads();
    if (lastf) {
        __shared__ float ms[64];
        if (t < 64) {
            __threadfence();
            ms[t] = atomicAdd(&colsum[t], 0.0f) * (1.0f / NN);  // coherent read
        }
        __syncthreads();
        if (t < 64) {
            float s = 0.0f;
#pragma unroll
            for (int k = 0; k < 64; k++) s += ms[k] * Waf[k * 64 + t];
            ctx[t] = tanhf(s);
        }
    }
}

// -------- pooling pass 2: attention pool + fused h3->out copy + tail ---------
__global__ __launch_bounds__(512) void k_pool(const unsigned short* __restrict__ h3,
                                              const float* __restrict__ ctx,
                                              float* __restrict__ pooled,
                                              void* __restrict__ out,
                                              const int* __restrict__ raw,
                                              int* __restrict__ wsync) {
    int t = threadIdx.x;
    int lane = t & 63;
    int rg = lane >> 4, cq = lane & 15;
    int wid = (blockIdx.x * 512 + t) >> 6;
    int nw = (gridDim.x * 512) >> 6;
    int f32o = raw[0] > 0;
    float c0 = ctx[cq * 4 + 0], c1 = ctx[cq * 4 + 1];
    float c2 = ctx[cq * 4 + 2], c3 = ctx[cq * 4 + 3];
    float q0 = 0, q1 = 0, q2 = 0, q3 = 0;
    for (int r = wid * 4 + rg; r < NN; r += nw * 4) {
        uint2 v = *(const uint2*)(h3 + ((size_t)r << 6) + cq * 4);
        float x0 = bfu((unsigned short)(v.x & 0xFFFF));
        float x1 = bfu((unsigned short)(v.x >> 16));
        float x2 = bfu((unsigned short)(v.y & 0xFFFF));
        float x3 = bfu((unsigned short)(v.y >> 16));
        // fused output write (h3 part of out); T3' scratch in d_out is dead here
        if (f32o) {
            *(float4*)((float*)out + ((size_t)r << 6) + cq * 4) =
                make_float4(x0, x1, x2, x3);
        } else {
            *(uint2*)((unsigned short*)out + ((size_t)r << 6) + cq * 4) = v;
        }
        float p = x0 * c0 + x1 * c1 + x2 * c2 + x3 * c3;
        p += __shfl_xor(p, 1, 64);
        p += __shfl_xor(p, 2, 64);
        p += __shfl_xor(p, 4, 64);
        p += __shfl_xor(p, 8, 64);
        float sc = 1.0f / (1.0f + expf(-p));
        q0 += sc * x0; q1 += sc * x1; q2 += sc * x2; q3 += sc * x3;
    }
    q0 += __shfl_xor(q0, 16, 64); q0 += __shfl_xor(q0, 32, 64);
    q1 += __shfl_xor(q1, 16, 64); q1 += __shfl_xor(q1, 32, 64);
    q2 += __shfl_xor(q2, 16, 64); q2 += __shfl_xor(q2, 32, 64);
    q3 += __shfl_xor(q3, 16, 64); q3 += __shfl_xor(q3, 32, 64);
    __shared__ float part[8][64];
    int w = t >> 6;
    if (rg == 0) {
        part[w][cq * 4 + 0] = q0;
        part[w][cq * 4 + 1] = q1;
        part[w][cq * 4 + 2] = q2;
        part[w][cq * 4 + 3] = q3;
    }
    __syncthreads();
    if (t < 64) {
        float s = 0;
#pragma unroll
        for (int i = 0; i < 8; i++) s += part[i][t];
        atomicAdd(&pooled[t], s);
    }
    // last block writes the 64 pooled tail values
    __shared__ int lastf;
    __syncthreads();
    if (t == 0) {
        __threadfence();
        int old = atomicAdd(&wsync[1], 1);
        lastf = (old == (int)gridDim.x - 1) ? 1 : 0;
    }
    __syncthreads();
    if (lastf && t < 64) {
        __threadfence();
        float pv = atomicAdd(&pooled[t], 0.0f);   // coherent read
        if (f32o) {
            ((float*)out)[6400000 + t] = pv;
        } else {
            ((unsigned short*)out)[6400000 + t] =
                __bfloat16_as_ushort(__float2bfloat16(pv));
        }
    }
}

// ---------------- workspace layout (~21.5 MB) ----------------
static constexpr size_t AL(size_t x) { return (x + 255) & ~size_t(255); }
static constexpr size_t OFF_FLAGS  = 0;
static constexpr size_t OFF_RAW    = OFF_FLAGS + 256;
static constexpr size_t OFF_GHIST  = OFF_RAW + 256;
static constexpr size_t OFF_OFFM   = OFF_GHIST + AL((size_t)NBLK * NB2 * 4);
static constexpr size_t OFF_CBASE  = OFF_OFFM + AL((size_t)NBLK * NB2 * 4);
static constexpr size_t OFF_ROWPTR = OFF_CBASE + AL((NB2 + 1) * 4);
static constexpr size_t OFF_CSR    = OFF_ROWPTR + AL((NN + 1) * 4);
static constexpr size_t OFF_DIS    = OFF_CSR + AL((size_t)NE * 4);
static constexpr size_t OFF_P      = OFF_DIS + AL(NN * 4);     // NR*128 fp8; also scatter scratch; also bf16 h3
static constexpr size_t OFF_W1B    = OFF_P + AL((size_t)NR * 128);
static constexpr size_t OFF_W2B    = OFF_W1B + AL(16384 * 2);
static constexpr size_t OFF_W3B    = OFF_W2B + AL(16384 * 2);
static constexpr size_t OFF_B1F    = OFF_W3B + AL(8192 * 2);
static constexpr size_t OFF_B2F    = OFF_B1F + AL(128 * 4);
static constexpr size_t OFF_B3F    = OFF_B2F + AL(128 * 4);
static constexpr size_t OFF_WAF    = OFF_B3F + AL(64 * 4);
static constexpr size_t OFF_COLSUM = OFF_WAF + AL(4096 * 4);
static constexpr size_t OFF_POOLED = OFF_COLSUM + AL(64 * 4);
static constexpr size_t OFF_CTX    = OFF_POOLED + AL(64 * 4);
static constexpr size_t OFF_SYNC   = OFF_CTX + AL(64 * 4);
static constexpr size_t OFF_TOT    = OFF_SYNC + 256;

extern "C" void kernel_launch(void* const* d_in, const int* in_sizes, int n_in,
                              void* d_out, int out_size, void* d_ws, size_t ws_size,
                              hipStream_t stream) {
    const int* ei = (const int*)d_in[0];
    const void* x  = d_in[1];
    const void* W1 = d_in[2];
    const void* b1 = d_in[3];
    const void* W2 = d_in[4];
    const void* b2 = d_in[5];
    const void* W3 = d_in[6];
    const void* b3 = d_in[7];
    const void* Wa = d_in[8];

    char* ws = (char*)d_ws;
    int*   raw    = (int*)(ws + OFF_RAW);
    int*   ghist  = (int*)(ws + OFF_GHIST);
    int*   offm   = (int*)(ws + OFF_OFFM);
    int*   cbase  = (int*)(ws + OFF_CBASE);
    int*   rowptr = (int*)(ws + OFF_ROWPTR);
    int*   csr    = (int*)(ws + OFF_CSR);
    float* dis    = (float*)(ws + OFF_DIS);
    unsigned char*  P    = (unsigned char*)(ws + OFF_P);
    int*            scrA = (int*)(ws + OFF_P);
    unsigned short* Hb   = (unsigned short*)(ws + OFF_P);
    unsigned short* W1b = (unsigned short*)(ws + OFF_W1B);
    unsigned short* W2b = (unsigned short*)(ws + OFF_W2B);
    unsigned short* W3b = (unsigned short*)(ws + OFF_W3B);
    float* b1f    = (float*)(ws + OFF_B1F);
    float* b2f    = (float*)(ws + OFF_B2F);
    float* b3f    = (float*)(ws + OFF_B3F);
    float* Waf    = (float*)(ws + OFF_WAF);
    float* colsum = (float*)(ws + OFF_COLSUM);
    float* pooled = (float*)(ws + OFF_POOLED);
    float* ctx    = (float*)(ws + OFF_CTX);
    int*   wsync  = (int*)(ws + OFF_SYNC);
    int*   tot    = (int*)(ws + OFF_TOT);

    unsigned char* Q = (unsigned char*)d_out;   // d_out doubles as T-scratch (12.8 MB)

    hipMemsetAsync(raw, 0, 256, stream);

    k_probe1<<<256, 256, 0, stream>>>((const unsigned short*)x, ei, raw);

    // atomic-free CSR build (uses P region as scatter scratch)
    k_hist<<<NBLK, 256, 0, stream>>>(ei, ghist, raw);
    k_offA<<<NB2, 512, 0, stream>>>(ghist, tot, offm);
    k_offB<<<1, 64, 0, stream>>>(tot, cbase, rowptr);
    k_scatter<<<NBLK, 256, 0, stream>>>(ei, offm, cbase, scrA, raw);
    k_build<<<NB2, 256, 0, stream>>>(scrA, cbase, rowptr, dis, csr);

    // fused prep: x->fp8 P (overwrites scratch), W tables, biases, zeroing
    k_prep<<<12564, 256, 0, stream>>>(x, W1, b1, W2, b2, W3, b3, Wa,
                                      W1b, W2b, W3b, b1f, b2f, b3f, Waf,
                                      P, raw, colsum, pooled, wsync);

    // L1: T' = dis*(P@W1) (Q, MFMA) ; P = relu((sum+self)*dn + b1)
    k_xf_mfma<8><<<NR / 64, 256, 0, stream>>>(P, W1b, dis, Q);
    k_agg128<true><<<NN / 4, 256, 0, stream>>>(Q, rowptr, csr, dis, b1f, P);
    // L2
    k_xf_mfma<8><<<NR / 64, 256, 0, stream>>>(P, W2b, dis, Q);
    k_agg128<true><<<NN / 4, 256, 0, stream>>>(Q, rowptr, csr, dis, b2f, P);
    // L3: T3' = dis*(P@W3) (Q, 64 cols) ; Hb = (sum+self)*dn + b3 (bf16)
    k_xf_mfma<4><<<NR / 64, 256, 0, stream>>>(P, W3b, dis, Q);
    k_agg64<<<NN / 8, 256, 0, stream>>>(Q, rowptr, csr, dis, b3f, Hb);

    // attention pooling (ctx fused into colsum's last block; tail in pool's)
    k_colsum<<<256, 512, 0, stream>>>(Hb, colsum, Waf, ctx, wsync);
    k_pool<<<256, 512, 0, stream>>>(Hb, ctx, pooled, d_out, raw, wsync);
}

// Round 8
// 348.114 us; speedup vs baseline: 1.4004x; 1.0550x over previous
//
#include <hip/hip_runtime.h>
#include <hip/hip_bf16.h>

#define NN 100000
#define NE 1600000
#define NR 100032            // NN rounded to 64-row blocks (table alloc rows)
#define NB2 196              // coarse buckets = ceil(NN/512)
#define NBLK 391             // hist/scatter blocks = ceil(NE/4096)
#define EPB 4096             // edges per hist/scatter block

#if defined(__has_builtin)
#  if __has_builtin(__builtin_amdgcn_cvt_pk_f32_fp8) && \
      __has_builtin(__builtin_amdgcn_cvt_pk_fp8_f32) && \
      __has_builtin(__builtin_amdgcn_cvt_f32_fp8)
#    define HWF8 1
#  endif
#endif

typedef float f32x2 __attribute__((ext_vector_type(2)));
typedef float f32x4 __attribute__((ext_vector_type(4)));
typedef short bf16x8 __attribute__((ext_vector_type(8)));

static __device__ __forceinline__ float bf2f(__hip_bfloat16 v) { return __bfloat162float(v); }
static __device__ __forceinline__ float bfu(unsigned short w) {
    return __uint_as_float((unsigned)w << 16);
}

// ---------------- fp8 e4m3 software codec (fallback, validated r3/r4) ---------
static __device__ __forceinline__ float f8d_sw(unsigned b) {
    unsigned e = (b >> 3) & 15u, m = b & 7u;
    float mag;
    if (e == 0) mag = (float)m * 0.001953125f;
    else        mag = __uint_as_float(((e + 120u) << 23) | (m << 20));
    return (b & 0x80u) ? -mag : mag;
}
static __device__ __forceinline__ unsigned char f8e_sw(float x) {
    unsigned u = __float_as_uint(x);
    unsigned s = (u >> 31) << 7;
    unsigned au = u & 0x7fffffffu;
    if (au >= 0x43E00000u) return (unsigned char)(s | 0x7Eu);
    if (au <  0x3A800000u) return (unsigned char)s;
    if (au <  0x3C800000u) {
        float a = __uint_as_float(au);
        int m = (int)rintf(a * 512.0f);
        if (m >= 8) return (unsigned char)(s | 0x08u);
        return (unsigned char)(s | (unsigned)m);
    }
    au += 0x80000u;
    if (au >= 0x43E00000u) return (unsigned char)(s | 0x7Eu);
    unsigned e = (au >> 23) - 120u;
    unsigned m = (au >> 20) & 7u;
    return (unsigned char)(s | (e << 3) | m);
}

// ---------------- fp8 helpers (HW if available) ----------------
static __device__ __forceinline__ void f8d4(unsigned u, float* o) {
#ifdef HWF8
    f32x2 lo = __builtin_amdgcn_cvt_pk_f32_fp8((int)u, false);
    f32x2 hi = __builtin_amdgcn_cvt_pk_f32_fp8((int)u, true);
    o[0] = lo.x; o[1] = lo.y; o[2] = hi.x; o[3] = hi.y;
#else
    o[0] = f8d_sw(u & 255u); o[1] = f8d_sw((u >> 8) & 255u);
    o[2] = f8d_sw((u >> 16) & 255u); o[3] = f8d_sw(u >> 24);
#endif
}
static __device__ __forceinline__ unsigned short f8e2(float a, float b) {
#ifdef HWF8
    float ca = fminf(fmaxf(a, -448.0f), 448.0f);
    float cb = fminf(fmaxf(b, -448.0f), 448.0f);
    int p = __builtin_amdgcn_cvt_pk_fp8_f32(ca, cb, 0, false);
    return (unsigned short)(p & 0xFFFF);
#else
    return (unsigned short)f8e_sw(a) | ((unsigned short)f8e_sw(b) << 8);
#endif
}
// f32 -> bf16 bits by truncation (EXACT for values that came from fp8 e4m3)
static __device__ __forceinline__ unsigned bfpack(float lo, float hi) {
    return (__float_as_uint(lo) >> 16) | (__float_as_uint(hi) & 0xFFFF0000u);
}

// decode 8 fp8 (uint2) and accumulate UNWEIGHTED into 4 f32x2 (v_pk_add_f32)
static __device__ __forceinline__ void acc8_add(f32x2* acc, uint2 v) {
#ifdef HWF8
    acc[0] += __builtin_amdgcn_cvt_pk_f32_fp8((int)v.x, false);
    acc[1] += __builtin_amdgcn_cvt_pk_f32_fp8((int)v.x, true);
    acc[2] += __builtin_amdgcn_cvt_pk_f32_fp8((int)v.y, false);
    acc[3] += __builtin_amdgcn_cvt_pk_f32_fp8((int)v.y, true);
#else
    unsigned u[2] = {v.x, v.y};
#pragma unroll
    for (int q = 0; q < 2; q++) {
        float o[4]; f8d4(u[q], o);
        acc[2 * q]     += (f32x2){o[0], o[1]};
        acc[2 * q + 1] += (f32x2){o[2], o[3]};
    }
#endif
}

// ---------------- dtype probe (writes raw; flags derived inline) --------------
__global__ void k_probe1(const unsigned short* __restrict__ xw,
                         const int* __restrict__ ei, int* __restrict__ raw) {
    int i = blockIdx.x * 256 + threadIdx.x;    // 65536 probes
    int nan = ((xw[i] & 0x7F80u) == 0x7F80u) ? 1 : 0;
    int odd = (ei[2 * i + 1] != 0) ? 1 : 0;
    unsigned long long bn = __ballot(nan);
    unsigned long long bo = __ballot(odd);
    if ((threadIdx.x & 63) == 0) {
        if (bn) atomicAdd(&raw[0], __popcll(bn));
        if (bo) atomicAdd(&raw[1], __popcll(bo));
    }
}
// raw[0] > 0  -> x/weights are f32 ;  raw[1] == 0 -> edge_index is int64

static __device__ __forceinline__ int e_src(const int* ei, int e, int f64) {
    int v = f64 ? ei[2 * e] : ei[e];
    return min(max(v, 0), NN - 1);
}
static __device__ __forceinline__ int e_dst(const int* ei, int e, int f64) {
    int v = f64 ? ei[2 * (NE + e)] : ei[NE + e];
    return min(max(v, 0), NN - 1);
}
static __device__ __forceinline__ float ldx(const void* p, long long i, int f32) {
    return f32 ? ((const float*)p)[i] : bf2f(((const __hip_bfloat16*)p)[i]);
}

// ---- fused prep: x->fp8 P, W->bf16 frag tables, biases, zeroing (post-build) -
__global__ __launch_bounds__(256) void k_prep(const void* __restrict__ x,
                                              const void* W1, const void* b1,
                                              const void* W2, const void* b2,
                                              const void* W3, const void* b3,
                                              const void* Wa,
                                              unsigned short* W1b, unsigned short* W2b,
                                              unsigned short* W3b,
                                              float* b1f, float* b2f, float* b3f,
                                              float* Waf,
                                              unsigned char* __restrict__ P,
                                              const int* __restrict__ raw,
                                              float* colsum, float* pooled, int* wsync) {
    int t = threadIdx.x;
    int gi = blockIdx.x;
    int f = raw[0] > 0;
    if (gi < 12500) {
        int i = gi * 256 + t;                     // < 3,200,000 exactly
        unsigned pk;
        if (f) {
            float4 v = ((const float4*)x)[i];
            pk = (unsigned)f8e2(v.x, v.y) | ((unsigned)f8e2(v.z, v.w) << 16);
        } else {
            ushort4 v = ((const ushort4*)x)[i];
            pk = (unsigned)f8e2(bfu(v.x), bfu(v.y)) | ((unsigned)f8e2(bfu(v.z), bfu(v.w)) << 16);
        }
        ((unsigned*)P)[i] = pk;
        return;
    }
    int i = (gi - 12500) * 256 + t;               // 0..16383
    {
        int j = i & 7, l = (i >> 3) & 63, c = (i >> 9) & 7, kc = i >> 12;
        int k = kc * 32 + ((l >> 4)) * 8 + j;
        int col = c * 16 + (l & 15);
        W1b[i] = __bfloat16_as_ushort(__float2bfloat16(ldx(W1, k * 128 + col, f)));
        W2b[i] = __bfloat16_as_ushort(__float2bfloat16(ldx(W2, k * 128 + col, f)));
    }
    if (i < 8192) {
        int j = i & 7, l = (i >> 3) & 63, c = (i >> 9) & 3, kc = i >> 11;
        int k = kc * 32 + ((l >> 4)) * 8 + j;
        int col = c * 16 + (l & 15);
        W3b[i] = __bfloat16_as_ushort(__float2bfloat16(ldx(W3, k * 64 + col, f)));
    }
    if (i < 4096)  Waf[i] = ldx(Wa, i, f);
    if (i < 128)   { b1f[i] = ldx(b1, i, f); b2f[i] = ldx(b2, i, f); }
    if (i < 64)    b3f[i] = ldx(b3, i, f);
    if (gi == 12500) {
        if (t < 64) { colsum[t] = 0.0f; pooled[t] = 0.0f; }
        if (t == 0) { wsync[0] = 0; wsync[1] = 0; }
    }
    if (gi == 12501) {
        // zero pad rows NN..NR-1 of P (gathered by invalid edge slots)
        for (int z = t; z < (NR - NN) * 32; z += 256)
            ((unsigned*)(P + (size_t)NN * 128))[z] = 0u;
    }
}

// ======== CSR build: atomic-free multisplit ========
__global__ __launch_bounds__(256) void k_hist(const int* __restrict__ ei,
                                              int* __restrict__ ghist,
                                              const int* __restrict__ raw) {
    __shared__ int h[NB2];
    int blk = blockIdx.x, t = threadIdx.x;
    for (int i = t; i < NB2; i += 256) h[i] = 0;
    __syncthreads();
    int f64 = (raw[1] == 0);
    int e0 = blk * EPB;
    for (int i = t; i < EPB; i += 256) {
        int e = e0 + i;
        if (e < NE) atomicAdd(&h[e_dst(ei, e, f64) >> 9], 1);
    }
    __syncthreads();
    for (int i = t; i < NB2; i += 256) ghist[blk * NB2 + i] = h[i];
}

// parallel per-bucket scan over the 391 hist blocks (196 blocks x 512 thr).
// Writes offm WITHOUT the cbase base (k_scatter adds it) and tot[b].
// v3: last block also performs the 196-bucket top scan (fused k_offB).
__global__ __launch_bounds__(512) void k_offA(const int* __restrict__ ghist,
                                              int* __restrict__ tot,
                                              int* __restrict__ offm,
                                              int* __restrict__ cbase,
                                              int* __restrict__ rowptr,
                                              int* __restrict__ sync) {
    int b = blockIdx.x;               // bucket 0..NB2-1
    int t = threadIdx.x;              // 0..511 (covers NBLK=391)
    __shared__ int wsum[8];
    __shared__ int woff[8];
    int v = (t < NBLK) ? ghist[t * NB2 + b] : 0;
    int s = v;
#pragma unroll
    for (int o = 1; o < 64; o <<= 1) {
        int u = __shfl_up(s, o, 64);
        if ((t & 63) >= o) s += u;
    }
    int w = t >> 6;
    if ((t & 63) == 63) wsum[w] = s;
    __syncthreads();
    if (t == 0) {
        int run = 0;
#pragma unroll
        for (int i = 0; i < 8; i++) { woff[i] = run; run += wsum[i]; }
        tot[b] = run;
    }
    __syncthreads();
    if (t < NBLK) offm[t * NB2 + b] = s - v + woff[w];   // exclusive prefix
    // last block: top scan tot -> cbase, rowptr[NN]
    __shared__ int lastf;
    if (t == 0) {
        __threadfence();
        int old = atomicAdd(sync, 1);
        lastf = (old == NB2 - 1) ? 1 : 0;
    }
    __syncthreads();
    if (lastf) {
        __shared__ int sv[NB2];
        if (t < NB2) sv[t] = atomicAdd(&tot[t], 0);   // coherent read
        __syncthreads();
        if (t == 0) {
            int run = 0;
            for (int bb = 0; bb < NB2; bb++) { cbase[bb] = run; run += sv[bb]; }
            cbase[NB2] = run;
            rowptr[NN] = run;   // == NE
        }
    }
}

__global__ __launch_bounds__(256) void k_scatter(const int* __restrict__ ei,
                                                 const int* __restrict__ offm,
                                                 const int* __restrict__ cbase,
                                                 int* __restrict__ scratch,
                                                 const int* __restrict__ raw) {
    __shared__ int cur[NB2];
    int blk = blockIdx.x, t = threadIdx.x;
    for (int i = t; i < NB2; i += 256) cur[i] = offm[blk * NB2 + i] + cbase[i];
    __syncthreads();
    int f64 = (raw[1] == 0);
    int e0 = blk * EPB;
    for (int i = t; i < EPB; i += 256) {
        int e = e0 + i;
        if (e < NE) {
            int d = e_dst(ei, e, f64);
            int s = e_src(ei, e, f64);
            int p = atomicAdd(&cur[d >> 9], 1);
            p = min(max(p, 0), NE - 1);
            scratch[p] = s | ((d & 511) << 17);
        }
    }
}

__global__ __launch_bounds__(256) void k_build(const int* __restrict__ scratch,
                                               const int* __restrict__ cbase,
                                               int* __restrict__ rowptr,
                                               float* __restrict__ dis,
                                               int* __restrict__ csr) {
    __shared__ int hist[512];
    __shared__ int base[512];
    __shared__ int sd[256];
    int b = blockIdx.x, t = threadIdx.x;
    int n0 = b << 9;
    int s0 = cbase[b], s1 = cbase[b + 1];
    hist[t] = 0; hist[t + 256] = 0;
    __syncthreads();
    for (int i = s0 + t; i < s1; i += 256) {
        int dlo = (scratch[i] >> 17) & 511;
        atomicAdd(&hist[dlo], 1);
    }
    __syncthreads();
    int v0 = hist[2 * t], v1 = hist[2 * t + 1];
    int s = v0 + v1;
    sd[t] = s; __syncthreads();
    for (int o = 1; o < 256; o <<= 1) {
        int add = (t >= o) ? sd[t - o] : 0;
        __syncthreads();
        sd[t] += add;
        __syncthreads();
    }
    int run = s0 + sd[t] - s;
    base[2 * t] = run;
    base[2 * t + 1] = run + v0;
    int n = n0 + 2 * t;
    if (n < NN) {
        rowptr[n] = run;
        dis[n] = rsqrtf((float)v0 + 1.0f);
    }
    if (n + 1 < NN) {
        rowptr[n + 1] = run + v0;
        dis[n + 1] = rsqrtf((float)v1 + 1.0f);
    }
    __syncthreads();
    for (int i = s0 + t; i < s1; i += 256) {
        int v = scratch[i];
        int dlo = (v >> 17) & 511;
        int p = atomicAdd(&base[dlo], 1);
        p = min(max(p, 0), NE - 1);
        csr[p] = v & 0x1FFFF;
    }
}

// ------------- MFMA GEMM: O[NNxCOLS] = dis[row] * (A(fp8,128) @ W) ------------
// Operands swapped (D = W^T · P^T): each lane's acc[c][0..3] are 4 consecutive
// output columns of one node -> pack to u32, 1 dword store per c.
template <int NCT>    // NCT = COLS/16 (8 or 4)
__global__ __launch_bounds__(256) void k_xf_mfma(const unsigned char* __restrict__ A,
                                                 const unsigned short* __restrict__ Wf,
                                                 const float* __restrict__ dis,
                                                 unsigned char* __restrict__ O) {
    __shared__ unsigned short wl[NCT * 4 * 64 * 8];
    int t = threadIdx.x;
    int n0 = blockIdx.x * 64;
    {
        const uint4* wg = (const uint4*)Wf;
        uint4* wld = (uint4*)wl;
#pragma unroll
        for (int i = 0; i < NCT; i++) wld[i * 256 + t] = wg[i * 256 + t];
    }
    __syncthreads();
    int w = t >> 6, l = t & 63;
    int quad = l >> 4, m = l & 15;
    int node = n0 + w * 16 + m;
    const unsigned char* ap = A + (size_t)node * 128 + quad * 8;
    f32x4 acc[NCT];
#pragma unroll
    for (int c = 0; c < NCT; c++) acc[c] = (f32x4){0.0f, 0.0f, 0.0f, 0.0f};
#pragma unroll
    for (int kc = 0; kc < 4; kc++) {
        uint2 g = *(const uint2*)(ap + kc * 32);
        float o[8];
        f8d4(g.x, o); f8d4(g.y, o + 4);
        union { unsigned u[4]; bf16x8 v; } fr;
        fr.u[0] = bfpack(o[0], o[1]);
        fr.u[1] = bfpack(o[2], o[3]);
        fr.u[2] = bfpack(o[4], o[5]);
        fr.u[3] = bfpack(o[6], o[7]);
#pragma unroll
        for (int c = 0; c < NCT; c++) {
            bf16x8 bw = *(const bf16x8*)&wl[((kc * NCT + c) * 64 + l) * 8];
            acc[c] = __builtin_amdgcn_mfma_f32_16x16x32_bf16(bw, fr.v, acc[c], 0, 0, 0);
        }
    }
    float d = (node < NN) ? dis[node] : 0.0f;     // node==NN -> store zeros
    if (node <= NN) {
        unsigned char* orow = O + (size_t)node * (NCT * 16) + quad * 4;
#pragma unroll
        for (int c = 0; c < NCT; c++) {
            unsigned pk = (unsigned)f8e2(acc[c][0] * d, acc[c][1] * d)
                        | ((unsigned)f8e2(acc[c][2] * d, acc[c][3] * d) << 16);
            *(unsigned*)(orow + c * 16) = pk;
        }
    }
}

// ---- agg, F=128: H = relu?((sum T'[src] + T'[n]) * dn + b), fp8->fp8 --------
// v6: 2 nodes/wave (32 lanes each), 2 slots x 16 lanes x 8B. Per-node fixed
// costs halved: one csr window per 2 nodes, slot-reduce = 1 shfl level,
// epilogue shared. Inner loop: 4 groups (8 edges/half) per iter, 4 loads in
// flight. Pad lanes gather zero row NN (branchless).
template <bool RELU>
__global__ __launch_bounds__(256) void k_agg128(const unsigned char* __restrict__ Tb,
                                                const int* __restrict__ rowptr,
                                                const int* __restrict__ csr,
                                                const float* __restrict__ dis,
                                                const float* __restrict__ bias,
                                                unsigned char* __restrict__ H) {
    int lane = threadIdx.x & 63;
    int half = lane >> 5;
    int hl = lane & 31;
    int n = blockIdx.x * 8 + (threadIdx.x >> 6) * 2 + half;
    int r = hl >> 4;              // slot 0..1
    int f = hl & 15;              // feature group: bytes 8f..8f+7
    int fo = f << 3;
    float dn = dis[n];
    int s0 = rowptr[n], s1 = rowptr[n + 1];
    s0 = min(max(s0, 0), NE); s1 = min(max(s1, s0), NE);
    f32x2 acc[4];
#pragma unroll
    for (int k = 0; k < 4; k++) acc[k] = (f32x2){0.0f, 0.0f};
    if (r == 0) {   // self term: T'[n], weight 1.0 (dis already folded into T')
        uint2 v = *(const uint2*)(Tb + (((unsigned)n << 7) + (unsigned)fo));
        acc8_add(acc, v);
    }
    int ab = half << 7;           // bpermute byte base of own half (32 lanes * 4B)
    for (int base = s0; base < s1; base += 32) {
        int m = min(32, s1 - base);
        unsigned voff = (unsigned)NN << 7;          // pad -> zero row
        if (hl < m) voff = (unsigned)csr[base + hl] << 7;
        int nq = (m + 7) >> 3;                      // iters of 4 groups (8 edges/half)
        for (int q = 0; q < nq; q++) {
            int a0 = ab + q * 32 + r * 4;           // group 4q+k at ab+(4q+k)*8+r*4
            unsigned vo0 = (unsigned)__builtin_amdgcn_ds_bpermute(a0,      (int)voff);
            unsigned vo1 = (unsigned)__builtin_amdgcn_ds_bpermute(a0 + 8,  (int)voff);
            unsigned vo2 = (unsigned)__builtin_amdgcn_ds_bpermute(a0 + 16, (int)voff);
            unsigned vo3 = (unsigned)__builtin_amdgcn_ds_bpermute(a0 + 24, (int)voff);
            uint2 v0 = *(const uint2*)(Tb + (vo0 + (unsigned)fo));
            uint2 v1 = *(const uint2*)(Tb + (vo1 + (unsigned)fo));
            uint2 v2 = *(const uint2*)(Tb + (vo2 + (unsigned)fo));
            uint2 v3 = *(const uint2*)(Tb + (vo3 + (unsigned)fo));
            acc8_add(acc, v0);
            acc8_add(acc, v1);
            acc8_add(acc, v2);
            acc8_add(acc, v3);
        }
    }
    // reduce across the 2 slots (lane stride 16; stays within each half)
#pragma unroll
    for (int k = 0; k < 4; k++) {
        acc[k].x += __shfl_xor(acc[k].x, 16, 64);
        acc[k].y += __shfl_xor(acc[k].y, 16, 64);
    }
    if (r == 0) {
        float4 bA = *(const float4*)(bias + fo);
        float4 bB = *(const float4*)(bias + fo + 4);
        float t[8];
        t[0] = acc[0].x * dn + bA.x; t[1] = acc[0].y * dn + bA.y;
        t[2] = acc[1].x * dn + bA.z; t[3] = acc[1].y * dn + bA.w;
        t[4] = acc[2].x * dn + bB.x; t[5] = acc[2].y * dn + bB.y;
        t[6] = acc[3].x * dn + bB.z; t[7] = acc[3].y * dn + bB.w;
        if (RELU) {
#pragma unroll
            for (int k = 0; k < 8; k++) t[k] = fmaxf(t[k], 0.0f);
        }
        unsigned lo = (unsigned)f8e2(t[0], t[1]) | ((unsigned)f8e2(t[2], t[3]) << 16);
        unsigned hi = (unsigned)f8e2(t[4], t[5]) | ((unsigned)f8e2(t[6], t[7]) << 16);
        *(uint2*)(H + (((size_t)n << 7) + (size_t)fo)) = make_uint2(lo, hi);
    }
}

// ---- agg, F=64 final: h3 = (sum T3'[src] + T3'[n]) * dn + b3 -> bf16 --------
// v6: 4 nodes/wave (16 lanes each), 2 slots x 8 lanes x 8B, reduce = 1 level.
__global__ __launch_bounds__(256) void k_agg64(const unsigned char* __restrict__ Tb,
                                               const int* __restrict__ rowptr,
                                               const int* __restrict__ csr,
                                               const float* __restrict__ dis,
                                               const float* __restrict__ bias,
                                               unsigned short* __restrict__ Hb) {
    int lane = threadIdx.x & 63;
    int qtr = lane >> 4;
    int ql = lane & 15;
    int n = blockIdx.x * 16 + (threadIdx.x >> 6) * 4 + qtr;
    int r = ql >> 3;              // slot 0..1
    int f = ql & 7;               // feature group: bytes 8f..8f+7
    int fo = f << 3;
    float dn = dis[n];
    int s0 = rowptr[n], s1 = rowptr[n + 1];
    s0 = min(max(s0, 0), NE); s1 = min(max(s1, s0), NE);
    f32x2 acc[4];
#pragma unroll
    for (int k = 0; k < 4; k++) acc[k] = (f32x2){0.0f, 0.0f};
    if (r == 0) {   // self term: weight 1.0 (dis folded into T3')
        uint2 v = *(const uint2*)(Tb + (((unsigned)n << 6) + (unsigned)fo));
        acc8_add(acc, v);
    }
    int ab = qtr << 6;            // bpermute byte base of own quarter (16 lanes * 4B)
    for (int base = s0; base < s1; base += 16) {
        int m = min(16, s1 - base);
        unsigned voff = (unsigned)NN << 6;          // pad -> zero row
        if (ql < m) voff = (unsigned)csr[base + ql] << 6;
        int nq = (m + 7) >> 3;                      // iters of 4 groups (8 edges/qtr)
        for (int q = 0; q < nq; q++) {
            int a0 = ab + q * 32 + r * 4;           // group 4q+k at ab+(4q+k)*8+r*4
            unsigned vo0 = (unsigned)__builtin_amdgcn_ds_bpermute(a0,      (int)voff);
            unsigned vo1 = (unsigned)__builtin_amdgcn_ds_bpermute(a0 + 8,  (int)voff);
            unsigned vo2 = (unsigned)__builtin_amdgcn_ds_bpermute(a0 + 16, (int)voff);
            unsigned vo3 = (unsigned)__builtin_amdgcn_ds_bpermute(a0 + 24, (int)voff);
            uint2 v0 = *(const uint2*)(Tb + (vo0 + (unsigned)fo));
            uint2 v1 = *(const uint2*)(Tb + (vo1 + (unsigned)fo));
            uint2 v2 = *(const uint2*)(Tb + (vo2 + (unsigned)fo));
            uint2 v3 = *(const uint2*)(Tb + (vo3 + (unsigned)fo));
            acc8_add(acc, v0);
            acc8_add(acc, v1);
            acc8_add(acc, v2);
            acc8_add(acc, v3);
        }
    }
    // reduce across the 2 slots (lane stride 8; stays within each quarter)
#pragma unroll
    for (int k = 0; k < 4; k++) {
        acc[k].x += __shfl_xor(acc[k].x, 8, 64);
        acc[k].y += __shfl_xor(acc[k].y, 8, 64);
    }
    if (r == 0) {
        float4 bA = *(const float4*)(bias + fo);
        float4 bB = *(const float4*)(bias + fo + 4);
        float t[8];
        t[0] = acc[0].x * dn + bA.x; t[1] = acc[0].y * dn + bA.y;
        t[2] = acc[1].x * dn + bA.z; t[3] = acc[1].y * dn + bA.w;
        t[4] = acc[2].x * dn + bB.x; t[5] = acc[2].y * dn + bB.y;
        t[6] = acc[3].x * dn + bB.z; t[7] = acc[3].y * dn + bB.w;
        unsigned p0 = (unsigned)__bfloat16_as_ushort(__float2bfloat16(t[0])) |
                      ((unsigned)__bfloat16_as_ushort(__float2bfloat16(t[1])) << 16);
        unsigned p1 = (unsigned)__bfloat16_as_ushort(__float2bfloat16(t[2])) |
                      ((unsigned)__bfloat16_as_ushort(__float2bfloat16(t[3])) << 16);
        unsigned p2 = (unsigned)__bfloat16_as_ushort(__float2bfloat16(t[4])) |
                      ((unsigned)__bfloat16_as_ushort(__float2bfloat16(t[5])) << 16);
        unsigned p3 = (unsigned)__bfloat16_as_ushort(__float2bfloat16(t[6])) |
                      ((unsigned)__bfloat16_as_ushort(__float2bfloat16(t[7])) << 16);
        *(uint4*)(Hb + (((size_t)n << 6) + (size_t)fo)) = make_uint4(p0, p1, p2, p3);
    }
}

// ---------------- pooling: colsum (+ fused ctx via last-block) ----------------
__global__ __launch_bounds__(512) void k_colsum(const unsigned short* __restrict__ h3,
                                                float* __restrict__ colsum,
                                                const float* __restrict__ Waf,
                                                float* __restrict__ ctx,
                                                int* __restrict__ wsync) {
    int t = threadIdx.x;
    int lane = t & 63;
    int rg = lane >> 4, cq = lane & 15;
    int wid = (blockIdx.x * 512 + t) >> 6;
    int nw = (gridDim.x * 512) >> 6;
    float a0 = 0, a1 = 0, a2 = 0, a3 = 0;
    for (int r = wid * 4 + rg; r < NN; r += nw * 4) {
        uint2 v = *(const uint2*)(h3 + ((size_t)r << 6) + cq * 4);
        a0 += bfu((unsigned short)(v.x & 0xFFFF));
        a1 += bfu((unsigned short)(v.x >> 16));
        a2 += bfu((unsigned short)(v.y & 0xFFFF));
        a3 += bfu((unsigned short)(v.y >> 16));
    }
    a0 += __shfl_xor(a0, 16, 64); a0 += __shfl_xor(a0, 32, 64);
    a1 += __shfl_xor(a1, 16, 64); a1 += __shfl_xor(a1, 32, 64);
    a2 += __shfl_xor(a2, 16, 64); a2 += __shfl_xor(a2, 32, 64);
    a3 += __shfl_xor(a3, 16, 64); a3 += __shfl_xor(a3, 32, 64);
    __shared__ float part[8][64];
    int w = t >> 6;
    if (rg == 0) {
        part[w][cq * 4 + 0] = a0;
        part[w][cq * 4 + 1] = a1;
        part[w][cq * 4 + 2] = a2;
        part[w][cq * 4 + 3] = a3;
    }
    __syncthreads();
    if (t < 64) {
        float s = 0;
#pragma unroll
        for (int i = 0; i < 8; i++) s += part[i][t];
        atomicAdd(&colsum[t], s);
    }
    // last block computes ctx = tanh(mean @ Wa)
    __shared__ int lastf;
    __syncthreads();
    if (t == 0) {
        __threadfence();
        int old = atomicAdd(&wsync[0], 1);
        lastf = (old == (int)gridDim.x - 1) ? 1 : 0;
    }
    __syncthreads();
    if (lastf) {
        __shared__ float ms[64];
        if (t < 64) {
            __threadfence();
            ms[t] = atomicAdd(&colsum[t], 0.0f) * (1.0f / NN);  // coherent read
        }
        __syncthreads();
        if (t < 64) {
            float s = 0.0f;
#pragma unroll
            for (int k = 0; k < 64; k++) s += ms[k] * Waf[k * 64 + t];
            ctx[t] = tanhf(s);
        }
    }
}

// -------- pooling pass 2: attention pool + fused h3->out copy + tail ---------
__global__ __launch_bounds__(512) void k_pool(const unsigned short* __restrict__ h3,
                                              const float* __restrict__ ctx,
                                              float* __restrict__ pooled,
                                              void* __restrict__ out,
                                              const int* __restrict__ raw,
                                              int* __restrict__ wsync) {
    int t = threadIdx.x;
    int lane = t & 63;
    int rg = lane >> 4, cq = lane & 15;
    int wid = (blockIdx.x * 512 + t) >> 6;
    int nw = (gridDim.x * 512) >> 6;
    int f32o = raw[0] > 0;
    float c0 = ctx[cq * 4 + 0], c1 = ctx[cq * 4 + 1];
    float c2 = ctx[cq * 4 + 2], c3 = ctx[cq * 4 + 3];
    float q0 = 0, q1 = 0, q2 = 0, q3 = 0;
    for (int r = wid * 4 + rg; r < NN; r += nw * 4) {
        uint2 v = *(const uint2*)(h3 + ((size_t)r << 6) + cq * 4);
        float x0 = bfu((unsigned short)(v.x & 0xFFFF));
        float x1 = bfu((unsigned short)(v.x >> 16));
        float x2 = bfu((unsigned short)(v.y & 0xFFFF));
        float x3 = bfu((unsigned short)(v.y >> 16));
        // fused output write (h3 part of out); T3' scratch in d_out is dead here
        if (f32o) {
            *(float4*)((float*)out + ((size_t)r << 6) + cq * 4) =
                make_float4(x0, x1, x2, x3);
        } else {
            *(uint2*)((unsigned short*)out + ((size_t)r << 6) + cq * 4) = v;
        }
        float p = x0 * c0 + x1 * c1 + x2 * c2 + x3 * c3;
        p += __shfl_xor(p, 1, 64);
        p += __shfl_xor(p, 2, 64);
        p += __shfl_xor(p, 4, 64);
        p += __shfl_xor(p, 8, 64);
        float sc = 1.0f / (1.0f + expf(-p));
        q0 += sc * x0; q1 += sc * x1; q2 += sc * x2; q3 += sc * x3;
    }
    q0 += __shfl_xor(q0, 16, 64); q0 += __shfl_xor(q0, 32, 64);
    q1 += __shfl_xor(q1, 16, 64); q1 += __shfl_xor(q1, 32, 64);
    q2 += __shfl_xor(q2, 16, 64); q2 += __shfl_xor(q2, 32, 64);
    q3 += __shfl_xor(q3, 16, 64); q3 += __shfl_xor(q3, 32, 64);
    __shared__ float part[8][64];
    int w = t >> 6;
    if (rg == 0) {
        part[w][cq * 4 + 0] = q0;
        part[w][cq * 4 + 1] = q1;
        part[w][cq * 4 + 2] = q2;
        part[w][cq * 4 + 3] = q3;
    }
    __syncthreads();
    if (t < 64) {
        float s = 0;
#pragma unroll
        for (int i = 0; i < 8; i++) s += part[i][t];
        atomicAdd(&pooled[t], s);
    }
    // last block writes the 64 pooled tail values
    __shared__ int lastf;
    __syncthreads();
    if (t == 0) {
        __threadfence();
        int old = atomicAdd(&wsync[1], 1);
        lastf = (old == (int)gridDim.x - 1) ? 1 : 0;
    }
    __syncthreads();
    if (lastf && t < 64) {
        __threadfence();
        float pv = atomicAdd(&pooled[t], 0.0f);   // coherent read
        if (f32o) {
            ((float*)out)[6400000 + t] = pv;
        } else {
            ((unsigned short*)out)[6400000 + t] =
                __bfloat16_as_ushort(__float2bfloat16(pv));
        }
    }
}

// ---------------- workspace layout (~21.5 MB) ----------------
static constexpr size_t AL(size_t x) { return (x + 255) & ~size_t(255); }
static constexpr size_t OFF_FLAGS  = 0;
static constexpr size_t OFF_RAW    = OFF_FLAGS + 256;
static constexpr size_t OFF_GHIST  = OFF_RAW + 256;
static constexpr size_t OFF_OFFM   = OFF_GHIST + AL((size_t)NBLK * NB2 * 4);
static constexpr size_t OFF_CBASE  = OFF_OFFM + AL((size_t)NBLK * NB2 * 4);
static constexpr size_t OFF_ROWPTR = OFF_CBASE + AL((NB2 + 1) * 4);
static constexpr size_t OFF_CSR    = OFF_ROWPTR + AL((NN + 1) * 4);
static constexpr size_t OFF_DIS    = OFF_CSR + AL((size_t)NE * 4);
static constexpr size_t OFF_P      = OFF_DIS + AL(NN * 4);     // NR*128 fp8; also scatter scratch; also bf16 h3
static constexpr size_t OFF_W1B    = OFF_P + AL((size_t)NR * 128);
static constexpr size_t OFF_W2B    = OFF_W1B + AL(16384 * 2);
static constexpr size_t OFF_W3B    = OFF_W2B + AL(16384 * 2);
static constexpr size_t OFF_B1F    = OFF_W3B + AL(8192 * 2);
static constexpr size_t OFF_B2F    = OFF_B1F + AL(128 * 4);
static constexpr size_t OFF_B3F    = OFF_B2F + AL(128 * 4);
static constexpr size_t OFF_WAF    = OFF_B3F + AL(64 * 4);
static constexpr size_t OFF_COLSUM = OFF_WAF + AL(4096 * 4);
static constexpr size_t OFF_POOLED = OFF_COLSUM + AL(64 * 4);
static constexpr size_t OFF_CTX    = OFF_POOLED + AL(64 * 4);
static constexpr size_t OFF_SYNC   = OFF_CTX + AL(64 * 4);
static constexpr size_t OFF_TOT    = OFF_SYNC + 256;

extern "C" void kernel_launch(void* const* d_in, const int* in_sizes, int n_in,
                              void* d_out, int out_size, void* d_ws, size_t ws_size,
                              hipStream_t stream) {
    const int* ei = (const int*)d_in[0];
    const void* x  = d_in[1];
    const void* W1 = d_in[2];
    const void* b1 = d_in[3];
    const void* W2 = d_in[4];
    const void* b2 = d_in[5];
    const void* W3 = d_in[6];
    const void* b3 = d_in[7];
    const void* Wa = d_in[8];

    char* ws = (char*)d_ws;
    int*   raw    = (int*)(ws + OFF_RAW);
    int*   ghist  = (int*)(ws + OFF_GHIST);
    int*   offm   = (int*)(ws + OFF_OFFM);
    int*   cbase  = (int*)(ws + OFF_CBASE);
    int*   rowptr = (int*)(ws + OFF_ROWPTR);
    int*   csr    = (int*)(ws + OFF_CSR);
    float* dis    = (float*)(ws + OFF_DIS);
    unsigned char*  P    = (unsigned char*)(ws + OFF_P);
    int*            scrA = (int*)(ws + OFF_P);
    unsigned short* Hb   = (unsigned short*)(ws + OFF_P);
    unsigned short* W1b = (unsigned short*)(ws + OFF_W1B);
    unsigned short* W2b = (unsigned short*)(ws + OFF_W2B);
    unsigned short* W3b = (unsigned short*)(ws + OFF_W3B);
    float* b1f    = (float*)(ws + OFF_B1F);
    float* b2f    = (float*)(ws + OFF_B2F);
    float* b3f    = (float*)(ws + OFF_B3F);
    float* Waf    = (float*)(ws + OFF_WAF);
    float* colsum = (float*)(ws + OFF_COLSUM);
    float* pooled = (float*)(ws + OFF_POOLED);
    float* ctx    = (float*)(ws + OFF_CTX);
    int*   wsync  = (int*)(ws + OFF_SYNC);
    int*   tot    = (int*)(ws + OFF_TOT);

    unsigned char* Q = (unsigned char*)d_out;   // d_out doubles as T-scratch (12.8 MB)

    hipMemsetAsync(raw, 0, 256, stream);        // zeroes raw[0..63] incl. offA sync

    k_probe1<<<256, 256, 0, stream>>>((const unsigned short*)x, ei, raw);

    // atomic-free CSR build (uses P region as scatter scratch)
    k_hist<<<NBLK, 256, 0, stream>>>(ei, ghist, raw);
    k_offA<<<NB2, 512, 0, stream>>>(ghist, tot, offm, cbase, rowptr, &raw[2]);
    k_scatter<<<NBLK, 256, 0, stream>>>(ei, offm, cbase, scrA, raw);
    k_build<<<NB2, 256, 0, stream>>>(scrA, cbase, rowptr, dis, csr);

    // fused prep: x->fp8 P (overwrites scratch), W tables, biases, zeroing
    k_prep<<<12564, 256, 0, stream>>>(x, W1, b1, W2, b2, W3, b3, Wa,
                                      W1b, W2b, W3b, b1f, b2f, b3f, Waf,
                                      P, raw, colsum, pooled, wsync);

    // L1: T' = dis*(P@W1) (Q, MFMA) ; P = relu((sum+self)*dn + b1)
    k_xf_mfma<8><<<NR / 64, 256, 0, stream>>>(P, W1b, dis, Q);
    k_agg128<true><<<NN / 8, 256, 0, stream>>>(Q, rowptr, csr, dis, b1f, P);
    // L2
    k_xf_mfma<8><<<NR / 64, 256, 0, stream>>>(P, W2b, dis, Q);
    k_agg128<true><<<NN / 8, 256, 0, stream>>>(Q, rowptr, csr, dis, b2f, P);
    // L3: T3' = dis*(P@W3) (Q, 64 cols) ; Hb = (sum+self)*dn + b3 (bf16)
    k_xf_mfma<4><<<NR / 64, 256, 0, stream>>>(P, W3b, dis, Q);
    k_agg64<<<NN / 16, 256, 0, stream>>>(Q, rowptr, csr, dis, b3f, Hb);

    // attention pooling (ctx fused into colsum's last block; tail in pool's)
    k_colsum<<<256, 512, 0, stream>>>(Hb, colsum, Waf, ctx, wsync);
    k_pool<<<256, 512, 0, stream>>>(Hb, ctx, pooled, d_out, raw, wsync);
}

// Round 9
// 344.909 us; speedup vs baseline: 1.4134x; 1.0093x over previous
//
#include <hip/hip_runtime.h>
#include <hip/hip_bf16.h>

#define NN 100000
#define NE 1600000
#define NR 100032            // NN rounded to 64-row blocks (table alloc rows)
#define NB2 196              // coarse buckets = ceil(NN/512)
#define NBLK 391             // hist/scatter blocks = ceil(NE/4096)
#define EPB 4096             // edges per hist/scatter block

#if defined(__has_builtin)
#  if __has_builtin(__builtin_amdgcn_cvt_pk_f32_fp8) && \
      __has_builtin(__builtin_amdgcn_cvt_pk_fp8_f32) && \
      __has_builtin(__builtin_amdgcn_cvt_f32_fp8)
#    define HWF8 1
#  endif
#endif

typedef float f32x2 __attribute__((ext_vector_type(2)));
typedef float f32x4 __attribute__((ext_vector_type(4)));
typedef short bf16x8 __attribute__((ext_vector_type(8)));

static __device__ __forceinline__ float bf2f(__hip_bfloat16 v) { return __bfloat162float(v); }
static __device__ __forceinline__ float bfu(unsigned short w) {
    return __uint_as_float((unsigned)w << 16);
}

// ---------------- fp8 e4m3 software codec (fallback, validated r3/r4) ---------
static __device__ __forceinline__ float f8d_sw(unsigned b) {
    unsigned e = (b >> 3) & 15u, m = b & 7u;
    float mag;
    if (e == 0) mag = (float)m * 0.001953125f;
    else        mag = __uint_as_float(((e + 120u) << 23) | (m << 20));
    return (b & 0x80u) ? -mag : mag;
}
static __device__ __forceinline__ unsigned char f8e_sw(float x) {
    unsigned u = __float_as_uint(x);
    unsigned s = (u >> 31) << 7;
    unsigned au = u & 0x7fffffffu;
    if (au >= 0x43E00000u) return (unsigned char)(s | 0x7Eu);
    if (au <  0x3A800000u) return (unsigned char)s;
    if (au <  0x3C800000u) {
        float a = __uint_as_float(au);
        int m = (int)rintf(a * 512.0f);
        if (m >= 8) return (unsigned char)(s | 0x08u);
        return (unsigned char)(s | (unsigned)m);
    }
    au += 0x80000u;
    if (au >= 0x43E00000u) return (unsigned char)(s | 0x7Eu);
    unsigned e = (au >> 23) - 120u;
    unsigned m = (au >> 20) & 7u;
    return (unsigned char)(s | (e << 3) | m);
}

// ---------------- fp8 helpers (HW if available) ----------------
static __device__ __forceinline__ void f8d4(unsigned u, float* o) {
#ifdef HWF8
    f32x2 lo = __builtin_amdgcn_cvt_pk_f32_fp8((int)u, false);
    f32x2 hi = __builtin_amdgcn_cvt_pk_f32_fp8((int)u, true);
    o[0] = lo.x; o[1] = lo.y; o[2] = hi.x; o[3] = hi.y;
#else
    o[0] = f8d_sw(u & 255u); o[1] = f8d_sw((u >> 8) & 255u);
    o[2] = f8d_sw((u >> 16) & 255u); o[3] = f8d_sw(u >> 24);
#endif
}
static __device__ __forceinline__ unsigned short f8e2(float a, float b) {
#ifdef HWF8
    float ca = fminf(fmaxf(a, -448.0f), 448.0f);
    float cb = fminf(fmaxf(b, -448.0f), 448.0f);
    int p = __builtin_amdgcn_cvt_pk_fp8_f32(ca, cb, 0, false);
    return (unsigned short)(p & 0xFFFF);
#else
    return (unsigned short)f8e_sw(a) | ((unsigned short)f8e_sw(b) << 8);
#endif
}
// f32 -> bf16 bits by truncation
static __device__ __forceinline__ unsigned bfpack(float lo, float hi) {
    return (__float_as_uint(lo) >> 16) | (__float_as_uint(hi) & 0xFFFF0000u);
}

// decode 8 fp8 (uint2) and accumulate UNWEIGHTED into 4 f32x2 (v_pk_add_f32)
static __device__ __forceinline__ void acc8_add(f32x2* acc, uint2 v) {
#ifdef HWF8
    acc[0] += __builtin_amdgcn_cvt_pk_f32_fp8((int)v.x, false);
    acc[1] += __builtin_amdgcn_cvt_pk_f32_fp8((int)v.x, true);
    acc[2] += __builtin_amdgcn_cvt_pk_f32_fp8((int)v.y, false);
    acc[3] += __builtin_amdgcn_cvt_pk_f32_fp8((int)v.y, true);
#else
    unsigned u[2] = {v.x, v.y};
#pragma unroll
    for (int q = 0; q < 2; q++) {
        float o[4]; f8d4(u[q], o);
        acc[2 * q]     += (f32x2){o[0], o[1]};
        acc[2 * q + 1] += (f32x2){o[2], o[3]};
    }
#endif
}

// ---------------- dtype probe (writes raw; flags derived inline) --------------
__global__ void k_probe1(const unsigned short* __restrict__ xw,
                         const int* __restrict__ ei, int* __restrict__ raw) {
    int i = blockIdx.x * 256 + threadIdx.x;    // 65536 probes
    int nan = ((xw[i] & 0x7F80u) == 0x7F80u) ? 1 : 0;
    int odd = (ei[2 * i + 1] != 0) ? 1 : 0;
    unsigned long long bn = __ballot(nan);
    unsigned long long bo = __ballot(odd);
    if ((threadIdx.x & 63) == 0) {
        if (bn) atomicAdd(&raw[0], __popcll(bn));
        if (bo) atomicAdd(&raw[1], __popcll(bo));
    }
}
// raw[0] > 0  -> x/weights are f32 ;  raw[1] == 0 -> edge_index is int64

static __device__ __forceinline__ int e_src(const int* ei, int e, int f64) {
    int v = f64 ? ei[2 * e] : ei[e];
    return min(max(v, 0), NN - 1);
}
static __device__ __forceinline__ int e_dst(const int* ei, int e, int f64) {
    int v = f64 ? ei[2 * (NE + e)] : ei[NE + e];
    return min(max(v, 0), NN - 1);
}
static __device__ __forceinline__ float ldx(const void* p, long long i, int f32) {
    return f32 ? ((const float*)p)[i] : bf2f(((const __hip_bfloat16*)p)[i]);
}

// ---- prep v2 (66 blocks): W->bf16 frag tables, biases, init, pad-row zero ----
// No x conversion any more: L1 GEMM reads x directly. Pad-zero writes at
// P+NN*128 (12.8MB) which is beyond the 6.4MB scatter scratch -> safe to run
// before the CSR chain.
__global__ __launch_bounds__(256) void k_prep(const void* W1, const void* b1,
                                              const void* W2, const void* b2,
                                              const void* W3, const void* b3,
                                              const void* Wa,
                                              unsigned short* W1b, unsigned short* W2b,
                                              unsigned short* W3b,
                                              float* b1f, float* b2f, float* b3f,
                                              float* Waf,
                                              unsigned char* __restrict__ P,
                                              const int* __restrict__ raw,
                                              float* colsum, float* pooled, int* wsync) {
    int t = threadIdx.x;
    int gi = blockIdx.x;
    int f = raw[0] > 0;
    if (gi < 64) {
        int i = gi * 256 + t;                     // 0..16383
        {
            int j = i & 7, l = (i >> 3) & 63, c = (i >> 9) & 7, kc = i >> 12;
            int k = kc * 32 + ((l >> 4)) * 8 + j;
            int col = c * 16 + (l & 15);
            W1b[i] = __bfloat16_as_ushort(__float2bfloat16(ldx(W1, k * 128 + col, f)));
            W2b[i] = __bfloat16_as_ushort(__float2bfloat16(ldx(W2, k * 128 + col, f)));
        }
        if (i < 8192) {
            int j = i & 7, l = (i >> 3) & 63, c = (i >> 9) & 3, kc = i >> 11;
            int k = kc * 32 + ((l >> 4)) * 8 + j;
            int col = c * 16 + (l & 15);
            W3b[i] = __bfloat16_as_ushort(__float2bfloat16(ldx(W3, k * 64 + col, f)));
        }
        if (i < 4096)  Waf[i] = ldx(Wa, i, f);
        if (i < 128)   { b1f[i] = ldx(b1, i, f); b2f[i] = ldx(b2, i, f); }
        if (i < 64)    b3f[i] = ldx(b3, i, f);
        return;
    }
    if (gi == 64) {
        if (t < 64) { colsum[t] = 0.0f; pooled[t] = 0.0f; }
        if (t == 0) { wsync[0] = 0; wsync[1] = 0; }
    } else {
        // zero pad rows NN..NR-1 of P (gathered by invalid edge slots)
        for (int z = t; z < (NR - NN) * 32; z += 256)
            ((unsigned*)(P + (size_t)NN * 128))[z] = 0u;
    }
}

// ======== CSR build: atomic-free multisplit ========
__global__ __launch_bounds__(256) void k_hist(const int* __restrict__ ei,
                                              int* __restrict__ ghist,
                                              const int* __restrict__ raw) {
    __shared__ int h[NB2];
    int blk = blockIdx.x, t = threadIdx.x;
    for (int i = t; i < NB2; i += 256) h[i] = 0;
    __syncthreads();
    int f64 = (raw[1] == 0);
    int e0 = blk * EPB;
    for (int i = t; i < EPB; i += 256) {
        int e = e0 + i;
        if (e < NE) atomicAdd(&h[e_dst(ei, e, f64) >> 9], 1);
    }
    __syncthreads();
    for (int i = t; i < NB2; i += 256) ghist[blk * NB2 + i] = h[i];
}

// parallel per-bucket scan over the 391 hist blocks (196 blocks x 512 thr).
// Writes offm WITHOUT the cbase base (k_scatter adds it) and tot[b].
// Last block also performs the 196-bucket top scan.
__global__ __launch_bounds__(512) void k_offA(const int* __restrict__ ghist,
                                              int* __restrict__ tot,
                                              int* __restrict__ offm,
                                              int* __restrict__ cbase,
                                              int* __restrict__ rowptr,
                                              int* __restrict__ sync) {
    int b = blockIdx.x;               // bucket 0..NB2-1
    int t = threadIdx.x;              // 0..511 (covers NBLK=391)
    __shared__ int wsum[8];
    __shared__ int woff[8];
    int v = (t < NBLK) ? ghist[t * NB2 + b] : 0;
    int s = v;
#pragma unroll
    for (int o = 1; o < 64; o <<= 1) {
        int u = __shfl_up(s, o, 64);
        if ((t & 63) >= o) s += u;
    }
    int w = t >> 6;
    if ((t & 63) == 63) wsum[w] = s;
    __syncthreads();
    if (t == 0) {
        int run = 0;
#pragma unroll
        for (int i = 0; i < 8; i++) { woff[i] = run; run += wsum[i]; }
        tot[b] = run;
    }
    __syncthreads();
    if (t < NBLK) offm[t * NB2 + b] = s - v + woff[w];   // exclusive prefix
    // last block: top scan tot -> cbase, rowptr[NN]
    __shared__ int lastf;
    if (t == 0) {
        __threadfence();
        int old = atomicAdd(sync, 1);
        lastf = (old == NB2 - 1) ? 1 : 0;
    }
    __syncthreads();
    if (lastf) {
        __shared__ int sv[NB2];
        if (t < NB2) sv[t] = atomicAdd(&tot[t], 0);   // coherent read
        __syncthreads();
        if (t == 0) {
            int run = 0;
            for (int bb = 0; bb < NB2; bb++) { cbase[bb] = run; run += sv[bb]; }
            cbase[NB2] = run;
            rowptr[NN] = run;   // == NE
        }
    }
}

__global__ __launch_bounds__(256) void k_scatter(const int* __restrict__ ei,
                                                 const int* __restrict__ offm,
                                                 const int* __restrict__ cbase,
                                                 int* __restrict__ scratch,
                                                 const int* __restrict__ raw) {
    __shared__ int cur[NB2];
    int blk = blockIdx.x, t = threadIdx.x;
    for (int i = t; i < NB2; i += 256) cur[i] = offm[blk * NB2 + i] + cbase[i];
    __syncthreads();
    int f64 = (raw[1] == 0);
    int e0 = blk * EPB;
    for (int i = t; i < EPB; i += 256) {
        int e = e0 + i;
        if (e < NE) {
            int d = e_dst(ei, e, f64);
            int s = e_src(ei, e, f64);
            int p = atomicAdd(&cur[d >> 9], 1);
            p = min(max(p, 0), NE - 1);
            scratch[p] = s | ((d & 511) << 17);
        }
    }
}

__global__ __launch_bounds__(256) void k_build(const int* __restrict__ scratch,
                                               const int* __restrict__ cbase,
                                               int* __restrict__ rowptr,
                                               float* __restrict__ dis,
                                               int* __restrict__ csr) {
    __shared__ int hist[512];
    __shared__ int base[512];
    __shared__ int sd[256];
    int b = blockIdx.x, t = threadIdx.x;
    int n0 = b << 9;
    int s0 = cbase[b], s1 = cbase[b + 1];
    hist[t] = 0; hist[t + 256] = 0;
    __syncthreads();
    for (int i = s0 + t; i < s1; i += 256) {
        int dlo = (scratch[i] >> 17) & 511;
        atomicAdd(&hist[dlo], 1);
    }
    __syncthreads();
    int v0 = hist[2 * t], v1 = hist[2 * t + 1];
    int s = v0 + v1;
    sd[t] = s; __syncthreads();
    for (int o = 1; o < 256; o <<= 1) {
        int add = (t >= o) ? sd[t - o] : 0;
        __syncthreads();
        sd[t] += add;
        __syncthreads();
    }
    int run = s0 + sd[t] - s;
    base[2 * t] = run;
    base[2 * t + 1] = run + v0;
    int n = n0 + 2 * t;
    if (n < NN) {
        rowptr[n] = run;
        dis[n] = rsqrtf((float)v0 + 1.0f);
    }
    if (n + 1 < NN) {
        rowptr[n + 1] = run + v0;
        dis[n + 1] = rsqrtf((float)v1 + 1.0f);
    }
    __syncthreads();
    for (int i = s0 + t; i < s1; i += 256) {
        int v = scratch[i];
        int dlo = (v >> 17) & 511;
        int p = atomicAdd(&base[dlo], 1);
        p = min(max(p, 0), NE - 1);
        csr[p] = v & 0x1FFFF;
    }
}

// ------------- MFMA GEMM: O[NNxCOLS] = dis[row] * (A @ W) --------------------
// Operands swapped (D = W^T · A^T): each lane's acc[c][0..3] are 4 consecutive
// output columns of one node -> pack to u32, 1 dword store per c.
// XS=0: A = fp8 table P (NR rows). XS=1: A = raw x (f32 or bf16 per raw[0]),
// row index clamped to NN-1 (x has exactly NN rows; clamped rows' outputs are
// discarded or zeroed via d=0).
template <int NCT, int XS>    // NCT = COLS/16 (8 or 4)
__global__ __launch_bounds__(256) void k_xf_mfma(const unsigned char* __restrict__ A,
                                                 const void* __restrict__ X,
                                                 const unsigned short* __restrict__ Wf,
                                                 const float* __restrict__ dis,
                                                 const int* __restrict__ raw,
                                                 unsigned char* __restrict__ O) {
    __shared__ unsigned short wl[NCT * 4 * 64 * 8];
    int t = threadIdx.x;
    int n0 = blockIdx.x * 64;
    {
        const uint4* wg = (const uint4*)Wf;
        uint4* wld = (uint4*)wl;
#pragma unroll
        for (int i = 0; i < NCT; i++) wld[i * 256 + t] = wg[i * 256 + t];
    }
    __syncthreads();
    int w = t >> 6, l = t & 63;
    int quad = l >> 4, m = l & 15;
    int node = n0 + w * 16 + m;
    int lrow = min(node, NN - 1);
    const unsigned char* ap = A + (size_t)node * 128 + quad * 8;
    const float* xf = (const float*)X + (size_t)lrow * 128 + quad * 8;
    const unsigned short* xh = (const unsigned short*)X + (size_t)lrow * 128 + quad * 8;
    int xf32 = XS ? (raw[0] > 0) : 0;
    f32x4 acc[NCT];
#pragma unroll
    for (int c = 0; c < NCT; c++) acc[c] = (f32x4){0.0f, 0.0f, 0.0f, 0.0f};
#pragma unroll
    for (int kc = 0; kc < 4; kc++) {
        union { unsigned u[4]; bf16x8 v; } fr;
        if (XS == 0) {
            uint2 g = *(const uint2*)(ap + kc * 32);
            float o[8];
            f8d4(g.x, o); f8d4(g.y, o + 4);
            fr.u[0] = bfpack(o[0], o[1]);
            fr.u[1] = bfpack(o[2], o[3]);
            fr.u[2] = bfpack(o[4], o[5]);
            fr.u[3] = bfpack(o[6], o[7]);
        } else if (xf32) {
            float4 a = *(const float4*)(xf + kc * 32);
            float4 b = *(const float4*)(xf + kc * 32 + 4);
            fr.u[0] = bfpack(a.x, a.y);
            fr.u[1] = bfpack(a.z, a.w);
            fr.u[2] = bfpack(b.x, b.y);
            fr.u[3] = bfpack(b.z, b.w);
        } else {
            uint4 u = *(const uint4*)(xh + kc * 32);
            fr.u[0] = u.x; fr.u[1] = u.y; fr.u[2] = u.z; fr.u[3] = u.w;
        }
#pragma unroll
        for (int c = 0; c < NCT; c++) {
            bf16x8 bw = *(const bf16x8*)&wl[((kc * NCT + c) * 64 + l) * 8];
            acc[c] = __builtin_amdgcn_mfma_f32_16x16x32_bf16(bw, fr.v, acc[c], 0, 0, 0);
        }
    }
    float d = (node < NN) ? dis[node] : 0.0f;     // node==NN -> store zeros
    if (node <= NN) {
        unsigned char* orow = O + (size_t)node * (NCT * 16) + quad * 4;
#pragma unroll
        for (int c = 0; c < NCT; c++) {
            unsigned pk = (unsigned)f8e2(acc[c][0] * d, acc[c][1] * d)
                        | ((unsigned)f8e2(acc[c][2] * d, acc[c][3] * d) << 16);
            *(unsigned*)(orow + c * 16) = pk;
        }
    }
}

// ---- agg, F=128: H = relu?((sum T'[src] + T'[n]) * dn + b), fp8->fp8 --------
// v6: 2 nodes/wave (32 lanes each), 2 slots x 16 lanes x 8B.
template <bool RELU>
__global__ __launch_bounds__(256) void k_agg128(const unsigned char* __restrict__ Tb,
                                                const int* __restrict__ rowptr,
                                                const int* __restrict__ csr,
                                                const float* __restrict__ dis,
                                                const float* __restrict__ bias,
                                                unsigned char* __restrict__ H) {
    int lane = threadIdx.x & 63;
    int half = lane >> 5;
    int hl = lane & 31;
    int n = blockIdx.x * 8 + (threadIdx.x >> 6) * 2 + half;
    int r = hl >> 4;              // slot 0..1
    int f = hl & 15;              // feature group: bytes 8f..8f+7
    int fo = f << 3;
    float dn = dis[n];
    int s0 = rowptr[n], s1 = rowptr[n + 1];
    s0 = min(max(s0, 0), NE); s1 = min(max(s1, s0), NE);
    f32x2 acc[4];
#pragma unroll
    for (int k = 0; k < 4; k++) acc[k] = (f32x2){0.0f, 0.0f};
    if (r == 0) {   // self term: T'[n], weight 1.0 (dis already folded into T')
        uint2 v = *(const uint2*)(Tb + (((unsigned)n << 7) + (unsigned)fo));
        acc8_add(acc, v);
    }
    int ab = half << 7;           // bpermute byte base of own half (32 lanes * 4B)
    for (int base = s0; base < s1; base += 32) {
        int m = min(32, s1 - base);
        unsigned voff = (unsigned)NN << 7;          // pad -> zero row
        if (hl < m) voff = (unsigned)csr[base + hl] << 7;
        int nq = (m + 7) >> 3;                      // iters of 4 groups (8 edges/half)
        for (int q = 0; q < nq; q++) {
            int a0 = ab + q * 32 + r * 4;           // group 4q+k at ab+(4q+k)*8+r*4
            unsigned vo0 = (unsigned)__builtin_amdgcn_ds_bpermute(a0,      (int)voff);
            unsigned vo1 = (unsigned)__builtin_amdgcn_ds_bpermute(a0 + 8,  (int)voff);
            unsigned vo2 = (unsigned)__builtin_amdgcn_ds_bpermute(a0 + 16, (int)voff);
            unsigned vo3 = (unsigned)__builtin_amdgcn_ds_bpermute(a0 + 24, (int)voff);
            uint2 v0 = *(const uint2*)(Tb + (vo0 + (unsigned)fo));
            uint2 v1 = *(const uint2*)(Tb + (vo1 + (unsigned)fo));
            uint2 v2 = *(const uint2*)(Tb + (vo2 + (unsigned)fo));
            uint2 v3 = *(const uint2*)(Tb + (vo3 + (unsigned)fo));
            acc8_add(acc, v0);
            acc8_add(acc, v1);
            acc8_add(acc, v2);
            acc8_add(acc, v3);
        }
    }
    // reduce across the 2 slots (lane stride 16; stays within each half)
#pragma unroll
    for (int k = 0; k < 4; k++) {
        acc[k].x += __shfl_xor(acc[k].x, 16, 64);
        acc[k].y += __shfl_xor(acc[k].y, 16, 64);
    }
    if (r == 0) {
        float4 bA = *(const float4*)(bias + fo);
        float4 bB = *(const float4*)(bias + fo + 4);
        float t[8];
        t[0] = acc[0].x * dn + bA.x; t[1] = acc[0].y * dn + bA.y;
        t[2] = acc[1].x * dn + bA.z; t[3] = acc[1].y * dn + bA.w;
        t[4] = acc[2].x * dn + bB.x; t[5] = acc[2].y * dn + bB.y;
        t[6] = acc[3].x * dn + bB.z; t[7] = acc[3].y * dn + bB.w;
        if (RELU) {
#pragma unroll
            for (int k = 0; k < 8; k++) t[k] = fmaxf(t[k], 0.0f);
        }
        unsigned lo = (unsigned)f8e2(t[0], t[1]) | ((unsigned)f8e2(t[2], t[3]) << 16);
        unsigned hi = (unsigned)f8e2(t[4], t[5]) | ((unsigned)f8e2(t[6], t[7]) << 16);
        *(uint2*)(H + (((size_t)n << 7) + (size_t)fo)) = make_uint2(lo, hi);
    }
}

// ---- agg, F=64 final: h3 = (sum T3'[src] + T3'[n]) * dn + b3 -> bf16 --------
// v6: 4 nodes/wave (16 lanes each), 2 slots x 8 lanes x 8B, reduce = 1 level.
__global__ __launch_bounds__(256) void k_agg64(const unsigned char* __restrict__ Tb,
                                               const int* __restrict__ rowptr,
                                               const int* __restrict__ csr,
                                               const float* __restrict__ dis,
                                               const float* __restrict__ bias,
                                               unsigned short* __restrict__ Hb) {
    int lane = threadIdx.x & 63;
    int qtr = lane >> 4;
    int ql = lane & 15;
    int n = blockIdx.x * 16 + (threadIdx.x >> 6) * 4 + qtr;
    int r = ql >> 3;              // slot 0..1
    int f = ql & 7;               // feature group: bytes 8f..8f+7
    int fo = f << 3;
    float dn = dis[n];
    int s0 = rowptr[n], s1 = rowptr[n + 1];
    s0 = min(max(s0, 0), NE); s1 = min(max(s1, s0), NE);
    f32x2 acc[4];
#pragma unroll
    for (int k = 0; k < 4; k++) acc[k] = (f32x2){0.0f, 0.0f};
    if (r == 0) {   // self term: weight 1.0 (dis folded into T3')
        uint2 v = *(const uint2*)(Tb + (((unsigned)n << 6) + (unsigned)fo));
        acc8_add(acc, v);
    }
    int ab = qtr << 6;            // bpermute byte base of own quarter (16 lanes * 4B)
    for (int base = s0; base < s1; base += 16) {
        int m = min(16, s1 - base);
        unsigned voff = (unsigned)NN << 6;          // pad -> zero row
        if (ql < m) voff = (unsigned)csr[base + ql] << 6;
        int nq = (m + 7) >> 3;                      // iters of 4 groups (8 edges/qtr)
        for (int q = 0; q < nq; q++) {
            int a0 = ab + q * 32 + r * 4;           // group 4q+k at ab+(4q+k)*8+r*4
            unsigned vo0 = (unsigned)__builtin_amdgcn_ds_bpermute(a0,      (int)voff);
            unsigned vo1 = (unsigned)__builtin_amdgcn_ds_bpermute(a0 + 8,  (int)voff);
            unsigned vo2 = (unsigned)__builtin_amdgcn_ds_bpermute(a0 + 16, (int)voff);
            unsigned vo3 = (unsigned)__builtin_amdgcn_ds_bpermute(a0 + 24, (int)voff);
            uint2 v0 = *(const uint2*)(Tb + (vo0 + (unsigned)fo));
            uint2 v1 = *(const uint2*)(Tb + (vo1 + (unsigned)fo));
            uint2 v2 = *(const uint2*)(Tb + (vo2 + (unsigned)fo));
            uint2 v3 = *(const uint2*)(Tb + (vo3 + (unsigned)fo));
            acc8_add(acc, v0);
            acc8_add(acc, v1);
            acc8_add(acc, v2);
            acc8_add(acc, v3);
        }
    }
    // reduce across the 2 slots (lane stride 8; stays within each quarter)
#pragma unroll
    for (int k = 0; k < 4; k++) {
        acc[k].x += __shfl_xor(acc[k].x, 8, 64);
        acc[k].y += __shfl_xor(acc[k].y, 8, 64);
    }
    if (r == 0) {
        float4 bA = *(const float4*)(bias + fo);
        float4 bB = *(const float4*)(bias + fo + 4);
        float t[8];
        t[0] = acc[0].x * dn + bA.x; t[1] = acc[0].y * dn + bA.y;
        t[2] = acc[1].x * dn + bA.z; t[3] = acc[1].y * dn + bA.w;
        t[4] = acc[2].x * dn + bB.x; t[5] = acc[2].y * dn + bB.y;
        t[6] = acc[3].x * dn + bB.z; t[7] = acc[3].y * dn + bB.w;
        unsigned p0 = (unsigned)__bfloat16_as_ushort(__float2bfloat16(t[0])) |
                      ((unsigned)__bfloat16_as_ushort(__float2bfloat16(t[1])) << 16);
        unsigned p1 = (unsigned)__bfloat16_as_ushort(__float2bfloat16(t[2])) |
                      ((unsigned)__bfloat16_as_ushort(__float2bfloat16(t[3])) << 16);
        unsigned p2 = (unsigned)__bfloat16_as_ushort(__float2bfloat16(t[4])) |
                      ((unsigned)__bfloat16_as_ushort(__float2bfloat16(t[5])) << 16);
        unsigned p3 = (unsigned)__bfloat16_as_ushort(__float2bfloat16(t[6])) |
                      ((unsigned)__bfloat16_as_ushort(__float2bfloat16(t[7])) << 16);
        *(uint4*)(Hb + (((size_t)n << 6) + (size_t)fo)) = make_uint4(p0, p1, p2, p3);
    }
}

// ---------------- pooling: colsum (+ fused ctx via last-block) ----------------
__global__ __launch_bounds__(512) void k_colsum(const unsigned short* __restrict__ h3,
                                                float* __restrict__ colsum,
                                                const float* __restrict__ Waf,
                                                float* __restrict__ ctx,
                                                int* __restrict__ wsync) {
    int t = threadIdx.x;
    int lane = t & 63;
    int rg = lane >> 4, cq = lane & 15;
    int wid = (blockIdx.x * 512 + t) >> 6;
    int nw = (gridDim.x * 512) >> 6;
    float a0 = 0, a1 = 0, a2 = 0, a3 = 0;
    for (int r = wid * 4 + rg; r < NN; r += nw * 4) {
        uint2 v = *(const uint2*)(h3 + ((size_t)r << 6) + cq * 4);
        a0 += bfu((unsigned short)(v.x & 0xFFFF));
        a1 += bfu((unsigned short)(v.x >> 16));
        a2 += bfu((unsigned short)(v.y & 0xFFFF));
        a3 += bfu((unsigned short)(v.y >> 16));
    }
    a0 += __shfl_xor(a0, 16, 64); a0 += __shfl_xor(a0, 32, 64);
    a1 += __shfl_xor(a1, 16, 64); a1 += __shfl_xor(a1, 32, 64);
    a2 += __shfl_xor(a2, 16, 64); a2 += __shfl_xor(a2, 32, 64);
    a3 += __shfl_xor(a3, 16, 64); a3 += __shfl_xor(a3, 32, 64);
    __shared__ float part[8][64];
    int w = t >> 6;
    if (rg == 0) {
        part[w][cq * 4 + 0] = a0;
        part[w][cq * 4 + 1] = a1;
        part[w][cq * 4 + 2] = a2;
        part[w][cq * 4 + 3] = a3;
    }
    __syncthreads();
    if (t < 64) {
        float s = 0;
#pragma unroll
        for (int i = 0; i < 8; i++) s += part[i][t];
        atomicAdd(&colsum[t], s);
    }
    // last block computes ctx = tanh(mean @ Wa)
    __shared__ int lastf;
    __syncthreads();
    if (t == 0) {
        __threadfence();
        int old = atomicAdd(&wsync[0], 1);
        lastf = (old == (int)gridDim.x - 1) ? 1 : 0;
    }
    __syncthreads();
    if (lastf) {
        __shared__ float ms[64];
        if (t < 64) {
            __threadfence();
            ms[t] = atomicAdd(&colsum[t], 0.0f) * (1.0f / NN);  // coherent read
        }
        __syncthreads();
        if (t < 64) {
            float s = 0.0f;
#pragma unroll
            for (int k = 0; k < 64; k++) s += ms[k] * Waf[k * 64 + t];
            ctx[t] = tanhf(s);
        }
    }
}

// -------- pooling pass 2: attention pool + fused h3->out copy + tail ---------
__global__ __launch_bounds__(512) void k_pool(const unsigned short* __restrict__ h3,
                                              const float* __restrict__ ctx,
                                              float* __restrict__ pooled,
                                              void* __restrict__ out,
                                              const int* __restrict__ raw,
                                              int* __restrict__ wsync) {
    int t = threadIdx.x;
    int lane = t & 63;
    int rg = lane >> 4, cq = lane & 15;
    int wid = (blockIdx.x * 512 + t) >> 6;
    int nw = (gridDim.x * 512) >> 6;
    int f32o = raw[0] > 0;
    float c0 = ctx[cq * 4 + 0], c1 = ctx[cq * 4 + 1];
    float c2 = ctx[cq * 4 + 2], c3 = ctx[cq * 4 + 3];
    float q0 = 0, q1 = 0, q2 = 0, q3 = 0;
    for (int r = wid * 4 + rg; r < NN; r += nw * 4) {
        uint2 v = *(const uint2*)(h3 + ((size_t)r << 6) + cq * 4);
        float x0 = bfu((unsigned short)(v.x & 0xFFFF));
        float x1 = bfu((unsigned short)(v.x >> 16));
        float x2 = bfu((unsigned short)(v.y & 0xFFFF));
        float x3 = bfu((unsigned short)(v.y >> 16));
        // fused output write (h3 part of out); T3' scratch in d_out is dead here
        if (f32o) {
            *(float4*)((float*)out + ((size_t)r << 6) + cq * 4) =
                make_float4(x0, x1, x2, x3);
        } else {
            *(uint2*)((unsigned short*)out + ((size_t)r << 6) + cq * 4) = v;
        }
        float p = x0 * c0 + x1 * c1 + x2 * c2 + x3 * c3;
        p += __shfl_xor(p, 1, 64);
        p += __shfl_xor(p, 2, 64);
        p += __shfl_xor(p, 4, 64);
        p += __shfl_xor(p, 8, 64);
        float sc = 1.0f / (1.0f + expf(-p));
        q0 += sc * x0; q1 += sc * x1; q2 += sc * x2; q3 += sc * x3;
    }
    q0 += __shfl_xor(q0, 16, 64); q0 += __shfl_xor(q0, 32, 64);
    q1 += __shfl_xor(q1, 16, 64); q1 += __shfl_xor(q1, 32, 64);
    q2 += __shfl_xor(q2, 16, 64); q2 += __shfl_xor(q2, 32, 64);
    q3 += __shfl_xor(q3, 16, 64); q3 += __shfl_xor(q3, 32, 64);
    __shared__ float part[8][64];
    int w = t >> 6;
    if (rg == 0) {
        part[w][cq * 4 + 0] = q0;
        part[w][cq * 4 + 1] = q1;
        part[w][cq * 4 + 2] = q2;
        part[w][cq * 4 + 3] = q3;
    }
    __syncthreads();
    if (t < 64) {
        float s = 0;
#pragma unroll
        for (int i = 0; i < 8; i++) s += part[i][t];
        atomicAdd(&pooled[t], s);
    }
    // last block writes the 64 pooled tail values
    __shared__ int lastf;
    __syncthreads();
    if (t == 0) {
        __threadfence();
        int old = atomicAdd(&wsync[1], 1);
        lastf = (old == (int)gridDim.x - 1) ? 1 : 0;
    }
    __syncthreads();
    if (lastf && t < 64) {
        __threadfence();
        float pv = atomicAdd(&pooled[t], 0.0f);   // coherent read
        if (f32o) {
            ((float*)out)[6400000 + t] = pv;
        } else {
            ((unsigned short*)out)[6400000 + t] =
                __bfloat16_as_ushort(__float2bfloat16(pv));
        }
    }
}

// ---------------- workspace layout (~21.5 MB) ----------------
static constexpr size_t AL(size_t x) { return (x + 255) & ~size_t(255); }
static constexpr size_t OFF_FLAGS  = 0;
static constexpr size_t OFF_RAW    = OFF_FLAGS + 256;
static constexpr size_t OFF_GHIST  = OFF_RAW + 256;
static constexpr size_t OFF_OFFM   = OFF_GHIST + AL((size_t)NBLK * NB2 * 4);
static constexpr size_t OFF_CBASE  = OFF_OFFM + AL((size_t)NBLK * NB2 * 4);
static constexpr size_t OFF_ROWPTR = OFF_CBASE + AL((NB2 + 1) * 4);
static constexpr size_t OFF_CSR    = OFF_ROWPTR + AL((NN + 1) * 4);
static constexpr size_t OFF_DIS    = OFF_CSR + AL((size_t)NE * 4);
static constexpr size_t OFF_P      = OFF_DIS + AL(NN * 4);     // NR*128 fp8; also scatter scratch; also bf16 h3
static constexpr size_t OFF_W1B    = OFF_P + AL((size_t)NR * 128);
static constexpr size_t OFF_W2B    = OFF_W1B + AL(16384 * 2);
static constexpr size_t OFF_W3B    = OFF_W2B + AL(16384 * 2);
static constexpr size_t OFF_B1F    = OFF_W3B + AL(8192 * 2);
static constexpr size_t OFF_B2F    = OFF_B1F + AL(128 * 4);
static constexpr size_t OFF_B3F    = OFF_B2F + AL(128 * 4);
static constexpr size_t OFF_WAF    = OFF_B3F + AL(64 * 4);
static constexpr size_t OFF_COLSUM = OFF_WAF + AL(4096 * 4);
static constexpr size_t OFF_POOLED = OFF_COLSUM + AL(64 * 4);
static constexpr size_t OFF_CTX    = OFF_POOLED + AL(64 * 4);
static constexpr size_t OFF_SYNC   = OFF_CTX + AL(64 * 4);
static constexpr size_t OFF_TOT    = OFF_SYNC + 256;

extern "C" void kernel_launch(void* const* d_in, const int* in_sizes, int n_in,
                              void* d_out, int out_size, void* d_ws, size_t ws_size,
                              hipStream_t stream) {
    const int* ei = (const int*)d_in[0];
    const void* x  = d_in[1];
    const void* W1 = d_in[2];
    const void* b1 = d_in[3];
    const void* W2 = d_in[4];
    const void* b2 = d_in[5];
    const void* W3 = d_in[6];
    const void* b3 = d_in[7];
    const void* Wa = d_in[8];

    char* ws = (char*)d_ws;
    int*   raw    = (int*)(ws + OFF_RAW);
    int*   ghist  = (int*)(ws + OFF_GHIST);
    int*   offm   = (int*)(ws + OFF_OFFM);
    int*   cbase  = (int*)(ws + OFF_CBASE);
    int*   rowptr = (int*)(ws + OFF_ROWPTR);
    int*   csr    = (int*)(ws + OFF_CSR);
    float* dis    = (float*)(ws + OFF_DIS);
    unsigned char*  P    = (unsigned char*)(ws + OFF_P);
    int*            scrA = (int*)(ws + OFF_P);
    unsigned short* Hb   = (unsigned short*)(ws + OFF_P);
    unsigned short* W1b = (unsigned short*)(ws + OFF_W1B);
    unsigned short* W2b = (unsigned short*)(ws + OFF_W2B);
    unsigned short* W3b = (unsigned short*)(ws + OFF_W3B);
    float* b1f    = (float*)(ws + OFF_B1F);
    float* b2f    = (float*)(ws + OFF_B2F);
    float* b3f    = (float*)(ws + OFF_B3F);
    float* Waf    = (float*)(ws + OFF_WAF);
    float* colsum = (float*)(ws + OFF_COLSUM);
    float* pooled = (float*)(ws + OFF_POOLED);
    float* ctx    = (float*)(ws + OFF_CTX);
    int*   wsync  = (int*)(ws + OFF_SYNC);
    int*   tot    = (int*)(ws + OFF_TOT);

    unsigned char* Q = (unsigned char*)d_out;   // d_out doubles as T-scratch (12.8 MB)

    hipMemsetAsync(raw, 0, 256, stream);        // zeroes raw[0..63] incl. offA sync

    k_probe1<<<256, 256, 0, stream>>>((const unsigned short*)x, ei, raw);

    // small prep: W tables, init, pad-row zero (above 6.4MB scratch -> safe here)
    k_prep<<<66, 256, 0, stream>>>(W1, b1, W2, b2, W3, b3, Wa,
                                   W1b, W2b, W3b, b1f, b2f, b3f, Waf,
                                   P, raw, colsum, pooled, wsync);

    // atomic-free CSR build (uses P region as scatter scratch)
    k_hist<<<NBLK, 256, 0, stream>>>(ei, ghist, raw);
    k_offA<<<NB2, 512, 0, stream>>>(ghist, tot, offm, cbase, rowptr, &raw[2]);
    k_scatter<<<NBLK, 256, 0, stream>>>(ei, offm, cbase, scrA, raw);
    k_build<<<NB2, 256, 0, stream>>>(scrA, cbase, rowptr, dis, csr);

    // L1: T' = dis*(x@W1) (Q, MFMA, reads x directly) ; P = relu((sum+self)*dn + b1)
    k_xf_mfma<8, 1><<<NR / 64, 256, 0, stream>>>(P, x, W1b, dis, raw, Q);
    k_agg128<true><<<NN / 8, 256, 0, stream>>>(Q, rowptr, csr, dis, b1f, P);
    // L2
    k_xf_mfma<8, 0><<<NR / 64, 256, 0, stream>>>(P, x, W2b, dis, raw, Q);
    k_agg128<true><<<NN / 8, 256, 0, stream>>>(Q, rowptr, csr, dis, b2f, P);
    // L3: T3' = dis*(P@W3) (Q, 64 cols) ; Hb = (sum+self)*dn + b3 (bf16)
    k_xf_mfma<4, 0><<<NR / 64, 256, 0, stream>>>(P, x, W3b, dis, raw, Q);
    k_agg64<<<NN / 16, 256, 0, stream>>>(Q, rowptr, csr, dis, b3f, Hb);

    // attention pooling (ctx fused into colsum's last block; tail in pool's)
    k_colsum<<<256, 512, 0, stream>>>(Hb, colsum, Waf, ctx, wsync);
    k_pool<<<256, 512, 0, stream>>>(Hb, ctx, pooled, d_out, raw, wsync);
}